// Round 1
// 2003.311 us; speedup vs baseline: 1.0863x; 1.0863x over previous
//
#include <hip/hip_runtime.h>
#include <math.h>

// forecastRNN on MI355X, round 7.
// Decode handoff rework (decode_persistent was 841us of 2176us, all
// utilization counters ~2% -> pure latency):
// - Hierarchical arrive: producers fetch_add a per-8-block SUBcounter
//   (release, agent); the 8th forwards +8 to the master; the last master
//   arriver broadcasts the epoch with relaxed agent stores to per-8-consumer
//   INBOX lines. Consumers RMW-poll ONLY their own inbox line (<=8 pollers
//   per line). Round 6 had up to 64 pollers + 64 producers RMW-serializing
//   on ONE line at the coherence point -> ~13us/stage.
// - Cell stage split: h@Whh^T half depends only on the previous cell output,
//   so it runs overlapped with the previous gap's L1/L2/L3; only x@Wih^T
//   (16 K-chunks) remains on the critical path after L3.
// - frag_gemm A-ring prefetch depth 4 -> 8 (1 block/CU, 4 waves; global
//   latency ~500-900cy needs ~7 iterations in flight; VGPRs are free here).
// RNN / large-GEMM / conversion kernels unchanged from round 6.

typedef unsigned short ushort_t;
typedef __attribute__((ext_vector_type(8))) short short8;
typedef __attribute__((ext_vector_type(4))) float f32x4;

#define BB 512
#define TT 65
#define TN 64
#define FF 512
#define HD 1000
#define HDP 1024
#define EPSBN 1e-5f
#define BF (BB*FF)          // 262144
#define MALL (BB*TN)        // 32768
#define CH 4
#define CM (MALL/CH)        // 8192
#define HP 520              // LDS h row stride (1040 B)
#define DNB 224
#define NGRP 28

// sync layout in cnt[] (unsigned words):
//   [0, 1024)      master counters, event ev at ev*64 (256 B apart)
//   [1024, 2048)   subcounters:   (ev*8  + sub)*32   (128 B apart)
//   [2048, 4096)   inbox lines:   (ev*16 + grp)*32   (128 B apart)
// events: 0=cell_done 1=l1_done 2=l2_done 3=l3_done; epoch = gap+1
#define SYNC_WORDS 4096

__device__ __forceinline__ ushort_t f2bf(float f) {
    union { float f; unsigned u; } v; v.f = f;
    unsigned r = v.u + 0x7FFFu + ((v.u >> 16) & 1u);
    return (ushort_t)(r >> 16);
}

__device__ __forceinline__ float ftanh(float x) {
    const float e = __expf(2.f * x);
    return 1.f - 2.f / (e + 1.f);
}

__device__ __forceinline__ void ld16(const ushort_t* g, ushort_t* l) {
    __builtin_amdgcn_global_load_lds(
        (const __attribute__((address_space(1))) unsigned*)g,
        (__attribute__((address_space(3))) unsigned*)l, 16, 0, 0);
}

// ---------------------------------------------------------------------------
// Large-GEMM kernel (XW precompute + autoenc), 128x128 tile, BK=32.
// ---------------------------------------------------------------------------
__global__ __launch_bounds__(256)
void mfma_gemm(const ushort_t* __restrict__ A, long a_rs,
               const ushort_t* __restrict__ W, int K, int Nreal,
               void* __restrict__ outv, long o_rs,
               const float* __restrict__ aux, int epi, int mbase,
               const float* __restrict__ p1, const float* __restrict__ p2,
               const float* __restrict__ rm, const float* __restrict__ rv,
               const float* __restrict__ gg, const float* __restrict__ be,
               ushort_t* __restrict__ out2, float* __restrict__ sums)
{
    __shared__ ushort_t As[128 * 32];
    __shared__ ushort_t Bs[128 * 32];
    __shared__ float red[256];

    const int tid  = threadIdx.x;
    const int wave = tid >> 6, lane = tid & 63;
    const int wm = wave >> 1, wn = wave & 1;
    const int tileM = blockIdx.y * 128, tileN = blockIdx.x * 128;

    f32x4 acc[4][4] = {};
    const int srow = lane >> 2;
    const int skb  = (lane & 3) * 8;

    for (int kt = 0; kt < K; kt += 32) {
        __syncthreads();
#pragma unroll
        for (int s = 0; s < 2; ++s) {
            const int instr = wave * 2 + s;
            const int row = instr * 16 + srow;
            ld16(A + (size_t)(tileM + row) * a_rs + kt + skb, &As[instr * 512]);
            ld16(W + (size_t)(tileN + row) * (size_t)K + kt + skb, &Bs[instr * 512]);
        }
        __syncthreads();
        const int lr = lane & 15;
        const int lk = (lane >> 4) * 8;
        short8 af[4], bfr[4];
#pragma unroll
        for (int i = 0; i < 4; ++i)
            af[i] = *(const short8*)&As[(wm * 64 + i * 16 + lr) * 32 + lk];
#pragma unroll
        for (int j = 0; j < 4; ++j)
            bfr[j] = *(const short8*)&Bs[(wn * 64 + j * 16 + lr) * 32 + lk];
#pragma unroll
        for (int i = 0; i < 4; ++i)
#pragma unroll
            for (int j = 0; j < 4; ++j)
                acc[i][j] = __builtin_amdgcn_mfma_f32_16x16x32_bf16(
                    af[i], bfr[j], acc[i][j], 0, 0, 0);
    }

    const int lr = lane & 15;
    const int rquad = (lane >> 4) * 4;
    float lsum = 0.f;
#pragma unroll
    for (int i = 0; i < 4; ++i) {
#pragma unroll
        for (int r = 0; r < 4; ++r) {
            const int grow = tileM + wm * 64 + i * 16 + rquad + r;
#pragma unroll
            for (int j = 0; j < 4; ++j) {
                const int gcol = tileN + wn * 64 + j * 16 + lr;
                const float v = acc[i][j][r];
                if (epi == 0) {
                    ((float*)outv)[(size_t)grow * o_rs + gcol] = v + p1[gcol] + p2[gcol];
                } else if (epi == 2) {
                    float o = 0.f;
                    if (gcol < Nreal) {
                        const float s = gg[gcol] * rsqrtf(rv[gcol] + EPSBN);
                        o = (v + p1[gcol] - rm[gcol]) * s + be[gcol];
                    }
                    ((ushort_t*)outv)[(size_t)grow * o_rs + gcol] = f2bf(o);
                } else { // epi 5
                    const float s = gg[gcol] * rsqrtf(rv[gcol] + EPSBN);
                    const float o = (v + p1[gcol] - rm[gcol]) * s + be[gcol];
                    const int gm = mbase + grow;
                    const int b = gm >> 6, tau = gm & 63;
                    if (tau < 63) {
                        const float d = o - aux[((size_t)b * TT + tau + 1) * FF + gcol];
                        lsum += d * d;
                    } else {
                        out2[(size_t)b * FF + gcol] = f2bf(o);
                    }
                }
            }
        }
    }
    if (epi == 5) {
        red[tid] = lsum;
        __syncthreads();
        for (int o = 128; o > 0; o >>= 1) {
            if (tid < o) red[tid] += red[tid + o];
            __syncthreads();
        }
        if (tid == 0) atomicAdd(&sums[0], red[0]);
    }
}

// ---------------------------------------------------------------------------
// Persistent recurrence: 32 blocks x 16 batch rows. 3-slot W prefetch ring
// (2 chunks ahead), XW register prefetch, fast tanh. 1 barrier/step.
// ---------------------------------------------------------------------------
__global__ __launch_bounds__(256)
void rnn_persistent(const ushort_t* __restrict__ Whh,
                    const float* __restrict__ XW,
                    ushort_t* __restrict__ hs)
{
    __shared__ ushort_t hb[2][16 * HP];
    const int tid = threadIdx.x, wave = tid >> 6, lane = tid & 63;
    const int b0 = blockIdx.x * 16;
    const int lr = lane & 15, lq = lane >> 4;
    const int c0 = wave * 128;

    // t = 0: h = tanh(XW_0)
    for (int it = 0; it < 8; ++it) {
        const int e = (it * 256 + tid) * 4;
        const int row = e >> 9, col = e & 511;
        const size_t gi = ((size_t)(b0 + row) * TN) * FF + col;
        const float4 v = *(const float4*)&XW[gi];
        const ushort_t h0 = f2bf(ftanh(v.x)), h1 = f2bf(ftanh(v.y));
        const ushort_t h2 = f2bf(ftanh(v.z)), h3 = f2bf(ftanh(v.w));
        hb[0][row * HP + col + 0] = h0; hb[0][row * HP + col + 1] = h1;
        hb[0][row * HP + col + 2] = h2; hb[0][row * HP + col + 3] = h3;
        unsigned r0 = (unsigned)h0 | ((unsigned)h1 << 16);
        unsigned r1 = (unsigned)h2 | ((unsigned)h3 << 16);
        *(uint2*)&hs[gi] = make_uint2(r0, r1);
    }
    __syncthreads();

    f32x4 acc[8];
    short8 wf[3][8];
    short8 af[3];
    float xw[8][4];

    for (int t = 1; t < TN; ++t) {
        const ushort_t* hcur = hb[(t - 1) & 1];

        // prologue: chunks 0,1 into slots 0,1
#pragma unroll
        for (int s = 0; s < 2; ++s) {
            const int kk = s * 32 + lq * 8;
            af[s] = *(const short8*)&hcur[lr * HP + kk];
#pragma unroll
            for (int j = 0; j < 8; ++j)
                wf[s][j] = *(const short8*)(Whh + (size_t)(c0 + j * 16 + lr) * FF + kk);
        }
        // XW register prefetch for this step (HBM; overlaps the K-loop)
#pragma unroll
        for (int j = 0; j < 8; ++j)
#pragma unroll
            for (int r = 0; r < 4; ++r)
                xw[j][r] = XW[((size_t)(b0 + lq * 4 + r) * TN + t) * FF
                              + c0 + j * 16 + lr];
#pragma unroll
        for (int j = 0; j < 8; ++j) acc[j] = (f32x4){0.f, 0.f, 0.f, 0.f};

#pragma unroll
        for (int kc = 0; kc < 16; ++kc) {
            if (kc + 2 < 16) {
                const int slot = (kc + 2) % 3;
                const int kk = (kc + 2) * 32 + lq * 8;
                af[slot] = *(const short8*)&hcur[lr * HP + kk];
#pragma unroll
                for (int j = 0; j < 8; ++j)
                    wf[slot][j] = *(const short8*)
                        (Whh + (size_t)(c0 + j * 16 + lr) * FF + kk);
            }
            const int b = kc % 3;
#pragma unroll
            for (int j = 0; j < 8; ++j)
                acc[j] = __builtin_amdgcn_mfma_f32_16x16x32_bf16(
                    af[b], wf[b][j], acc[j], 0, 0, 0);
        }

        ushort_t* hnxt = hb[t & 1];
#pragma unroll
        for (int j = 0; j < 8; ++j) {
            const int col = c0 + j * 16 + lr;
#pragma unroll
            for (int r = 0; r < 4; ++r) {
                const int row = lq * 4 + r;
                const size_t gi = ((size_t)(b0 + row) * TN + t) * FF + col;
                const ushort_t hv = f2bf(ftanh(acc[j][r] + xw[j][r]));
                hnxt[row * HP + col] = hv;
                hs[gi] = hv;
            }
        }
        __syncthreads();
    }
}

// ---------------------------------------------------------------------------
// Producer/consumer sync primitives (decode).
// ---------------------------------------------------------------------------
__device__ __forceinline__ void poll_ge(unsigned* __restrict__ w, unsigned tgt)
{
    while (__hip_atomic_fetch_add(w, 0u, __ATOMIC_RELAXED,
                                  __HIP_MEMORY_SCOPE_AGENT) < tgt)
        __builtin_amdgcn_s_sleep(1);
}

// consumer: poll OWN inbox line (<=8 pollers share it), then one acquire
__device__ __forceinline__ void wait_inbox(unsigned* __restrict__ line,
                                           unsigned epoch)
{
    if (threadIdx.x == 0) {
        poll_ge(line, epoch);
        (void)__hip_atomic_load(line, __ATOMIC_ACQUIRE, __HIP_MEMORY_SCOPE_AGENT);
    }
    __syncthreads();
}

// producer: hierarchical arrive; last master arriver broadcasts epoch to
// nlines inbox lines (128 B apart).
__device__ __forceinline__ void arrive_h(unsigned* __restrict__ sub,
                                         unsigned subtgt,
                                         unsigned* __restrict__ master,
                                         unsigned mtgt, unsigned epoch,
                                         unsigned* __restrict__ lines,
                                         int nlines)
{
    __syncthreads();
    if (threadIdx.x == 0) {
        const unsigned so = __hip_atomic_fetch_add(sub, 1u, __ATOMIC_RELEASE,
                                                   __HIP_MEMORY_SCOPE_AGENT);
        if (so == subtgt - 1u) {
            const unsigned mo = __hip_atomic_fetch_add(master, 8u,
                                                       __ATOMIC_RELEASE,
                                                       __HIP_MEMORY_SCOPE_AGENT);
            if (mo == mtgt - 8u) {
                for (int i = 0; i < nlines; ++i)
                    __hip_atomic_store(lines + i * 32, epoch, __ATOMIC_RELAXED,
                                       __HIP_MEMORY_SCOPE_AGENT);
            }
        }
    }
}

// load a weight slice (rows [n0,n0+rows) of W[*, K]) into LDS, row stride wrs
__device__ __forceinline__ void load_wslice(const ushort_t* __restrict__ W,
                                            int n0, int K, int rows,
                                            ushort_t* dst, int wrs)
{
    const int nch = K >> 3;
    const int total = rows * nch;
    for (int c = threadIdx.x; c < total; c += 256) {
        const int row = c / nch, col = (c - row * nch) * 8;
        *(uint4*)&dst[(size_t)row * wrs + col] =
            *(const uint4*)&W[(size_t)(n0 + row) * K + col];
    }
}

// fragment GEMM: acc[MT][4] over rows mrow0+mt*16, 64 cols (4 ntiles).
// PF-deep A-register ring (default 8: ~7 iterations of latency cover).
template <int MT, int NCH1, int NCH2, int PF = 8>
__device__ __forceinline__ void frag_gemm(
    const ushort_t* __restrict__ A1, long a1_rs,
    const ushort_t* __restrict__ A2, long a2_rs,
    const ushort_t* w1, const ushort_t* w2, int wrs,
    int mrow0, f32x4 (&acc)[MT][4])
{
    const int lane = threadIdx.x & 63;
    const int lr = lane & 15, lk = (lane >> 4) * 8;
    constexpr int NCH = NCH1 + NCH2;
    short8 a[PF][MT];

    auto aload = [&](int kc, int slot) {
        const bool p2 = (kc >= NCH1);
        const ushort_t* Ap = p2 ? A2 : A1;
        const long rs = p2 ? a2_rs : a1_rs;
        const int kk = (p2 ? kc - NCH1 : kc) * 32 + lk;
#pragma unroll
        for (int mt = 0; mt < MT; ++mt)
            a[slot][mt] = *(const short8*)(Ap + (size_t)(mrow0 + mt * 16 + lr) * rs + kk);
    };
#pragma unroll
    for (int p = 0; p < PF - 1; ++p) aload(p, p);
#pragma unroll
    for (int kc = 0; kc < NCH; ++kc) {
        if (kc + PF - 1 < NCH) aload(kc + PF - 1, (kc + PF - 1) % PF);
        const bool p2 = (kc >= NCH1);
        const ushort_t* wl = p2 ? w2 : w1;
        const int kk = (p2 ? kc - NCH1 : kc) * 32 + lk;
        short8 wfr[4];
#pragma unroll
        for (int nt = 0; nt < 4; ++nt)
            wfr[nt] = *(const short8*)&wl[(size_t)(nt * 16 + lr) * wrs + kk];
#pragma unroll
        for (int mt = 0; mt < MT; ++mt)
#pragma unroll
            for (int nt = 0; nt < 4; ++nt)
                acc[mt][nt] = __builtin_amdgcn_mfma_f32_16x16x32_bf16(
                    a[kc % PF][mt], wfr[nt], acc[mt][nt], 0, 0, 0);
    }
}

template <int MT>
__device__ __forceinline__ void ep_tanh(f32x4 (&acc)[MT][4], int mrow0, int gc0,
                                        const float* __restrict__ p1,
                                        const float* __restrict__ p2,
                                        ushort_t* __restrict__ obf, long o_rs)
{
    const int lane = threadIdx.x & 63;
    const int lr = lane & 15, rq = (lane >> 4) * 4;
#pragma unroll
    for (int mt = 0; mt < MT; ++mt)
#pragma unroll
        for (int nt = 0; nt < 4; ++nt) {
            const int gcol = gc0 + nt * 16 + lr;
            const float bb = p1[gcol] + p2[gcol];
#pragma unroll
            for (int r = 0; r < 4; ++r) {
                const int grow = mrow0 + mt * 16 + rq + r;
                obf[(size_t)grow * o_rs + gcol] = f2bf(ftanh(acc[mt][nt][r] + bb));
            }
        }
}

template <int MT>
__device__ __forceinline__ void ep_bn(f32x4 (&acc)[MT][4], int mrow0, int gc0,
                                      const float* __restrict__ b,
                                      const float* __restrict__ rm,
                                      const float* __restrict__ rv,
                                      const float* __restrict__ gg,
                                      const float* __restrict__ be,
                                      int Nreal,
                                      ushort_t* __restrict__ obf, long o_rs,
                                      float* __restrict__ of32)
{
    const int lane = threadIdx.x & 63;
    const int lr = lane & 15, rq = (lane >> 4) * 4;
#pragma unroll
    for (int mt = 0; mt < MT; ++mt)
#pragma unroll
        for (int nt = 0; nt < 4; ++nt) {
            const int gcol = gc0 + nt * 16 + lr;
            const bool ok = gcol < Nreal;
            const float s = ok ? gg[gcol] * rsqrtf(rv[gcol] + EPSBN) : 0.f;
            const float c = ok ? (b[gcol] - rm[gcol]) * s + be[gcol] : 0.f;
#pragma unroll
            for (int r = 0; r < 4; ++r) {
                const int grow = mrow0 + mt * 16 + rq + r;
                const float o = ok ? acc[mt][nt][r] * s + c : 0.f;
                obf[(size_t)grow * o_rs + gcol] = f2bf(o);
                if (of32) of32[(size_t)grow * o_rs + gcol] = o;
            }
        }
}

// ---------------------------------------------------------------------------
// Persistent decode: 224 stage-specialized blocks, weights resident in LDS.
// roles: [0,32) cell, [32,96) L1, [96,160) L2, [160,224) L3.
// ---------------------------------------------------------------------------
__global__ __launch_bounds__(256)
void decode_persistent(const ushort_t* __restrict__ seed,
                       const ushort_t* __restrict__ hs,
                       const ushort_t* __restrict__ Wih,
                       const ushort_t* __restrict__ Whh,
                       const ushort_t* __restrict__ W1b,
                       const ushort_t* __restrict__ W2b,
                       const ushort_t* __restrict__ W3b,
                       ushort_t* __restrict__ hdec,
                       ushort_t* __restrict__ zd1, ushort_t* __restrict__ zd2,
                       float* __restrict__ xg, ushort_t* __restrict__ xgb,
                       unsigned* __restrict__ cnt,
                       const float* __restrict__ b_ih, const float* __restrict__ b_hh,
                       const float* __restrict__ b1, const float* __restrict__ rm1,
                       const float* __restrict__ rv1, const float* __restrict__ g1,
                       const float* __restrict__ be1,
                       const float* __restrict__ b2, const float* __restrict__ rm2,
                       const float* __restrict__ rv2, const float* __restrict__ g2,
                       const float* __restrict__ be2,
                       const float* __restrict__ b3, const float* __restrict__ rm3,
                       const float* __restrict__ rv3, const float* __restrict__ g3,
                       const float* __restrict__ be3)
{
    __shared__ ushort_t wlds[66560];   // 133,120 B -> 1 block/CU
    const int id = blockIdx.x;
    const int wave = threadIdx.x >> 6;
    unsigned* master = cnt;            // + ev*64
    unsigned* subc   = cnt + 1024;     // + (ev*8  + sub)*32
    unsigned* inbox  = cnt + 2048;     // + (ev*16 + grp)*32

    if (id < 32) {
        // ---- cell role ----
        const int rg = id >> 3, cg = id & 7;
        unsigned* in_cell = inbox + (0 * 16 + 8 + (id >> 3)) * 32; // grp 8..11
        unsigned* in_l3   = inbox + (3 * 16 + (id >> 3)) * 32;     // grp 0..3
        load_wslice(Wih, cg * 64, FF, 64, wlds, HP);
        load_wslice(Whh, cg * 64, FF, 64, wlds + 64 * HP, HP);
        __syncthreads();
        const int m0 = rg * 128 + wave * 32;
        for (int g = 0; g < 16; ++g) {
            f32x4 acc[2][4] = {};
            // h-half: needs only previous cell output; overlaps prev gap's
            // L1/L2/L3 stages.
            if (g) wait_inbox(in_cell, (unsigned)g);
            const ushort_t* hprev = g ? (hdec + (size_t)((g - 1) & 1) * BF)
                                      : (hs + (size_t)63 * FF);
            const long h_rs = g ? (long)FF : (long)(TN * FF);
            frag_gemm<2, 16, 0>(hprev, h_rs, nullptr, 0,
                                wlds + 64 * HP, nullptr, HP, m0, acc);
            // x-half: critical path, released by L3 of previous gap.
            if (g) wait_inbox(in_l3, (unsigned)g);
            const ushort_t* xprev = g ? (xgb + (size_t)(g - 1) * BF) : seed;
            frag_gemm<2, 16, 0>(xprev, FF, nullptr, 0,
                                wlds, nullptr, HP, m0, acc);
            ushort_t* hnew = hdec + (size_t)(g & 1) * BF;
            ep_tanh<2>(acc, m0, cg * 64, b_ih, b_hh, hnew, FF);
            // broadcast cell_done -> L1 grps 0..7 + cell grps 8..11
            arrive_h(subc + (0 * 8 + (id >> 3)) * 32, 8u * (g + 1),
                     master + 0 * 64, 32u * (g + 1), (unsigned)(g + 1),
                     inbox + (0 * 16) * 32, 12);
        }
    } else if (id < 96) {
        // ---- L1 role ----
        const int lidx = id - 32;
        const int rg = lidx >> 3, cg = lidx & 7;
        unsigned* in_cell = inbox + (0 * 16 + (lidx >> 3)) * 32;
        load_wslice(W1b, cg * 128, FF, 128, wlds, HP);
        __syncthreads();
        for (int g = 0; g < 16; ++g) {
            wait_inbox(in_cell, (unsigned)(g + 1));
            const ushort_t* hnew = hdec + (size_t)(g & 1) * BF;
            const int m0 = rg * 64 + (wave >> 1) * 32;
            const int gc0 = cg * 128 + (wave & 1) * 64;
            f32x4 acc[2][4] = {};
            frag_gemm<2, 16, 0>(hnew, FF, nullptr, 0,
                                wlds + (wave & 1) * 64 * HP, nullptr, HP, m0, acc);
            ep_bn<2>(acc, m0, gc0, b1, rm1, rv1, g1, be1, HD, zd1, HDP, nullptr);
            arrive_h(subc + (1 * 8 + (lidx >> 3)) * 32, 8u * (g + 1),
                     master + 1 * 64, 64u * (g + 1), (unsigned)(g + 1),
                     inbox + (1 * 16) * 32, 8);
        }
    } else if (id < 160) {
        // ---- L2 role ----
        const int lidx = id - 96;
        const int rg = lidx >> 4, cg = lidx & 15;
        unsigned* in_l1 = inbox + (1 * 16 + (lidx >> 3)) * 32;
        load_wslice(W2b, cg * 64, HDP, 64, wlds, 1032);
        __syncthreads();
        for (int g = 0; g < 16; ++g) {
            wait_inbox(in_l1, (unsigned)(g + 1));
            const int m0 = rg * 128 + wave * 32;
            f32x4 acc[2][4] = {};
            frag_gemm<2, 32, 0>(zd1, HDP, nullptr, 0,
                                wlds, nullptr, 1032, m0, acc);
            ep_bn<2>(acc, m0, cg * 64, b2, rm2, rv2, g2, be2, HD, zd2, HDP, nullptr);
            arrive_h(subc + (2 * 8 + (lidx >> 3)) * 32, 8u * (g + 1),
                     master + 2 * 64, 64u * (g + 1), (unsigned)(g + 1),
                     inbox + (2 * 16) * 32, 8);
        }
    } else {
        // ---- L3 role ----
        const int lidx = id - 160;
        const int rg = lidx >> 3, cg = lidx & 7;
        unsigned* in_l2 = inbox + (2 * 16 + (lidx >> 3)) * 32;
        load_wslice(W3b, cg * 64, HDP, 64, wlds, 1032);
        __syncthreads();
        for (int g = 0; g < 16; ++g) {
            wait_inbox(in_l2, (unsigned)(g + 1));
            const int m0 = rg * 64 + wave * 16;
            f32x4 acc[1][4] = {};
            frag_gemm<1, 32, 0>(zd2, HDP, nullptr, 0,
                                wlds, nullptr, 1032, m0, acc);
            ep_bn<1>(acc, m0, cg * 64, b3, rm3, rv3, g3, be3, FF,
                     xgb + (size_t)g * BF, FF, xg + (size_t)g * BF);
            // broadcast l3_done -> cell grps 0..3 (releases next gap's x-half)
            arrive_h(subc + (3 * 8 + (lidx >> 3)) * 32, 8u * (g + 1),
                     master + 3 * 64, 64u * (g + 1), (unsigned)(g + 1),
                     inbox + (3 * 16) * 32, 4);
        }
    }
}

// ---------------------------------------------------------------------------
__global__ void zero_init(float* __restrict__ sums, unsigned* __restrict__ cnt)
{
    const int i = threadIdx.x + blockIdx.x * blockDim.x;
    if (i < 2) sums[i] = 0.f;
    for (int k = i; k < SYNC_WORDS; k += blockDim.x * gridDim.x) cnt[k] = 0u;
}

__global__ void conv_x(const float* __restrict__ x, ushort_t* __restrict__ xb)
{
    const int i = blockIdx.x * blockDim.x + threadIdx.x;
    if (i < MALL * FF / 4) {
        const int e = i * 4;
        const int m = e >> 9;
        const int f = e & (FF - 1);
        const int b = m >> 6, t = m & 63;
        const float4 v = *(const float4*)&x[((size_t)b * TT + t) * FF + f];
        unsigned r0 = (unsigned)f2bf(v.x) | ((unsigned)f2bf(v.y) << 16);
        unsigned r1 = (unsigned)f2bf(v.z) | ((unsigned)f2bf(v.w) << 16);
        *(uint2*)&xb[e] = make_uint2(r0, r1);
    }
}

__global__ void conv_w(const float* __restrict__ src, ushort_t* __restrict__ dst,
                       int Nsrc, int Ksrc, int Npad, int Kpad)
{
    const int i = blockIdx.x * blockDim.x + threadIdx.x;
    if (i < Npad * Kpad) {
        const int n = i / Kpad, k = i - n * Kpad;
        const float v = (n < Nsrc && k < Ksrc) ? src[(size_t)n * Ksrc + k] : 0.f;
        dst[i] = f2bf(v);
    }
}

__global__ void gather_kernel(const float* __restrict__ xgaps,
                              const int* __restrict__ tgap,
                              const float* __restrict__ x,
                              float* __restrict__ out,
                              float* __restrict__ sums)
{
    const int i = blockIdx.x * blockDim.x + threadIdx.x;
    float s = 0.f;
    if (i < BF) {
        const int b = i >> 9, f = i & (FF - 1);
        const int g = tgap[b] - 1;
        const float v = xgaps[((size_t)g * BB + b) * FF + f];
        out[i] = v;
        const float d = v - x[((size_t)b * TT + (TT - 1)) * FF + f];
        s = d * d;
    }
    __shared__ float red[256];
    red[threadIdx.x] = s;
    __syncthreads();
    for (int o = 128; o > 0; o >>= 1) {
        if (threadIdx.x < o) red[threadIdx.x] += red[threadIdx.x + o];
        __syncthreads();
    }
    if (threadIdx.x == 0) atomicAdd(&sums[1], red[0]);
}

__global__ void finalize_kernel(const float* __restrict__ sums,
                                float* __restrict__ out)
{
    if (threadIdx.x == 0 && blockIdx.x == 0) {
        const double n1 = 63.0 * 512.0 * 512.0;
        const double n2 = 512.0 * 512.0;
        out[BF] = (float)((double)sums[0] / (n1 * n1) +
                          (double)sums[1] / (n2 * n2));
    }
}

extern "C" void kernel_launch(void* const* d_in, const int* in_sizes, int n_in,
                              void* d_out, int out_size, void* d_ws, size_t ws_size,
                              hipStream_t stream)
{
    const float* x    = (const float*)d_in[0];
    const int*   tgap = (const int*)d_in[1];
    const float* W_ih = (const float*)d_in[2];
    const float* W_hh = (const float*)d_in[3];
    const float* b_ih = (const float*)d_in[4];
    const float* b_hh = (const float*)d_in[5];
    const float* W1 = (const float*)d_in[6];
    const float* b1 = (const float*)d_in[7];
    const float* g1 = (const float*)d_in[8];
    const float* be1 = (const float*)d_in[9];
    const float* rm1 = (const float*)d_in[10];
    const float* rv1 = (const float*)d_in[11];
    const float* W2 = (const float*)d_in[12];
    const float* b2 = (const float*)d_in[13];
    const float* g2 = (const float*)d_in[14];
    const float* be2 = (const float*)d_in[15];
    const float* rm2 = (const float*)d_in[16];
    const float* rv2 = (const float*)d_in[17];
    const float* W3 = (const float*)d_in[18];
    const float* b3 = (const float*)d_in[19];
    const float* g3 = (const float*)d_in[20];
    const float* be3 = (const float*)d_in[21];
    const float* rm3 = (const float*)d_in[22];
    const float* rv3 = (const float*)d_in[23];
    float* out = (float*)d_out;

    char* p = (char*)d_ws;
    auto take = [&](size_t bytes) -> char* {
        char* r = p; p += (bytes + 63) & ~(size_t)63; return r;
    };
    float*    XWbuf = (float*)take((size_t)MALL * FF * 4);      // 67.1 MB
    ushort_t* hs    = (ushort_t*)take((size_t)MALL * FF * 2);   // 33.5 MB
    ushort_t* xbf   = (ushort_t*)take((size_t)MALL * FF * 2);   // 33.5 MB
    ushort_t* z1    = (ushort_t*)take((size_t)CM * HDP * 2);    // 16.8 MB
    ushort_t* z2    = (ushort_t*)take((size_t)CM * HDP * 2);    // 16.8 MB
    float*    xg    = (float*)take((size_t)16 * BF * 4);        // 16.8 MB
    ushort_t* xgb   = (ushort_t*)take((size_t)16 * BF * 2);     //  8.4 MB
    ushort_t* seed  = (ushort_t*)take((size_t)BF * 2);
    ushort_t* hdec  = (ushort_t*)take((size_t)2 * BF * 2);
    ushort_t* zd1   = (ushort_t*)take((size_t)BB * HDP * 2);
    ushort_t* zd2   = (ushort_t*)take((size_t)BB * HDP * 2);
    ushort_t* Wihb  = (ushort_t*)take((size_t)FF * FF * 2);
    ushort_t* Whhb  = (ushort_t*)take((size_t)FF * FF * 2);
    ushort_t* W1b   = (ushort_t*)take((size_t)HDP * FF * 2);
    ushort_t* W2b   = (ushort_t*)take((size_t)HDP * HDP * 2);
    ushort_t* W3b   = (ushort_t*)take((size_t)FF * HDP * 2);
    float*    sums  = (float*)take(16 * 4);
    unsigned* cnt   = (unsigned*)take((size_t)SYNC_WORDS * 4);

    const dim3 blk(256);

    zero_init<<<dim3(2), blk, 0, stream>>>(sums, cnt);
    conv_x<<<dim3(MALL * FF / 4 / 256), blk, 0, stream>>>(x, xbf);
    conv_w<<<dim3((FF * FF + 255) / 256), blk, 0, stream>>>(W_ih, Wihb, FF, FF, FF, FF);
    conv_w<<<dim3((FF * FF + 255) / 256), blk, 0, stream>>>(W_hh, Whhb, FF, FF, FF, FF);
    conv_w<<<dim3((HDP * FF + 255) / 256), blk, 0, stream>>>(W1, W1b, HD, FF, HDP, FF);
    conv_w<<<dim3((HDP * HDP + 255) / 256), blk, 0, stream>>>(W2, W2b, HD, HD, HDP, HDP);
    conv_w<<<dim3((FF * HDP + 255) / 256), blk, 0, stream>>>(W3, W3b, FF, HD, FF, HDP);

    // 1) XW = x @ W_ih^T + b_ih + b_hh -> fp32
    mfma_gemm<<<dim3(FF / 128, MALL / 128), blk, 0, stream>>>(
        xbf, FF, Wihb, FF, FF, XWbuf, FF, nullptr, 0, 0,
        b_ih, b_hh, nullptr, nullptr, nullptr, nullptr, nullptr, nullptr);

    // 2) recurrence (persistent, batch-split, register W-stream)
    rnn_persistent<<<dim3(BB / 16), blk, 0, stream>>>(Whhb, XWbuf, hs);

    // 3) autoenc over 32768 rows in 4 chunks
    for (int c = 0; c < CH; ++c) {
        const ushort_t* Ac = hs + (size_t)c * CM * FF;
        mfma_gemm<<<dim3(HDP / 128, CM / 128), blk, 0, stream>>>(
            Ac, FF, W1b, FF, HD, z1, HDP, nullptr, 2, 0,
            b1, nullptr, rm1, rv1, g1, be1, nullptr, nullptr);
        mfma_gemm<<<dim3(HDP / 128, CM / 128), blk, 0, stream>>>(
            z1, HDP, W2b, HDP, HD, z2, HDP, nullptr, 2, 0,
            b2, nullptr, rm2, rv2, g2, be2, nullptr, nullptr);
        mfma_gemm<<<dim3(FF / 128, CM / 128), blk, 0, stream>>>(
            z2, HDP, W3b, HDP, FF, nullptr, 0, x, 5, c * CM,
            b3, nullptr, rm3, rv3, g3, be3, seed, sums);
    }

    // 4) decode (persistent, stage-specialized, inbox-broadcast handoffs)
    decode_persistent<<<dim3(DNB), blk, 0, stream>>>(
        seed, hs, Wihb, Whhb, W1b, W2b, W3b,
        hdec, zd1, zd2, xg, xgb, cnt,
        b_ih, b_hh,
        b1, rm1, rv1, g1, be1,
        b2, rm2, rv2, g2, be2,
        b3, rm3, rv3, g3, be3);

    // 5) gather + finalize
    gather_kernel<<<dim3(BF / 256), blk, 0, stream>>>(xg, tgap, x, out, sums);
    finalize_kernel<<<dim3(1), dim3(64), 0, stream>>>(sums, out);
}

// Round 2
// 1984.982 us; speedup vs baseline: 1.0964x; 1.0092x over previous
//
#include <hip/hip_runtime.h>
#include <math.h>

// forecastRNN on MI355X, round 8.
// Decode handoff: FINE-GRAINED DIRECT-INBOX sync. The stage dependency
// structure is row-aligned (L1 rg1 needs only cell group rg1>>1, L2 rg2
// needs only L1 groups {2rg2,2rg2+1}, L3 rg3 needs only L2 group rg3>>1,
// cell-x rg needs only L3 groups {2rg,2rg+1}), so each producer does ONE
// release fetch_add directly on the consumer row-group's inbox line and
// each consumer polls ONE line for 8*(g+1) / 16*(g+1). This removes the
// round-7 sub->master->broadcast chain (3 serial L3 round-trips) and
// shrinks each wait set from 64 producers to the 8-16 actually read.
// WAR on single-buffered zd1/zd2 remains safe: per-row-range chains
// cell->L1->L2->L3->cell are transitively ordered.
// Also: BN scale/shift + bias constants hoisted out of the 16-gap loop
// (they were re-fetched through L3 after every acquire-invalidate).
// RNN / large-GEMM / conversion kernels unchanged.

typedef unsigned short ushort_t;
typedef __attribute__((ext_vector_type(8))) short short8;
typedef __attribute__((ext_vector_type(4))) float f32x4;

#define BB 512
#define TT 65
#define TN 64
#define FF 512
#define HD 1000
#define HDP 1024
#define EPSBN 1e-5f
#define BF (BB*FF)          // 262144
#define MALL (BB*TN)        // 32768
#define CH 4
#define CM (MALL/CH)        // 8192
#define HP 520              // LDS h row stride (1040 B)
#define DNB 224

// sync lines in cnt[]: line(ev, rg) = cnt + (ev*4 + rg)*64   (256 B apart)
// ev: 0=cell_done 1=l1_done 2=l2_done 3=l3_done; rg in [0,4)
#define SYNC_WORDS 4096

__device__ __forceinline__ ushort_t f2bf(float f) {
    union { float f; unsigned u; } v; v.f = f;
    unsigned r = v.u + 0x7FFFu + ((v.u >> 16) & 1u);
    return (ushort_t)(r >> 16);
}

__device__ __forceinline__ float ftanh(float x) {
    const float e = __expf(2.f * x);
    return 1.f - 2.f / (e + 1.f);
}

__device__ __forceinline__ void ld16(const ushort_t* g, ushort_t* l) {
    __builtin_amdgcn_global_load_lds(
        (const __attribute__((address_space(1))) unsigned*)g,
        (__attribute__((address_space(3))) unsigned*)l, 16, 0, 0);
}

// ---------------------------------------------------------------------------
// Large-GEMM kernel (XW precompute + autoenc), 128x128 tile, BK=32.
// ---------------------------------------------------------------------------
__global__ __launch_bounds__(256)
void mfma_gemm(const ushort_t* __restrict__ A, long a_rs,
               const ushort_t* __restrict__ W, int K, int Nreal,
               void* __restrict__ outv, long o_rs,
               const float* __restrict__ aux, int epi, int mbase,
               const float* __restrict__ p1, const float* __restrict__ p2,
               const float* __restrict__ rm, const float* __restrict__ rv,
               const float* __restrict__ gg, const float* __restrict__ be,
               ushort_t* __restrict__ out2, float* __restrict__ sums)
{
    __shared__ ushort_t As[128 * 32];
    __shared__ ushort_t Bs[128 * 32];
    __shared__ float red[256];

    const int tid  = threadIdx.x;
    const int wave = tid >> 6, lane = tid & 63;
    const int wm = wave >> 1, wn = wave & 1;
    const int tileM = blockIdx.y * 128, tileN = blockIdx.x * 128;

    f32x4 acc[4][4] = {};
    const int srow = lane >> 2;
    const int skb  = (lane & 3) * 8;

    for (int kt = 0; kt < K; kt += 32) {
        __syncthreads();
#pragma unroll
        for (int s = 0; s < 2; ++s) {
            const int instr = wave * 2 + s;
            const int row = instr * 16 + srow;
            ld16(A + (size_t)(tileM + row) * a_rs + kt + skb, &As[instr * 512]);
            ld16(W + (size_t)(tileN + row) * (size_t)K + kt + skb, &Bs[instr * 512]);
        }
        __syncthreads();
        const int lr = lane & 15;
        const int lk = (lane >> 4) * 8;
        short8 af[4], bfr[4];
#pragma unroll
        for (int i = 0; i < 4; ++i)
            af[i] = *(const short8*)&As[(wm * 64 + i * 16 + lr) * 32 + lk];
#pragma unroll
        for (int j = 0; j < 4; ++j)
            bfr[j] = *(const short8*)&Bs[(wn * 64 + j * 16 + lr) * 32 + lk];
#pragma unroll
        for (int i = 0; i < 4; ++i)
#pragma unroll
            for (int j = 0; j < 4; ++j)
                acc[i][j] = __builtin_amdgcn_mfma_f32_16x16x32_bf16(
                    af[i], bfr[j], acc[i][j], 0, 0, 0);
    }

    const int lr = lane & 15;
    const int rquad = (lane >> 4) * 4;
    float lsum = 0.f;
#pragma unroll
    for (int i = 0; i < 4; ++i) {
#pragma unroll
        for (int r = 0; r < 4; ++r) {
            const int grow = tileM + wm * 64 + i * 16 + rquad + r;
#pragma unroll
            for (int j = 0; j < 4; ++j) {
                const int gcol = tileN + wn * 64 + j * 16 + lr;
                const float v = acc[i][j][r];
                if (epi == 0) {
                    ((float*)outv)[(size_t)grow * o_rs + gcol] = v + p1[gcol] + p2[gcol];
                } else if (epi == 2) {
                    float o = 0.f;
                    if (gcol < Nreal) {
                        const float s = gg[gcol] * rsqrtf(rv[gcol] + EPSBN);
                        o = (v + p1[gcol] - rm[gcol]) * s + be[gcol];
                    }
                    ((ushort_t*)outv)[(size_t)grow * o_rs + gcol] = f2bf(o);
                } else { // epi 5
                    const float s = gg[gcol] * rsqrtf(rv[gcol] + EPSBN);
                    const float o = (v + p1[gcol] - rm[gcol]) * s + be[gcol];
                    const int gm = mbase + grow;
                    const int b = gm >> 6, tau = gm & 63;
                    if (tau < 63) {
                        const float d = o - aux[((size_t)b * TT + tau + 1) * FF + gcol];
                        lsum += d * d;
                    } else {
                        out2[(size_t)b * FF + gcol] = f2bf(o);
                    }
                }
            }
        }
    }
    if (epi == 5) {
        red[tid] = lsum;
        __syncthreads();
        for (int o = 128; o > 0; o >>= 1) {
            if (tid < o) red[tid] += red[tid + o];
            __syncthreads();
        }
        if (tid == 0) atomicAdd(&sums[0], red[0]);
    }
}

// ---------------------------------------------------------------------------
// Persistent recurrence: 32 blocks x 16 batch rows. 3-slot W prefetch ring
// (2 chunks ahead), XW register prefetch, fast tanh. 1 barrier/step.
// ---------------------------------------------------------------------------
__global__ __launch_bounds__(256)
void rnn_persistent(const ushort_t* __restrict__ Whh,
                    const float* __restrict__ XW,
                    ushort_t* __restrict__ hs)
{
    __shared__ ushort_t hb[2][16 * HP];
    const int tid = threadIdx.x, wave = tid >> 6, lane = tid & 63;
    const int b0 = blockIdx.x * 16;
    const int lr = lane & 15, lq = lane >> 4;
    const int c0 = wave * 128;

    // t = 0: h = tanh(XW_0)
    for (int it = 0; it < 8; ++it) {
        const int e = (it * 256 + tid) * 4;
        const int row = e >> 9, col = e & 511;
        const size_t gi = ((size_t)(b0 + row) * TN) * FF + col;
        const float4 v = *(const float4*)&XW[gi];
        const ushort_t h0 = f2bf(ftanh(v.x)), h1 = f2bf(ftanh(v.y));
        const ushort_t h2 = f2bf(ftanh(v.z)), h3 = f2bf(ftanh(v.w));
        hb[0][row * HP + col + 0] = h0; hb[0][row * HP + col + 1] = h1;
        hb[0][row * HP + col + 2] = h2; hb[0][row * HP + col + 3] = h3;
        unsigned r0 = (unsigned)h0 | ((unsigned)h1 << 16);
        unsigned r1 = (unsigned)h2 | ((unsigned)h3 << 16);
        *(uint2*)&hs[gi] = make_uint2(r0, r1);
    }
    __syncthreads();

    f32x4 acc[8];
    short8 wf[3][8];
    short8 af[3];
    float xw[8][4];

    for (int t = 1; t < TN; ++t) {
        const ushort_t* hcur = hb[(t - 1) & 1];

        // prologue: chunks 0,1 into slots 0,1
#pragma unroll
        for (int s = 0; s < 2; ++s) {
            const int kk = s * 32 + lq * 8;
            af[s] = *(const short8*)&hcur[lr * HP + kk];
#pragma unroll
            for (int j = 0; j < 8; ++j)
                wf[s][j] = *(const short8*)(Whh + (size_t)(c0 + j * 16 + lr) * FF + kk);
        }
        // XW register prefetch for this step (HBM; overlaps the K-loop)
#pragma unroll
        for (int j = 0; j < 8; ++j)
#pragma unroll
            for (int r = 0; r < 4; ++r)
                xw[j][r] = XW[((size_t)(b0 + lq * 4 + r) * TN + t) * FF
                              + c0 + j * 16 + lr];
#pragma unroll
        for (int j = 0; j < 8; ++j) acc[j] = (f32x4){0.f, 0.f, 0.f, 0.f};

#pragma unroll
        for (int kc = 0; kc < 16; ++kc) {
            if (kc + 2 < 16) {
                const int slot = (kc + 2) % 3;
                const int kk = (kc + 2) * 32 + lq * 8;
                af[slot] = *(const short8*)&hcur[lr * HP + kk];
#pragma unroll
                for (int j = 0; j < 8; ++j)
                    wf[slot][j] = *(const short8*)
                        (Whh + (size_t)(c0 + j * 16 + lr) * FF + kk);
            }
            const int b = kc % 3;
#pragma unroll
            for (int j = 0; j < 8; ++j)
                acc[j] = __builtin_amdgcn_mfma_f32_16x16x32_bf16(
                    af[b], wf[b][j], acc[j], 0, 0, 0);
        }

        ushort_t* hnxt = hb[t & 1];
#pragma unroll
        for (int j = 0; j < 8; ++j) {
            const int col = c0 + j * 16 + lr;
#pragma unroll
            for (int r = 0; r < 4; ++r) {
                const int row = lq * 4 + r;
                const size_t gi = ((size_t)(b0 + row) * TN + t) * FF + col;
                const ushort_t hv = f2bf(ftanh(acc[j][r] + xw[j][r]));
                hnxt[row * HP + col] = hv;
                hs[gi] = hv;
            }
        }
        __syncthreads();
    }
}

// ---------------------------------------------------------------------------
// Producer/consumer sync primitives (decode). Single-hop direct inbox:
// producer release-RMW on the consumer group's line; consumer RMW-polls
// its one line (fetch_add 0 executes at the coherence point -> never stale).
// ---------------------------------------------------------------------------
__device__ __forceinline__ void wait_line(unsigned* __restrict__ line,
                                          unsigned tgt)
{
    if (threadIdx.x == 0) {
        while (__hip_atomic_fetch_add(line, 0u, __ATOMIC_RELAXED,
                                      __HIP_MEMORY_SCOPE_AGENT) < tgt)
            __builtin_amdgcn_s_sleep(1);
        (void)__hip_atomic_load(line, __ATOMIC_ACQUIRE, __HIP_MEMORY_SCOPE_AGENT);
    }
    __syncthreads();
}

__device__ __forceinline__ void arrive_line(unsigned* __restrict__ line)
{
    __syncthreads();
    if (threadIdx.x == 0)
        __hip_atomic_fetch_add(line, 1u, __ATOMIC_RELEASE,
                               __HIP_MEMORY_SCOPE_AGENT);
}

// load a weight slice (rows [n0,n0+rows) of W[*, K]) into LDS, row stride wrs
__device__ __forceinline__ void load_wslice(const ushort_t* __restrict__ W,
                                            int n0, int K, int rows,
                                            ushort_t* dst, int wrs)
{
    const int nch = K >> 3;
    const int total = rows * nch;
    for (int c = threadIdx.x; c < total; c += 256) {
        const int row = c / nch, col = (c - row * nch) * 8;
        *(uint4*)&dst[(size_t)row * wrs + col] =
            *(const uint4*)&W[(size_t)(n0 + row) * K + col];
    }
}

// fragment GEMM: acc[MT][4] over rows mrow0+mt*16, 64 cols (4 ntiles).
// PF-deep A-register ring (~PF-1 iterations of latency cover).
template <int MT, int NCH1, int NCH2, int PF = 8>
__device__ __forceinline__ void frag_gemm(
    const ushort_t* __restrict__ A1, long a1_rs,
    const ushort_t* __restrict__ A2, long a2_rs,
    const ushort_t* w1, const ushort_t* w2, int wrs,
    int mrow0, f32x4 (&acc)[MT][4])
{
    const int lane = threadIdx.x & 63;
    const int lr = lane & 15, lk = (lane >> 4) * 8;
    constexpr int NCH = NCH1 + NCH2;
    short8 a[PF][MT];

    auto aload = [&](int kc, int slot) {
        const bool p2 = (kc >= NCH1);
        const ushort_t* Ap = p2 ? A2 : A1;
        const long rs = p2 ? a2_rs : a1_rs;
        const int kk = (p2 ? kc - NCH1 : kc) * 32 + lk;
#pragma unroll
        for (int mt = 0; mt < MT; ++mt)
            a[slot][mt] = *(const short8*)(Ap + (size_t)(mrow0 + mt * 16 + lr) * rs + kk);
    };
#pragma unroll
    for (int p = 0; p < PF - 1; ++p) aload(p, p);
#pragma unroll
    for (int kc = 0; kc < NCH; ++kc) {
        if (kc + PF - 1 < NCH) aload(kc + PF - 1, (kc + PF - 1) % PF);
        const bool p2 = (kc >= NCH1);
        const ushort_t* wl = p2 ? w2 : w1;
        const int kk = (p2 ? kc - NCH1 : kc) * 32 + lk;
        short8 wfr[4];
#pragma unroll
        for (int nt = 0; nt < 4; ++nt)
            wfr[nt] = *(const short8*)&wl[(size_t)(nt * 16 + lr) * wrs + kk];
#pragma unroll
        for (int mt = 0; mt < MT; ++mt)
#pragma unroll
            for (int nt = 0; nt < 4; ++nt)
                acc[mt][nt] = __builtin_amdgcn_mfma_f32_16x16x32_bf16(
                    a[kc % PF][mt], wfr[nt], acc[mt][nt], 0, 0, 0);
    }
}

// epilogues with hoisted per-block constants (bb / s,c computed once per
// block outside the 16-gap loop, not re-fetched through L3 every stage).
template <int MT>
__device__ __forceinline__ void ep_tanh_pre(f32x4 (&acc)[MT][4], int mrow0,
                                            int gc0, const float (&bb)[4],
                                            ushort_t* __restrict__ obf, long o_rs)
{
    const int lane = threadIdx.x & 63;
    const int lr = lane & 15, rq = (lane >> 4) * 4;
#pragma unroll
    for (int mt = 0; mt < MT; ++mt)
#pragma unroll
        for (int nt = 0; nt < 4; ++nt) {
            const int gcol = gc0 + nt * 16 + lr;
#pragma unroll
            for (int r = 0; r < 4; ++r) {
                const int grow = mrow0 + mt * 16 + rq + r;
                obf[(size_t)grow * o_rs + gcol] = f2bf(ftanh(acc[mt][nt][r] + bb[nt]));
            }
        }
}

template <int MT>
__device__ __forceinline__ void ep_bn_pre(f32x4 (&acc)[MT][4], int mrow0,
                                          int gc0, const float (&s)[4],
                                          const float (&c)[4],
                                          ushort_t* __restrict__ obf, long o_rs,
                                          float* __restrict__ of32)
{
    const int lane = threadIdx.x & 63;
    const int lr = lane & 15, rq = (lane >> 4) * 4;
#pragma unroll
    for (int mt = 0; mt < MT; ++mt)
#pragma unroll
        for (int nt = 0; nt < 4; ++nt) {
            const int gcol = gc0 + nt * 16 + lr;
#pragma unroll
            for (int r = 0; r < 4; ++r) {
                const int grow = mrow0 + mt * 16 + rq + r;
                const float o = acc[mt][nt][r] * s[nt] + c[nt];
                obf[(size_t)grow * o_rs + gcol] = f2bf(o);
                if (of32) of32[(size_t)grow * o_rs + gcol] = o;
            }
        }
}

// ---------------------------------------------------------------------------
// Persistent decode: 224 stage-specialized blocks, weights resident in LDS.
// roles: [0,32) cell, [32,96) L1, [96,160) L2, [160,224) L3.
// ---------------------------------------------------------------------------
__global__ __launch_bounds__(256)
void decode_persistent(const ushort_t* __restrict__ seed,
                       const ushort_t* __restrict__ hs,
                       const ushort_t* __restrict__ Wih,
                       const ushort_t* __restrict__ Whh,
                       const ushort_t* __restrict__ W1b,
                       const ushort_t* __restrict__ W2b,
                       const ushort_t* __restrict__ W3b,
                       ushort_t* __restrict__ hdec,
                       ushort_t* __restrict__ zd1, ushort_t* __restrict__ zd2,
                       float* __restrict__ xg, ushort_t* __restrict__ xgb,
                       unsigned* __restrict__ cnt,
                       const float* __restrict__ b_ih, const float* __restrict__ b_hh,
                       const float* __restrict__ b1, const float* __restrict__ rm1,
                       const float* __restrict__ rv1, const float* __restrict__ g1,
                       const float* __restrict__ be1,
                       const float* __restrict__ b2, const float* __restrict__ rm2,
                       const float* __restrict__ rv2, const float* __restrict__ g2,
                       const float* __restrict__ be2,
                       const float* __restrict__ b3, const float* __restrict__ rm3,
                       const float* __restrict__ rv3, const float* __restrict__ g3,
                       const float* __restrict__ be3)
{
    __shared__ ushort_t wlds[66560];   // 133,120 B -> 1 block/CU
    const int id = blockIdx.x;
    const int wave = threadIdx.x >> 6;
    const int lane = threadIdx.x & 63;
    const int lr = lane & 15;
    // line(ev, rg) = cnt + (ev*4 + rg)*64
    // per-gap increments: EV_CELL +8, EV_L1 +16, EV_L2 +16, EV_L3 +16

    if (id < 32) {
        // ---- cell role: 4 rgroups x 8 cgroups; 128 rows x 64 cols each ----
        const int rg = id >> 3, cg = id & 7;
        unsigned* ln_cell = cnt + (0 * 4 + rg) * 64;   // own group's output
        unsigned* ln_l3   = cnt + (3 * 4 + rg) * 64;   // L3 rows [rg*128,+128)
        load_wslice(Wih, cg * 64, FF, 64, wlds, HP);
        load_wslice(Whh, cg * 64, FF, 64, wlds + 64 * HP, HP);
        float bb[4];
#pragma unroll
        for (int nt = 0; nt < 4; ++nt) {
            const int gcol = cg * 64 + nt * 16 + lr;
            bb[nt] = b_ih[gcol] + b_hh[gcol];
        }
        __syncthreads();
        const int m0 = rg * 128 + wave * 32;
        for (int g = 0; g < 16; ++g) {
            f32x4 acc[2][4] = {};
            // h-half: needs only previous cell output (overlaps prev gap's
            // L1/L2/L3 stages).
            if (g) wait_line(ln_cell, 8u * g);
            const ushort_t* hprev = g ? (hdec + (size_t)((g - 1) & 1) * BF)
                                      : (hs + (size_t)63 * FF);
            const long h_rs = g ? (long)FF : (long)(TN * FF);
            frag_gemm<2, 16, 0>(hprev, h_rs, nullptr, 0,
                                wlds + 64 * HP, nullptr, HP, m0, acc);
            // x-half: critical path, released by L3 groups {2rg,2rg+1}.
            if (g) wait_line(ln_l3, 16u * g);
            const ushort_t* xprev = g ? (xgb + (size_t)(g - 1) * BF) : seed;
            frag_gemm<2, 16, 0>(xprev, FF, nullptr, 0,
                                wlds, nullptr, HP, m0, acc);
            ushort_t* hnew = hdec + (size_t)(g & 1) * BF;
            ep_tanh_pre<2>(acc, m0, cg * 64, bb, hnew, FF);
            arrive_line(ln_cell);
        }
    } else if (id < 96) {
        // ---- L1 role: 8 rgroups x 8 cgroups; 64 rows x 128 cols each ----
        const int lidx = id - 32;
        const int rg1 = lidx >> 3, cg = lidx & 7;
        unsigned* ln_in  = cnt + (0 * 4 + (rg1 >> 1)) * 64;
        unsigned* ln_out = cnt + (1 * 4 + (rg1 >> 1)) * 64;
        load_wslice(W1b, cg * 128, FF, 128, wlds, HP);
        const int gc0 = cg * 128 + (wave & 1) * 64;
        float sA[4], cA[4];
#pragma unroll
        for (int nt = 0; nt < 4; ++nt) {
            const int gcol = gc0 + nt * 16 + lr;
            const bool ok = gcol < HD;
            sA[nt] = ok ? g1[gcol] * rsqrtf(rv1[gcol] + EPSBN) : 0.f;
            cA[nt] = ok ? (b1[gcol] - rm1[gcol]) * sA[nt] + be1[gcol] : 0.f;
        }
        __syncthreads();
        const int m0 = rg1 * 64 + (wave >> 1) * 32;
        for (int g = 0; g < 16; ++g) {
            wait_line(ln_in, 8u * (g + 1));
            const ushort_t* hnew = hdec + (size_t)(g & 1) * BF;
            f32x4 acc[2][4] = {};
            frag_gemm<2, 16, 0>(hnew, FF, nullptr, 0,
                                wlds + (wave & 1) * 64 * HP, nullptr, HP, m0, acc);
            ep_bn_pre<2>(acc, m0, gc0, sA, cA, zd1, HDP, nullptr);
            arrive_line(ln_out);
        }
    } else if (id < 160) {
        // ---- L2 role: 4 rgroups x 16 cgroups; 128 rows x 64 cols each ----
        const int lidx = id - 96;
        const int rg2 = lidx >> 4, cg = lidx & 15;
        unsigned* ln_in  = cnt + (1 * 4 + rg2) * 64;
        unsigned* ln_out = cnt + (2 * 4 + rg2) * 64;
        load_wslice(W2b, cg * 64, HDP, 64, wlds, 1032);
        const int gc0 = cg * 64;
        float sA[4], cA[4];
#pragma unroll
        for (int nt = 0; nt < 4; ++nt) {
            const int gcol = gc0 + nt * 16 + lr;
            const bool ok = gcol < HD;
            sA[nt] = ok ? g2[gcol] * rsqrtf(rv2[gcol] + EPSBN) : 0.f;
            cA[nt] = ok ? (b2[gcol] - rm2[gcol]) * sA[nt] + be2[gcol] : 0.f;
        }
        __syncthreads();
        const int m0 = rg2 * 128 + wave * 32;
        for (int g = 0; g < 16; ++g) {
            wait_line(ln_in, 16u * (g + 1));
            f32x4 acc[2][4] = {};
            frag_gemm<2, 32, 0>(zd1, HDP, nullptr, 0,
                                wlds, nullptr, 1032, m0, acc);
            ep_bn_pre<2>(acc, m0, gc0, sA, cA, zd2, HDP, nullptr);
            arrive_line(ln_out);
        }
    } else {
        // ---- L3 role: 8 rgroups x 8 cgroups; 64 rows x 64 cols each ----
        const int lidx = id - 160;
        const int rg3 = lidx >> 3, cg = lidx & 7;
        unsigned* ln_in  = cnt + (2 * 4 + (rg3 >> 1)) * 64;
        unsigned* ln_out = cnt + (3 * 4 + (rg3 >> 1)) * 64;
        load_wslice(W3b, cg * 64, HDP, 64, wlds, 1032);
        const int gc0 = cg * 64;
        float sA[4], cA[4];
#pragma unroll
        for (int nt = 0; nt < 4; ++nt) {
            const int gcol = gc0 + nt * 16 + lr;   // < 512 always
            sA[nt] = g3[gcol] * rsqrtf(rv3[gcol] + EPSBN);
            cA[nt] = (b3[gcol] - rm3[gcol]) * sA[nt] + be3[gcol];
        }
        __syncthreads();
        const int m0 = rg3 * 64 + wave * 16;
        for (int g = 0; g < 16; ++g) {
            wait_line(ln_in, 16u * (g + 1));
            f32x4 acc[1][4] = {};
            frag_gemm<1, 32, 0>(zd2, HDP, nullptr, 0,
                                wlds, nullptr, 1032, m0, acc);
            ep_bn_pre<1>(acc, m0, gc0, sA, cA,
                         xgb + (size_t)g * BF, FF, xg + (size_t)g * BF);
            arrive_line(ln_out);
        }
    }
}

// ---------------------------------------------------------------------------
__global__ void zero_init(float* __restrict__ sums, unsigned* __restrict__ cnt)
{
    const int i = threadIdx.x + blockIdx.x * blockDim.x;
    if (i < 2) sums[i] = 0.f;
    for (int k = i; k < SYNC_WORDS; k += blockDim.x * gridDim.x) cnt[k] = 0u;
}

__global__ void conv_x(const float* __restrict__ x, ushort_t* __restrict__ xb)
{
    const int i = blockIdx.x * blockDim.x + threadIdx.x;
    if (i < MALL * FF / 4) {
        const int e = i * 4;
        const int m = e >> 9;
        const int f = e & (FF - 1);
        const int b = m >> 6, t = m & 63;
        const float4 v = *(const float4*)&x[((size_t)b * TT + t) * FF + f];
        unsigned r0 = (unsigned)f2bf(v.x) | ((unsigned)f2bf(v.y) << 16);
        unsigned r1 = (unsigned)f2bf(v.z) | ((unsigned)f2bf(v.w) << 16);
        *(uint2*)&xb[e] = make_uint2(r0, r1);
    }
}

__global__ void conv_w(const float* __restrict__ src, ushort_t* __restrict__ dst,
                       int Nsrc, int Ksrc, int Npad, int Kpad)
{
    const int i = blockIdx.x * blockDim.x + threadIdx.x;
    if (i < Npad * Kpad) {
        const int n = i / Kpad, k = i - n * Kpad;
        const float v = (n < Nsrc && k < Ksrc) ? src[(size_t)n * Ksrc + k] : 0.f;
        dst[i] = f2bf(v);
    }
}

__global__ void gather_kernel(const float* __restrict__ xgaps,
                              const int* __restrict__ tgap,
                              const float* __restrict__ x,
                              float* __restrict__ out,
                              float* __restrict__ sums)
{
    const int i = blockIdx.x * blockDim.x + threadIdx.x;
    float s = 0.f;
    if (i < BF) {
        const int b = i >> 9, f = i & (FF - 1);
        const int g = tgap[b] - 1;
        const float v = xgaps[((size_t)g * BB + b) * FF + f];
        out[i] = v;
        const float d = v - x[((size_t)b * TT + (TT - 1)) * FF + f];
        s = d * d;
    }
    __shared__ float red[256];
    red[threadIdx.x] = s;
    __syncthreads();
    for (int o = 128; o > 0; o >>= 1) {
        if (threadIdx.x < o) red[threadIdx.x] += red[threadIdx.x + o];
        __syncthreads();
    }
    if (threadIdx.x == 0) atomicAdd(&sums[1], red[0]);
}

__global__ void finalize_kernel(const float* __restrict__ sums,
                                float* __restrict__ out)
{
    if (threadIdx.x == 0 && blockIdx.x == 0) {
        const double n1 = 63.0 * 512.0 * 512.0;
        const double n2 = 512.0 * 512.0;
        out[BF] = (float)((double)sums[0] / (n1 * n1) +
                          (double)sums[1] / (n2 * n2));
    }
}

extern "C" void kernel_launch(void* const* d_in, const int* in_sizes, int n_in,
                              void* d_out, int out_size, void* d_ws, size_t ws_size,
                              hipStream_t stream)
{
    const float* x    = (const float*)d_in[0];
    const int*   tgap = (const int*)d_in[1];
    const float* W_ih = (const float*)d_in[2];
    const float* W_hh = (const float*)d_in[3];
    const float* b_ih = (const float*)d_in[4];
    const float* b_hh = (const float*)d_in[5];
    const float* W1 = (const float*)d_in[6];
    const float* b1 = (const float*)d_in[7];
    const float* g1 = (const float*)d_in[8];
    const float* be1 = (const float*)d_in[9];
    const float* rm1 = (const float*)d_in[10];
    const float* rv1 = (const float*)d_in[11];
    const float* W2 = (const float*)d_in[12];
    const float* b2 = (const float*)d_in[13];
    const float* g2 = (const float*)d_in[14];
    const float* be2 = (const float*)d_in[15];
    const float* rm2 = (const float*)d_in[16];
    const float* rv2 = (const float*)d_in[17];
    const float* W3 = (const float*)d_in[18];
    const float* b3 = (const float*)d_in[19];
    const float* g3 = (const float*)d_in[20];
    const float* be3 = (const float*)d_in[21];
    const float* rm3 = (const float*)d_in[22];
    const float* rv3 = (const float*)d_in[23];
    float* out = (float*)d_out;

    char* p = (char*)d_ws;
    auto take = [&](size_t bytes) -> char* {
        char* r = p; p += (bytes + 63) & ~(size_t)63; return r;
    };
    float*    XWbuf = (float*)take((size_t)MALL * FF * 4);      // 67.1 MB
    ushort_t* hs    = (ushort_t*)take((size_t)MALL * FF * 2);   // 33.5 MB
    ushort_t* xbf   = (ushort_t*)take((size_t)MALL * FF * 2);   // 33.5 MB
    ushort_t* z1    = (ushort_t*)take((size_t)CM * HDP * 2);    // 16.8 MB
    ushort_t* z2    = (ushort_t*)take((size_t)CM * HDP * 2);    // 16.8 MB
    float*    xg    = (float*)take((size_t)16 * BF * 4);        // 16.8 MB
    ushort_t* xgb   = (ushort_t*)take((size_t)16 * BF * 2);     //  8.4 MB
    ushort_t* seed  = (ushort_t*)take((size_t)BF * 2);
    ushort_t* hdec  = (ushort_t*)take((size_t)2 * BF * 2);
    ushort_t* zd1   = (ushort_t*)take((size_t)BB * HDP * 2);
    ushort_t* zd2   = (ushort_t*)take((size_t)BB * HDP * 2);
    ushort_t* Wihb  = (ushort_t*)take((size_t)FF * FF * 2);
    ushort_t* Whhb  = (ushort_t*)take((size_t)FF * FF * 2);
    ushort_t* W1b   = (ushort_t*)take((size_t)HDP * FF * 2);
    ushort_t* W2b   = (ushort_t*)take((size_t)HDP * HDP * 2);
    ushort_t* W3b   = (ushort_t*)take((size_t)FF * HDP * 2);
    float*    sums  = (float*)take(16 * 4);
    unsigned* cnt   = (unsigned*)take((size_t)SYNC_WORDS * 4);

    const dim3 blk(256);

    zero_init<<<dim3(2), blk, 0, stream>>>(sums, cnt);
    conv_x<<<dim3(MALL * FF / 4 / 256), blk, 0, stream>>>(x, xbf);
    conv_w<<<dim3((FF * FF + 255) / 256), blk, 0, stream>>>(W_ih, Wihb, FF, FF, FF, FF);
    conv_w<<<dim3((FF * FF + 255) / 256), blk, 0, stream>>>(W_hh, Whhb, FF, FF, FF, FF);
    conv_w<<<dim3((HDP * FF + 255) / 256), blk, 0, stream>>>(W1, W1b, HD, FF, HDP, FF);
    conv_w<<<dim3((HDP * HDP + 255) / 256), blk, 0, stream>>>(W2, W2b, HD, HD, HDP, HDP);
    conv_w<<<dim3((FF * HDP + 255) / 256), blk, 0, stream>>>(W3, W3b, FF, HD, FF, HDP);

    // 1) XW = x @ W_ih^T + b_ih + b_hh -> fp32
    mfma_gemm<<<dim3(FF / 128, MALL / 128), blk, 0, stream>>>(
        xbf, FF, Wihb, FF, FF, XWbuf, FF, nullptr, 0, 0,
        b_ih, b_hh, nullptr, nullptr, nullptr, nullptr, nullptr, nullptr);

    // 2) recurrence (persistent, batch-split, register W-stream)
    rnn_persistent<<<dim3(BB / 16), blk, 0, stream>>>(Whhb, XWbuf, hs);

    // 3) autoenc over 32768 rows in 4 chunks
    for (int c = 0; c < CH; ++c) {
        const ushort_t* Ac = hs + (size_t)c * CM * FF;
        mfma_gemm<<<dim3(HDP / 128, CM / 128), blk, 0, stream>>>(
            Ac, FF, W1b, FF, HD, z1, HDP, nullptr, 2, 0,
            b1, nullptr, rm1, rv1, g1, be1, nullptr, nullptr);
        mfma_gemm<<<dim3(HDP / 128, CM / 128), blk, 0, stream>>>(
            z1, HDP, W2b, HDP, HD, z2, HDP, nullptr, 2, 0,
            b2, nullptr, rm2, rv2, g2, be2, nullptr, nullptr);
        mfma_gemm<<<dim3(FF / 128, CM / 128), blk, 0, stream>>>(
            z2, HDP, W3b, HDP, FF, nullptr, 0, x, 5, c * CM,
            b3, nullptr, rm3, rv3, g3, be3, seed, sums);
    }

    // 4) decode (persistent, stage-specialized, direct-inbox handoffs)
    decode_persistent<<<dim3(DNB), blk, 0, stream>>>(
        seed, hs, Wihb, Whhb, W1b, W2b, W3b,
        hdec, zd1, zd2, xg, xgb, cnt,
        b_ih, b_hh,
        b1, rm1, rv1, g1, be1,
        b2, rm2, rv2, g2, be2,
        b3, rm3, rv3, g3, be3);

    // 5) gather + finalize
    gather_kernel<<<dim3(BF / 256), blk, 0, stream>>>(xg, tgap, x, out, sums);
    finalize_kernel<<<dim3(1), dim3(64), 0, stream>>>(sums, out);
}

// Round 3
// 1936.535 us; speedup vs baseline: 1.1238x; 1.0250x over previous
//
#include <hip/hip_runtime.h>
#include <math.h>

// forecastRNN on MI355X, round 9.
// Decode: ELIMINATE THE L2 WRITEBACK SWEEP from the handoff path.
// Rounds 7/8 proved the sync protocol isn't the cost (671->648 only).
// The invariant term: every release fetch_add at agent scope lowers to
// s_waitcnt + buffer_wbl2 (full dirty-L2 writeback sweep) because XCD L2s
// are not coherent. 64 producers/stage -> up to 8 serialized sweeps per
// XCD per stage on the critical path (~9us/stage).
// Fix: inter-stage data (hdec/zd1/zd2/xgb/xg) is written with AGENT-scope
// RELAXED ATOMIC stores (sc1 write-through -> data lands at the L3
// coherence point, never dirty in L2); bf16 pairs packed to 4B via one
// shfl_xor (no sub-word atomic expansion), f32 pairs to 8B. arrive is then
// __syncthreads (drains vmcnt per wave) + vmcnt(0) + RELAXED fetch_add:
// no release fence, no wbl2 anywhere. Consumer keeps relaxed RMW-poll +
// one acquire load (flash buffer_inv, cheap) to drop stale L2 lines.
// RNN / large-GEMM / conversion kernels unchanged.

typedef unsigned short ushort_t;
typedef __attribute__((ext_vector_type(8))) short short8;
typedef __attribute__((ext_vector_type(4))) float f32x4;

#define BB 512
#define TT 65
#define TN 64
#define FF 512
#define HD 1000
#define HDP 1024
#define EPSBN 1e-5f
#define BF (BB*FF)          // 262144
#define MALL (BB*TN)        // 32768
#define CH 4
#define CM (MALL/CH)        // 8192
#define HP 520              // LDS h row stride (1040 B)
#define DNB 224

// sync lines in cnt[]: line(ev, rg) = cnt + (ev*4 + rg)*64   (256 B apart)
// ev: 0=cell_done 1=l1_done 2=l2_done 3=l3_done; rg in [0,4)
// per-gap increments: EV_CELL +8, others +16
#define SYNC_WORDS 4096

__device__ __forceinline__ ushort_t f2bf(float f) {
    union { float f; unsigned u; } v; v.f = f;
    unsigned r = v.u + 0x7FFFu + ((v.u >> 16) & 1u);
    return (ushort_t)(r >> 16);
}

__device__ __forceinline__ float ftanh(float x) {
    const float e = __expf(2.f * x);
    return 1.f - 2.f / (e + 1.f);
}

__device__ __forceinline__ void ld16(const ushort_t* g, ushort_t* l) {
    __builtin_amdgcn_global_load_lds(
        (const __attribute__((address_space(1))) unsigned*)g,
        (__attribute__((address_space(3))) unsigned*)l, 16, 0, 0);
}

// agent-scope coherent stores (sc1 write-through to L3; no dirty L2 lines)
__device__ __forceinline__ void st_u32(unsigned* p, unsigned v) {
    __hip_atomic_store(p, v, __ATOMIC_RELAXED, __HIP_MEMORY_SCOPE_AGENT);
}
__device__ __forceinline__ void st_u64(unsigned long long* p,
                                       unsigned long long v) {
    __hip_atomic_store(p, v, __ATOMIC_RELAXED, __HIP_MEMORY_SCOPE_AGENT);
}

// ---------------------------------------------------------------------------
// Large-GEMM kernel (XW precompute + autoenc), 128x128 tile, BK=32.
// ---------------------------------------------------------------------------
__global__ __launch_bounds__(256)
void mfma_gemm(const ushort_t* __restrict__ A, long a_rs,
               const ushort_t* __restrict__ W, int K, int Nreal,
               void* __restrict__ outv, long o_rs,
               const float* __restrict__ aux, int epi, int mbase,
               const float* __restrict__ p1, const float* __restrict__ p2,
               const float* __restrict__ rm, const float* __restrict__ rv,
               const float* __restrict__ gg, const float* __restrict__ be,
               ushort_t* __restrict__ out2, float* __restrict__ sums)
{
    __shared__ ushort_t As[128 * 32];
    __shared__ ushort_t Bs[128 * 32];
    __shared__ float red[256];

    const int tid  = threadIdx.x;
    const int wave = tid >> 6, lane = tid & 63;
    const int wm = wave >> 1, wn = wave & 1;
    const int tileM = blockIdx.y * 128, tileN = blockIdx.x * 128;

    f32x4 acc[4][4] = {};
    const int srow = lane >> 2;
    const int skb  = (lane & 3) * 8;

    for (int kt = 0; kt < K; kt += 32) {
        __syncthreads();
#pragma unroll
        for (int s = 0; s < 2; ++s) {
            const int instr = wave * 2 + s;
            const int row = instr * 16 + srow;
            ld16(A + (size_t)(tileM + row) * a_rs + kt + skb, &As[instr * 512]);
            ld16(W + (size_t)(tileN + row) * (size_t)K + kt + skb, &Bs[instr * 512]);
        }
        __syncthreads();
        const int lr = lane & 15;
        const int lk = (lane >> 4) * 8;
        short8 af[4], bfr[4];
#pragma unroll
        for (int i = 0; i < 4; ++i)
            af[i] = *(const short8*)&As[(wm * 64 + i * 16 + lr) * 32 + lk];
#pragma unroll
        for (int j = 0; j < 4; ++j)
            bfr[j] = *(const short8*)&Bs[(wn * 64 + j * 16 + lr) * 32 + lk];
#pragma unroll
        for (int i = 0; i < 4; ++i)
#pragma unroll
            for (int j = 0; j < 4; ++j)
                acc[i][j] = __builtin_amdgcn_mfma_f32_16x16x32_bf16(
                    af[i], bfr[j], acc[i][j], 0, 0, 0);
    }

    const int lr = lane & 15;
    const int rquad = (lane >> 4) * 4;
    float lsum = 0.f;
#pragma unroll
    for (int i = 0; i < 4; ++i) {
#pragma unroll
        for (int r = 0; r < 4; ++r) {
            const int grow = tileM + wm * 64 + i * 16 + rquad + r;
#pragma unroll
            for (int j = 0; j < 4; ++j) {
                const int gcol = tileN + wn * 64 + j * 16 + lr;
                const float v = acc[i][j][r];
                if (epi == 0) {
                    ((float*)outv)[(size_t)grow * o_rs + gcol] = v + p1[gcol] + p2[gcol];
                } else if (epi == 2) {
                    float o = 0.f;
                    if (gcol < Nreal) {
                        const float s = gg[gcol] * rsqrtf(rv[gcol] + EPSBN);
                        o = (v + p1[gcol] - rm[gcol]) * s + be[gcol];
                    }
                    ((ushort_t*)outv)[(size_t)grow * o_rs + gcol] = f2bf(o);
                } else { // epi 5
                    const float s = gg[gcol] * rsqrtf(rv[gcol] + EPSBN);
                    const float o = (v + p1[gcol] - rm[gcol]) * s + be[gcol];
                    const int gm = mbase + grow;
                    const int b = gm >> 6, tau = gm & 63;
                    if (tau < 63) {
                        const float d = o - aux[((size_t)b * TT + tau + 1) * FF + gcol];
                        lsum += d * d;
                    } else {
                        out2[(size_t)b * FF + gcol] = f2bf(o);
                    }
                }
            }
        }
    }
    if (epi == 5) {
        red[tid] = lsum;
        __syncthreads();
        for (int o = 128; o > 0; o >>= 1) {
            if (tid < o) red[tid] += red[tid + o];
            __syncthreads();
        }
        if (tid == 0) atomicAdd(&sums[0], red[0]);
    }
}

// ---------------------------------------------------------------------------
// Persistent recurrence: 32 blocks x 16 batch rows. 3-slot W prefetch ring
// (2 chunks ahead), XW register prefetch, fast tanh. 1 barrier/step.
// ---------------------------------------------------------------------------
__global__ __launch_bounds__(256)
void rnn_persistent(const ushort_t* __restrict__ Whh,
                    const float* __restrict__ XW,
                    ushort_t* __restrict__ hs)
{
    __shared__ ushort_t hb[2][16 * HP];
    const int tid = threadIdx.x, wave = tid >> 6, lane = tid & 63;
    const int b0 = blockIdx.x * 16;
    const int lr = lane & 15, lq = lane >> 4;
    const int c0 = wave * 128;

    // t = 0: h = tanh(XW_0)
    for (int it = 0; it < 8; ++it) {
        const int e = (it * 256 + tid) * 4;
        const int row = e >> 9, col = e & 511;
        const size_t gi = ((size_t)(b0 + row) * TN) * FF + col;
        const float4 v = *(const float4*)&XW[gi];
        const ushort_t h0 = f2bf(ftanh(v.x)), h1 = f2bf(ftanh(v.y));
        const ushort_t h2 = f2bf(ftanh(v.z)), h3 = f2bf(ftanh(v.w));
        hb[0][row * HP + col + 0] = h0; hb[0][row * HP + col + 1] = h1;
        hb[0][row * HP + col + 2] = h2; hb[0][row * HP + col + 3] = h3;
        unsigned r0 = (unsigned)h0 | ((unsigned)h1 << 16);
        unsigned r1 = (unsigned)h2 | ((unsigned)h3 << 16);
        *(uint2*)&hs[gi] = make_uint2(r0, r1);
    }
    __syncthreads();

    f32x4 acc[8];
    short8 wf[3][8];
    short8 af[3];
    float xw[8][4];

    for (int t = 1; t < TN; ++t) {
        const ushort_t* hcur = hb[(t - 1) & 1];

        // prologue: chunks 0,1 into slots 0,1
#pragma unroll
        for (int s = 0; s < 2; ++s) {
            const int kk = s * 32 + lq * 8;
            af[s] = *(const short8*)&hcur[lr * HP + kk];
#pragma unroll
            for (int j = 0; j < 8; ++j)
                wf[s][j] = *(const short8*)(Whh + (size_t)(c0 + j * 16 + lr) * FF + kk);
        }
        // XW register prefetch for this step (HBM; overlaps the K-loop)
#pragma unroll
        for (int j = 0; j < 8; ++j)
#pragma unroll
            for (int r = 0; r < 4; ++r)
                xw[j][r] = XW[((size_t)(b0 + lq * 4 + r) * TN + t) * FF
                              + c0 + j * 16 + lr];
#pragma unroll
        for (int j = 0; j < 8; ++j) acc[j] = (f32x4){0.f, 0.f, 0.f, 0.f};

#pragma unroll
        for (int kc = 0; kc < 16; ++kc) {
            if (kc + 2 < 16) {
                const int slot = (kc + 2) % 3;
                const int kk = (kc + 2) * 32 + lq * 8;
                af[slot] = *(const short8*)&hcur[lr * HP + kk];
#pragma unroll
                for (int j = 0; j < 8; ++j)
                    wf[slot][j] = *(const short8*)
                        (Whh + (size_t)(c0 + j * 16 + lr) * FF + kk);
            }
            const int b = kc % 3;
#pragma unroll
            for (int j = 0; j < 8; ++j)
                acc[j] = __builtin_amdgcn_mfma_f32_16x16x32_bf16(
                    af[b], wf[b][j], acc[j], 0, 0, 0);
        }

        ushort_t* hnxt = hb[t & 1];
#pragma unroll
        for (int j = 0; j < 8; ++j) {
            const int col = c0 + j * 16 + lr;
#pragma unroll
            for (int r = 0; r < 4; ++r) {
                const int row = lq * 4 + r;
                const size_t gi = ((size_t)(b0 + row) * TN + t) * FF + col;
                const ushort_t hv = f2bf(ftanh(acc[j][r] + xw[j][r]));
                hnxt[row * HP + col] = hv;
                hs[gi] = hv;
            }
        }
        __syncthreads();
    }
}

// ---------------------------------------------------------------------------
// Producer/consumer sync primitives (decode). No release fences anywhere:
// data stores are agent-coherent (sc1), so arrive = drain vmcnt + RELAXED
// fetch_add (no buffer_wbl2 sweep). Consumer RMW-polls (executes at the
// coherence point -> never stale) then one acquire load (flash buffer_inv
// drops stale L2 lines from the previous gap).
// ---------------------------------------------------------------------------
__device__ __forceinline__ void wait_line(unsigned* __restrict__ line,
                                          unsigned tgt)
{
    if (threadIdx.x == 0) {
        while (__hip_atomic_fetch_add(line, 0u, __ATOMIC_RELAXED,
                                      __HIP_MEMORY_SCOPE_AGENT) < tgt)
            __builtin_amdgcn_s_sleep(1);
        (void)__hip_atomic_load(line, __ATOMIC_ACQUIRE, __HIP_MEMORY_SCOPE_AGENT);
    }
    __syncthreads();
}

__device__ __forceinline__ void arrive_line(unsigned* __restrict__ line)
{
    // __syncthreads drains each wave's vmcnt (sc1 stores are then at L3)
    __syncthreads();
    if (threadIdx.x == 0) {
        asm volatile("s_waitcnt vmcnt(0)" ::: "memory");
        __hip_atomic_fetch_add(line, 1u, __ATOMIC_RELAXED,
                               __HIP_MEMORY_SCOPE_AGENT);
    }
}

// load a weight slice (rows [n0,n0+rows) of W[*, K]) into LDS, row stride wrs
__device__ __forceinline__ void load_wslice(const ushort_t* __restrict__ W,
                                            int n0, int K, int rows,
                                            ushort_t* dst, int wrs)
{
    const int nch = K >> 3;
    const int total = rows * nch;
    for (int c = threadIdx.x; c < total; c += 256) {
        const int row = c / nch, col = (c - row * nch) * 8;
        *(uint4*)&dst[(size_t)row * wrs + col] =
            *(const uint4*)&W[(size_t)(n0 + row) * K + col];
    }
}

// fragment GEMM: acc[MT][4] over rows mrow0+mt*16, 64 cols (4 ntiles).
// PF-deep A-register ring (~PF-1 iterations of latency cover).
template <int MT, int NCH1, int NCH2, int PF = 8>
__device__ __forceinline__ void frag_gemm(
    const ushort_t* __restrict__ A1, long a1_rs,
    const ushort_t* __restrict__ A2, long a2_rs,
    const ushort_t* w1, const ushort_t* w2, int wrs,
    int mrow0, f32x4 (&acc)[MT][4])
{
    const int lane = threadIdx.x & 63;
    const int lr = lane & 15, lk = (lane >> 4) * 8;
    constexpr int NCH = NCH1 + NCH2;
    short8 a[PF][MT];

    auto aload = [&](int kc, int slot) {
        const bool p2 = (kc >= NCH1);
        const ushort_t* Ap = p2 ? A2 : A1;
        const long rs = p2 ? a2_rs : a1_rs;
        const int kk = (p2 ? kc - NCH1 : kc) * 32 + lk;
#pragma unroll
        for (int mt = 0; mt < MT; ++mt)
            a[slot][mt] = *(const short8*)(Ap + (size_t)(mrow0 + mt * 16 + lr) * rs + kk);
    };
#pragma unroll
    for (int p = 0; p < PF - 1; ++p) aload(p, p);
#pragma unroll
    for (int kc = 0; kc < NCH; ++kc) {
        if (kc + PF - 1 < NCH) aload(kc + PF - 1, (kc + PF - 1) % PF);
        const bool p2 = (kc >= NCH1);
        const ushort_t* wl = p2 ? w2 : w1;
        const int kk = (p2 ? kc - NCH1 : kc) * 32 + lk;
        short8 wfr[4];
#pragma unroll
        for (int nt = 0; nt < 4; ++nt)
            wfr[nt] = *(const short8*)&wl[(size_t)(nt * 16 + lr) * wrs + kk];
#pragma unroll
        for (int mt = 0; mt < MT; ++mt)
#pragma unroll
            for (int nt = 0; nt < 4; ++nt)
                acc[mt][nt] = __builtin_amdgcn_mfma_f32_16x16x32_bf16(
                    a[kc % PF][mt], wfr[nt], acc[mt][nt], 0, 0, 0);
    }
}

// epilogues: hoisted per-block constants; outputs written as agent-coherent
// (sc1) atomic stores. bf16 pairs packed to 4B via one shfl_xor (lane l even
// holds cols {gcol, gcol+1}); f32 pairs to 8B. Even lanes store.
template <int MT>
__device__ __forceinline__ void ep_tanh_pre(f32x4 (&acc)[MT][4], int mrow0,
                                            int gc0, const float (&bb)[4],
                                            ushort_t* __restrict__ obf, long o_rs)
{
    const int lane = threadIdx.x & 63;
    const int lr = lane & 15, rq = (lane >> 4) * 4;
    const bool even = !(lane & 1);
#pragma unroll
    for (int mt = 0; mt < MT; ++mt)
#pragma unroll
        for (int nt = 0; nt < 4; ++nt) {
            const int gcol = gc0 + nt * 16 + lr;
#pragma unroll
            for (int r = 0; r < 4; ++r) {
                const int grow = mrow0 + mt * 16 + rq + r;
                const unsigned v =
                    (unsigned)f2bf(ftanh(acc[mt][nt][r] + bb[nt]));
                const unsigned pv = __shfl_xor(v, 1);
                if (even)
                    st_u32((unsigned*)&obf[(size_t)grow * o_rs + gcol],
                           v | (pv << 16));
            }
        }
}

template <int MT>
__device__ __forceinline__ void ep_bn_pre(f32x4 (&acc)[MT][4], int mrow0,
                                          int gc0, const float (&s)[4],
                                          const float (&c)[4],
                                          ushort_t* __restrict__ obf, long o_rs,
                                          float* __restrict__ of32)
{
    const int lane = threadIdx.x & 63;
    const int lr = lane & 15, rq = (lane >> 4) * 4;
    const bool even = !(lane & 1);
#pragma unroll
    for (int mt = 0; mt < MT; ++mt)
#pragma unroll
        for (int nt = 0; nt < 4; ++nt) {
            const int gcol = gc0 + nt * 16 + lr;
#pragma unroll
            for (int r = 0; r < 4; ++r) {
                const int grow = mrow0 + mt * 16 + rq + r;
                const float o = acc[mt][nt][r] * s[nt] + c[nt];
                const unsigned v = (unsigned)f2bf(o);
                const unsigned pv = __shfl_xor(v, 1);
                union { float f; unsigned u; } ou; ou.f = o;
                const unsigned po = __shfl_xor(ou.u, 1);
                if (even) {
                    st_u32((unsigned*)&obf[(size_t)grow * o_rs + gcol],
                           v | (pv << 16));
                    if (of32)
                        st_u64((unsigned long long*)
                                   &of32[(size_t)grow * o_rs + gcol],
                               (unsigned long long)ou.u |
                                   ((unsigned long long)po << 32));
                }
            }
        }
}

// ---------------------------------------------------------------------------
// Persistent decode: 224 stage-specialized blocks, weights resident in LDS.
// roles: [0,32) cell, [32,96) L1, [96,160) L2, [160,224) L3.
// ---------------------------------------------------------------------------
__global__ __launch_bounds__(256)
void decode_persistent(const ushort_t* __restrict__ seed,
                       const ushort_t* __restrict__ hs,
                       const ushort_t* __restrict__ Wih,
                       const ushort_t* __restrict__ Whh,
                       const ushort_t* __restrict__ W1b,
                       const ushort_t* __restrict__ W2b,
                       const ushort_t* __restrict__ W3b,
                       ushort_t* __restrict__ hdec,
                       ushort_t* __restrict__ zd1, ushort_t* __restrict__ zd2,
                       float* __restrict__ xg, ushort_t* __restrict__ xgb,
                       unsigned* __restrict__ cnt,
                       const float* __restrict__ b_ih, const float* __restrict__ b_hh,
                       const float* __restrict__ b1, const float* __restrict__ rm1,
                       const float* __restrict__ rv1, const float* __restrict__ g1,
                       const float* __restrict__ be1,
                       const float* __restrict__ b2, const float* __restrict__ rm2,
                       const float* __restrict__ rv2, const float* __restrict__ g2,
                       const float* __restrict__ be2,
                       const float* __restrict__ b3, const float* __restrict__ rm3,
                       const float* __restrict__ rv3, const float* __restrict__ g3,
                       const float* __restrict__ be3)
{
    __shared__ ushort_t wlds[66560];   // 133,120 B -> 1 block/CU
    const int id = blockIdx.x;
    const int wave = threadIdx.x >> 6;
    const int lane = threadIdx.x & 63;
    const int lr = lane & 15;
    // line(ev, rg) = cnt + (ev*4 + rg)*64

    if (id < 32) {
        // ---- cell role: 4 rgroups x 8 cgroups; 128 rows x 64 cols each ----
        const int rg = id >> 3, cg = id & 7;
        unsigned* ln_cell = cnt + (0 * 4 + rg) * 64;   // own group's output
        unsigned* ln_l3   = cnt + (3 * 4 + rg) * 64;   // L3 rows [rg*128,+128)
        load_wslice(Wih, cg * 64, FF, 64, wlds, HP);
        load_wslice(Whh, cg * 64, FF, 64, wlds + 64 * HP, HP);
        float bb[4];
#pragma unroll
        for (int nt = 0; nt < 4; ++nt) {
            const int gcol = cg * 64 + nt * 16 + lr;
            bb[nt] = b_ih[gcol] + b_hh[gcol];
        }
        __syncthreads();
        const int m0 = rg * 128 + wave * 32;
        for (int g = 0; g < 16; ++g) {
            f32x4 acc[2][4] = {};
            // h-half: needs only previous cell output (overlaps prev gap's
            // L1/L2/L3 stages).
            if (g) wait_line(ln_cell, 8u * g);
            const ushort_t* hprev = g ? (hdec + (size_t)((g - 1) & 1) * BF)
                                      : (hs + (size_t)63 * FF);
            const long h_rs = g ? (long)FF : (long)(TN * FF);
            frag_gemm<2, 16, 0>(hprev, h_rs, nullptr, 0,
                                wlds + 64 * HP, nullptr, HP, m0, acc);
            // x-half: critical path, released by L3 groups {2rg,2rg+1}.
            if (g) wait_line(ln_l3, 16u * g);
            const ushort_t* xprev = g ? (xgb + (size_t)(g - 1) * BF) : seed;
            frag_gemm<2, 16, 0>(xprev, FF, nullptr, 0,
                                wlds, nullptr, HP, m0, acc);
            ushort_t* hnew = hdec + (size_t)(g & 1) * BF;
            ep_tanh_pre<2>(acc, m0, cg * 64, bb, hnew, FF);
            arrive_line(ln_cell);
        }
    } else if (id < 96) {
        // ---- L1 role: 8 rgroups x 8 cgroups; 64 rows x 128 cols each ----
        const int lidx = id - 32;
        const int rg1 = lidx >> 3, cg = lidx & 7;
        unsigned* ln_in  = cnt + (0 * 4 + (rg1 >> 1)) * 64;
        unsigned* ln_out = cnt + (1 * 4 + (rg1 >> 1)) * 64;
        load_wslice(W1b, cg * 128, FF, 128, wlds, HP);
        const int gc0 = cg * 128 + (wave & 1) * 64;
        float sA[4], cA[4];
#pragma unroll
        for (int nt = 0; nt < 4; ++nt) {
            const int gcol = gc0 + nt * 16 + lr;
            const bool ok = gcol < HD;
            sA[nt] = ok ? g1[gcol] * rsqrtf(rv1[gcol] + EPSBN) : 0.f;
            cA[nt] = ok ? (b1[gcol] - rm1[gcol]) * sA[nt] + be1[gcol] : 0.f;
        }
        __syncthreads();
        const int m0 = rg1 * 64 + (wave >> 1) * 32;
        for (int g = 0; g < 16; ++g) {
            wait_line(ln_in, 8u * (g + 1));
            const ushort_t* hnew = hdec + (size_t)(g & 1) * BF;
            f32x4 acc[2][4] = {};
            frag_gemm<2, 16, 0>(hnew, FF, nullptr, 0,
                                wlds + (wave & 1) * 64 * HP, nullptr, HP, m0, acc);
            ep_bn_pre<2>(acc, m0, gc0, sA, cA, zd1, HDP, nullptr);
            arrive_line(ln_out);
        }
    } else if (id < 160) {
        // ---- L2 role: 4 rgroups x 16 cgroups; 128 rows x 64 cols each ----
        const int lidx = id - 96;
        const int rg2 = lidx >> 4, cg = lidx & 15;
        unsigned* ln_in  = cnt + (1 * 4 + rg2) * 64;
        unsigned* ln_out = cnt + (2 * 4 + rg2) * 64;
        load_wslice(W2b, cg * 64, HDP, 64, wlds, 1032);
        const int gc0 = cg * 64;
        float sA[4], cA[4];
#pragma unroll
        for (int nt = 0; nt < 4; ++nt) {
            const int gcol = gc0 + nt * 16 + lr;
            const bool ok = gcol < HD;
            sA[nt] = ok ? g2[gcol] * rsqrtf(rv2[gcol] + EPSBN) : 0.f;
            cA[nt] = ok ? (b2[gcol] - rm2[gcol]) * sA[nt] + be2[gcol] : 0.f;
        }
        __syncthreads();
        const int m0 = rg2 * 128 + wave * 32;
        for (int g = 0; g < 16; ++g) {
            wait_line(ln_in, 16u * (g + 1));
            f32x4 acc[2][4] = {};
            frag_gemm<2, 32, 0>(zd1, HDP, nullptr, 0,
                                wlds, nullptr, 1032, m0, acc);
            ep_bn_pre<2>(acc, m0, gc0, sA, cA, zd2, HDP, nullptr);
            arrive_line(ln_out);
        }
    } else {
        // ---- L3 role: 8 rgroups x 8 cgroups; 64 rows x 64 cols each ----
        const int lidx = id - 160;
        const int rg3 = lidx >> 3, cg = lidx & 7;
        unsigned* ln_in  = cnt + (2 * 4 + (rg3 >> 1)) * 64;
        unsigned* ln_out = cnt + (3 * 4 + (rg3 >> 1)) * 64;
        load_wslice(W3b, cg * 64, HDP, 64, wlds, 1032);
        const int gc0 = cg * 64;
        float sA[4], cA[4];
#pragma unroll
        for (int nt = 0; nt < 4; ++nt) {
            const int gcol = gc0 + nt * 16 + lr;   // < 512 always
            sA[nt] = g3[gcol] * rsqrtf(rv3[gcol] + EPSBN);
            cA[nt] = (b3[gcol] - rm3[gcol]) * sA[nt] + be3[gcol];
        }
        __syncthreads();
        const int m0 = rg3 * 64 + wave * 16;
        for (int g = 0; g < 16; ++g) {
            wait_line(ln_in, 16u * (g + 1));
            f32x4 acc[1][4] = {};
            frag_gemm<1, 32, 0>(zd2, HDP, nullptr, 0,
                                wlds, nullptr, 1032, m0, acc);
            ep_bn_pre<1>(acc, m0, gc0, sA, cA,
                         xgb + (size_t)g * BF, FF, xg + (size_t)g * BF);
            arrive_line(ln_out);
        }
    }
}

// ---------------------------------------------------------------------------
__global__ void zero_init(float* __restrict__ sums, unsigned* __restrict__ cnt)
{
    const int i = threadIdx.x + blockIdx.x * blockDim.x;
    if (i < 2) sums[i] = 0.f;
    for (int k = i; k < SYNC_WORDS; k += blockDim.x * gridDim.x) cnt[k] = 0u;
}

__global__ void conv_x(const float* __restrict__ x, ushort_t* __restrict__ xb)
{
    const int i = blockIdx.x * blockDim.x + threadIdx.x;
    if (i < MALL * FF / 4) {
        const int e = i * 4;
        const int m = e >> 9;
        const int f = e & (FF - 1);
        const int b = m >> 6, t = m & 63;
        const float4 v = *(const float4*)&x[((size_t)b * TT + t) * FF + f];
        unsigned r0 = (unsigned)f2bf(v.x) | ((unsigned)f2bf(v.y) << 16);
        unsigned r1 = (unsigned)f2bf(v.z) | ((unsigned)f2bf(v.w) << 16);
        *(uint2*)&xb[e] = make_uint2(r0, r1);
    }
}

__global__ void conv_w(const float* __restrict__ src, ushort_t* __restrict__ dst,
                       int Nsrc, int Ksrc, int Npad, int Kpad)
{
    const int i = blockIdx.x * blockDim.x + threadIdx.x;
    if (i < Npad * Kpad) {
        const int n = i / Kpad, k = i - n * Kpad;
        const float v = (n < Nsrc && k < Ksrc) ? src[(size_t)n * Ksrc + k] : 0.f;
        dst[i] = f2bf(v);
    }
}

__global__ void gather_kernel(const float* __restrict__ xgaps,
                              const int* __restrict__ tgap,
                              const float* __restrict__ x,
                              float* __restrict__ out,
                              float* __restrict__ sums)
{
    const int i = blockIdx.x * blockDim.x + threadIdx.x;
    float s = 0.f;
    if (i < BF) {
        const int b = i >> 9, f = i & (FF - 1);
        const int g = tgap[b] - 1;
        const float v = xgaps[((size_t)g * BB + b) * FF + f];
        out[i] = v;
        const float d = v - x[((size_t)b * TT + (TT - 1)) * FF + f];
        s = d * d;
    }
    __shared__ float red[256];
    red[threadIdx.x] = s;
    __syncthreads();
    for (int o = 128; o > 0; o >>= 1) {
        if (threadIdx.x < o) red[threadIdx.x] += red[threadIdx.x + o];
        __syncthreads();
    }
    if (threadIdx.x == 0) atomicAdd(&sums[1], red[0]);
}

__global__ void finalize_kernel(const float* __restrict__ sums,
                                float* __restrict__ out)
{
    if (threadIdx.x == 0 && blockIdx.x == 0) {
        const double n1 = 63.0 * 512.0 * 512.0;
        const double n2 = 512.0 * 512.0;
        out[BF] = (float)((double)sums[0] / (n1 * n1) +
                          (double)sums[1] / (n2 * n2));
    }
}

extern "C" void kernel_launch(void* const* d_in, const int* in_sizes, int n_in,
                              void* d_out, int out_size, void* d_ws, size_t ws_size,
                              hipStream_t stream)
{
    const float* x    = (const float*)d_in[0];
    const int*   tgap = (const int*)d_in[1];
    const float* W_ih = (const float*)d_in[2];
    const float* W_hh = (const float*)d_in[3];
    const float* b_ih = (const float*)d_in[4];
    const float* b_hh = (const float*)d_in[5];
    const float* W1 = (const float*)d_in[6];
    const float* b1 = (const float*)d_in[7];
    const float* g1 = (const float*)d_in[8];
    const float* be1 = (const float*)d_in[9];
    const float* rm1 = (const float*)d_in[10];
    const float* rv1 = (const float*)d_in[11];
    const float* W2 = (const float*)d_in[12];
    const float* b2 = (const float*)d_in[13];
    const float* g2 = (const float*)d_in[14];
    const float* be2 = (const float*)d_in[15];
    const float* rm2 = (const float*)d_in[16];
    const float* rv2 = (const float*)d_in[17];
    const float* W3 = (const float*)d_in[18];
    const float* b3 = (const float*)d_in[19];
    const float* g3 = (const float*)d_in[20];
    const float* be3 = (const float*)d_in[21];
    const float* rm3 = (const float*)d_in[22];
    const float* rv3 = (const float*)d_in[23];
    float* out = (float*)d_out;

    char* p = (char*)d_ws;
    auto take = [&](size_t bytes) -> char* {
        char* r = p; p += (bytes + 63) & ~(size_t)63; return r;
    };
    float*    XWbuf = (float*)take((size_t)MALL * FF * 4);      // 67.1 MB
    ushort_t* hs    = (ushort_t*)take((size_t)MALL * FF * 2);   // 33.5 MB
    ushort_t* xbf   = (ushort_t*)take((size_t)MALL * FF * 2);   // 33.5 MB
    ushort_t* z1    = (ushort_t*)take((size_t)CM * HDP * 2);    // 16.8 MB
    ushort_t* z2    = (ushort_t*)take((size_t)CM * HDP * 2);    // 16.8 MB
    float*    xg    = (float*)take((size_t)16 * BF * 4);        // 16.8 MB
    ushort_t* xgb   = (ushort_t*)take((size_t)16 * BF * 2);     //  8.4 MB
    ushort_t* seed  = (ushort_t*)take((size_t)BF * 2);
    ushort_t* hdec  = (ushort_t*)take((size_t)2 * BF * 2);
    ushort_t* zd1   = (ushort_t*)take((size_t)BB * HDP * 2);
    ushort_t* zd2   = (ushort_t*)take((size_t)BB * HDP * 2);
    ushort_t* Wihb  = (ushort_t*)take((size_t)FF * FF * 2);
    ushort_t* Whhb  = (ushort_t*)take((size_t)FF * FF * 2);
    ushort_t* W1b   = (ushort_t*)take((size_t)HDP * FF * 2);
    ushort_t* W2b   = (ushort_t*)take((size_t)HDP * HDP * 2);
    ushort_t* W3b   = (ushort_t*)take((size_t)FF * HDP * 2);
    float*    sums  = (float*)take(16 * 4);
    unsigned* cnt   = (unsigned*)take((size_t)SYNC_WORDS * 4);

    const dim3 blk(256);

    zero_init<<<dim3(2), blk, 0, stream>>>(sums, cnt);
    conv_x<<<dim3(MALL * FF / 4 / 256), blk, 0, stream>>>(x, xbf);
    conv_w<<<dim3((FF * FF + 255) / 256), blk, 0, stream>>>(W_ih, Wihb, FF, FF, FF, FF);
    conv_w<<<dim3((FF * FF + 255) / 256), blk, 0, stream>>>(W_hh, Whhb, FF, FF, FF, FF);
    conv_w<<<dim3((HDP * FF + 255) / 256), blk, 0, stream>>>(W1, W1b, HD, FF, HDP, FF);
    conv_w<<<dim3((HDP * HDP + 255) / 256), blk, 0, stream>>>(W2, W2b, HD, HD, HDP, HDP);
    conv_w<<<dim3((FF * HDP + 255) / 256), blk, 0, stream>>>(W3, W3b, FF, HD, FF, HDP);

    // 1) XW = x @ W_ih^T + b_ih + b_hh -> fp32
    mfma_gemm<<<dim3(FF / 128, MALL / 128), blk, 0, stream>>>(
        xbf, FF, Wihb, FF, FF, XWbuf, FF, nullptr, 0, 0,
        b_ih, b_hh, nullptr, nullptr, nullptr, nullptr, nullptr, nullptr);

    // 2) recurrence (persistent, batch-split, register W-stream)
    rnn_persistent<<<dim3(BB / 16), blk, 0, stream>>>(Whhb, XWbuf, hs);

    // 3) autoenc over 32768 rows in 4 chunks
    for (int c = 0; c < CH; ++c) {
        const ushort_t* Ac = hs + (size_t)c * CM * FF;
        mfma_gemm<<<dim3(HDP / 128, CM / 128), blk, 0, stream>>>(
            Ac, FF, W1b, FF, HD, z1, HDP, nullptr, 2, 0,
            b1, nullptr, rm1, rv1, g1, be1, nullptr, nullptr);
        mfma_gemm<<<dim3(HDP / 128, CM / 128), blk, 0, stream>>>(
            z1, HDP, W2b, HDP, HD, z2, HDP, nullptr, 2, 0,
            b2, nullptr, rm2, rv2, g2, be2, nullptr, nullptr);
        mfma_gemm<<<dim3(FF / 128, CM / 128), blk, 0, stream>>>(
            z2, HDP, W3b, HDP, FF, nullptr, 0, x, 5, c * CM,
            b3, nullptr, rm3, rv3, g3, be3, seed, sums);
    }

    // 4) decode (persistent, stage-specialized, wbl2-free handoffs)
    decode_persistent<<<dim3(DNB), blk, 0, stream>>>(
        seed, hs, Wihb, Whhb, W1b, W2b, W3b,
        hdec, zd1, zd2, xg, xgb, cnt,
        b_ih, b_hh,
        b1, rm1, rv1, g1, be1,
        b2, rm2, rv2, g2, be2,
        b3, rm3, rv3, g3, be3);

    // 5) gather + finalize
    gather_kernel<<<dim3(BF / 256), blk, 0, stream>>>(xg, tgap, x, out, sums);
    finalize_kernel<<<dim3(1), dim3(64), 0, stream>>>(sums, out);
}

// Round 4
// 1869.499 us; speedup vs baseline: 1.1641x; 1.0359x over previous
//
#include <hip/hip_runtime.h>
#include <math.h>

// forecastRNN on MI355X, round 10.
// Decode: PRIVATE PER-CONSUMER INBOX LINES + PF=16 A-ring.
// Rounds 7-9 (hierarchy, direct group lines, wbl2-free stores) each gained
// ~5%: the surviving term is the RMW-POLL QUEUE on shared lines. A line
// with ~24 pollers doing serialized same-address RMWs at the TCC is always
// saturated; the producer's increment and the consumer's detecting poll
// both queue behind junk polls. Fix: each decode block polls ITS OWN
// 256B-spaced line (1 poller/line); producers fan out one fire-and-forget
// relaxed agent fetch_add per consumer block (8-24, issued in parallel by
// threads 0..n-1 after the post-epilogue barrier; sc1 data stores already
// drained). Cell's line carries cell-done(+8/gap) and l3-done(+16/gap);
// causality makes thresholds 24g-16 (h-half) / 24g (x-half) exact.
// Also PF 8->16 in frag_gemm: 1 block/CU = 1 wave/SIMD, pure ILP; 15
// in-flight A-chunks (~960cy cover) vs L3 latency ~900cy, GEMM ~1.7->0.9us.
// RNN / large-GEMM / conversion kernels unchanged.

typedef unsigned short ushort_t;
typedef __attribute__((ext_vector_type(8))) short short8;
typedef __attribute__((ext_vector_type(4))) float f32x4;

#define BB 512
#define TT 65
#define TN 64
#define FF 512
#define HD 1000
#define HDP 1024
#define EPSBN 1e-5f
#define BF (BB*FF)          // 262144
#define MALL (BB*TN)        // 32768
#define CH 4
#define CM (MALL/CH)        // 8192
#define HP 520              // LDS h row stride (1040 B)
#define DNB 224

// sync: private inbox per decode block: cnt + blockid*64 (256 B apart).
// increments/gap: cell line +24 (8 cell-done + 16 l3-done);
// L1 +8 (cell-done); L2 +16 (l1-done); L3 +16 (l2-done).
#define SYNC_WORDS 16384

__device__ __forceinline__ ushort_t f2bf(float f) {
    union { float f; unsigned u; } v; v.f = f;
    unsigned r = v.u + 0x7FFFu + ((v.u >> 16) & 1u);
    return (ushort_t)(r >> 16);
}

__device__ __forceinline__ float ftanh(float x) {
    const float e = __expf(2.f * x);
    return 1.f - 2.f / (e + 1.f);
}

__device__ __forceinline__ void ld16(const ushort_t* g, ushort_t* l) {
    __builtin_amdgcn_global_load_lds(
        (const __attribute__((address_space(1))) unsigned*)g,
        (__attribute__((address_space(3))) unsigned*)l, 16, 0, 0);
}

// agent-scope coherent stores (sc1 write-through to L3; no dirty L2 lines)
__device__ __forceinline__ void st_u32(unsigned* p, unsigned v) {
    __hip_atomic_store(p, v, __ATOMIC_RELAXED, __HIP_MEMORY_SCOPE_AGENT);
}
__device__ __forceinline__ void st_u64(unsigned long long* p,
                                       unsigned long long v) {
    __hip_atomic_store(p, v, __ATOMIC_RELAXED, __HIP_MEMORY_SCOPE_AGENT);
}

// ---------------------------------------------------------------------------
// Large-GEMM kernel (XW precompute + autoenc), 128x128 tile, BK=32.
// ---------------------------------------------------------------------------
__global__ __launch_bounds__(256)
void mfma_gemm(const ushort_t* __restrict__ A, long a_rs,
               const ushort_t* __restrict__ W, int K, int Nreal,
               void* __restrict__ outv, long o_rs,
               const float* __restrict__ aux, int epi, int mbase,
               const float* __restrict__ p1, const float* __restrict__ p2,
               const float* __restrict__ rm, const float* __restrict__ rv,
               const float* __restrict__ gg, const float* __restrict__ be,
               ushort_t* __restrict__ out2, float* __restrict__ sums)
{
    __shared__ ushort_t As[128 * 32];
    __shared__ ushort_t Bs[128 * 32];
    __shared__ float red[256];

    const int tid  = threadIdx.x;
    const int wave = tid >> 6, lane = tid & 63;
    const int wm = wave >> 1, wn = wave & 1;
    const int tileM = blockIdx.y * 128, tileN = blockIdx.x * 128;

    f32x4 acc[4][4] = {};
    const int srow = lane >> 2;
    const int skb  = (lane & 3) * 8;

    for (int kt = 0; kt < K; kt += 32) {
        __syncthreads();
#pragma unroll
        for (int s = 0; s < 2; ++s) {
            const int instr = wave * 2 + s;
            const int row = instr * 16 + srow;
            ld16(A + (size_t)(tileM + row) * a_rs + kt + skb, &As[instr * 512]);
            ld16(W + (size_t)(tileN + row) * (size_t)K + kt + skb, &Bs[instr * 512]);
        }
        __syncthreads();
        const int lr = lane & 15;
        const int lk = (lane >> 4) * 8;
        short8 af[4], bfr[4];
#pragma unroll
        for (int i = 0; i < 4; ++i)
            af[i] = *(const short8*)&As[(wm * 64 + i * 16 + lr) * 32 + lk];
#pragma unroll
        for (int j = 0; j < 4; ++j)
            bfr[j] = *(const short8*)&Bs[(wn * 64 + j * 16 + lr) * 32 + lk];
#pragma unroll
        for (int i = 0; i < 4; ++i)
#pragma unroll
            for (int j = 0; j < 4; ++j)
                acc[i][j] = __builtin_amdgcn_mfma_f32_16x16x32_bf16(
                    af[i], bfr[j], acc[i][j], 0, 0, 0);
    }

    const int lr = lane & 15;
    const int rquad = (lane >> 4) * 4;
    float lsum = 0.f;
#pragma unroll
    for (int i = 0; i < 4; ++i) {
#pragma unroll
        for (int r = 0; r < 4; ++r) {
            const int grow = tileM + wm * 64 + i * 16 + rquad + r;
#pragma unroll
            for (int j = 0; j < 4; ++j) {
                const int gcol = tileN + wn * 64 + j * 16 + lr;
                const float v = acc[i][j][r];
                if (epi == 0) {
                    ((float*)outv)[(size_t)grow * o_rs + gcol] = v + p1[gcol] + p2[gcol];
                } else if (epi == 2) {
                    float o = 0.f;
                    if (gcol < Nreal) {
                        const float s = gg[gcol] * rsqrtf(rv[gcol] + EPSBN);
                        o = (v + p1[gcol] - rm[gcol]) * s + be[gcol];
                    }
                    ((ushort_t*)outv)[(size_t)grow * o_rs + gcol] = f2bf(o);
                } else { // epi 5
                    const float s = gg[gcol] * rsqrtf(rv[gcol] + EPSBN);
                    const float o = (v + p1[gcol] - rm[gcol]) * s + be[gcol];
                    const int gm = mbase + grow;
                    const int b = gm >> 6, tau = gm & 63;
                    if (tau < 63) {
                        const float d = o - aux[((size_t)b * TT + tau + 1) * FF + gcol];
                        lsum += d * d;
                    } else {
                        out2[(size_t)b * FF + gcol] = f2bf(o);
                    }
                }
            }
        }
    }
    if (epi == 5) {
        red[tid] = lsum;
        __syncthreads();
        for (int o = 128; o > 0; o >>= 1) {
            if (tid < o) red[tid] += red[tid + o];
            __syncthreads();
        }
        if (tid == 0) atomicAdd(&sums[0], red[0]);
    }
}

// ---------------------------------------------------------------------------
// Persistent recurrence: 32 blocks x 16 batch rows. 3-slot W prefetch ring
// (2 chunks ahead), XW register prefetch, fast tanh. 1 barrier/step.
// ---------------------------------------------------------------------------
__global__ __launch_bounds__(256)
void rnn_persistent(const ushort_t* __restrict__ Whh,
                    const float* __restrict__ XW,
                    ushort_t* __restrict__ hs)
{
    __shared__ ushort_t hb[2][16 * HP];
    const int tid = threadIdx.x, wave = tid >> 6, lane = tid & 63;
    const int b0 = blockIdx.x * 16;
    const int lr = lane & 15, lq = lane >> 4;
    const int c0 = wave * 128;

    // t = 0: h = tanh(XW_0)
    for (int it = 0; it < 8; ++it) {
        const int e = (it * 256 + tid) * 4;
        const int row = e >> 9, col = e & 511;
        const size_t gi = ((size_t)(b0 + row) * TN) * FF + col;
        const float4 v = *(const float4*)&XW[gi];
        const ushort_t h0 = f2bf(ftanh(v.x)), h1 = f2bf(ftanh(v.y));
        const ushort_t h2 = f2bf(ftanh(v.z)), h3 = f2bf(ftanh(v.w));
        hb[0][row * HP + col + 0] = h0; hb[0][row * HP + col + 1] = h1;
        hb[0][row * HP + col + 2] = h2; hb[0][row * HP + col + 3] = h3;
        unsigned r0 = (unsigned)h0 | ((unsigned)h1 << 16);
        unsigned r1 = (unsigned)h2 | ((unsigned)h3 << 16);
        *(uint2*)&hs[gi] = make_uint2(r0, r1);
    }
    __syncthreads();

    f32x4 acc[8];
    short8 wf[3][8];
    short8 af[3];
    float xw[8][4];

    for (int t = 1; t < TN; ++t) {
        const ushort_t* hcur = hb[(t - 1) & 1];

        // prologue: chunks 0,1 into slots 0,1
#pragma unroll
        for (int s = 0; s < 2; ++s) {
            const int kk = s * 32 + lq * 8;
            af[s] = *(const short8*)&hcur[lr * HP + kk];
#pragma unroll
            for (int j = 0; j < 8; ++j)
                wf[s][j] = *(const short8*)(Whh + (size_t)(c0 + j * 16 + lr) * FF + kk);
        }
        // XW register prefetch for this step (HBM; overlaps the K-loop)
#pragma unroll
        for (int j = 0; j < 8; ++j)
#pragma unroll
            for (int r = 0; r < 4; ++r)
                xw[j][r] = XW[((size_t)(b0 + lq * 4 + r) * TN + t) * FF
                              + c0 + j * 16 + lr];
#pragma unroll
        for (int j = 0; j < 8; ++j) acc[j] = (f32x4){0.f, 0.f, 0.f, 0.f};

#pragma unroll
        for (int kc = 0; kc < 16; ++kc) {
            if (kc + 2 < 16) {
                const int slot = (kc + 2) % 3;
                const int kk = (kc + 2) * 32 + lq * 8;
                af[slot] = *(const short8*)&hcur[lr * HP + kk];
#pragma unroll
                for (int j = 0; j < 8; ++j)
                    wf[slot][j] = *(const short8*)
                        (Whh + (size_t)(c0 + j * 16 + lr) * FF + kk);
            }
            const int b = kc % 3;
#pragma unroll
            for (int j = 0; j < 8; ++j)
                acc[j] = __builtin_amdgcn_mfma_f32_16x16x32_bf16(
                    af[b], wf[b][j], acc[j], 0, 0, 0);
        }

        ushort_t* hnxt = hb[t & 1];
#pragma unroll
        for (int j = 0; j < 8; ++j) {
            const int col = c0 + j * 16 + lr;
#pragma unroll
            for (int r = 0; r < 4; ++r) {
                const int row = lq * 4 + r;
                const size_t gi = ((size_t)(b0 + row) * TN + t) * FF + col;
                const ushort_t hv = f2bf(ftanh(acc[j][r] + xw[j][r]));
                hnxt[row * HP + col] = hv;
                hs[gi] = hv;
            }
        }
        __syncthreads();
    }
}

// ---------------------------------------------------------------------------
// Producer/consumer sync (decode). Private inbox per consumer block:
// ONE poller per line; producers fan out fire-and-forget relaxed RMWs.
// Data stores are agent-coherent (sc1) so no release fence / wbl2 anywhere.
// ---------------------------------------------------------------------------
__device__ __forceinline__ void wait_line(unsigned* __restrict__ line,
                                          unsigned tgt)
{
    if (threadIdx.x == 0) {
        while (__hip_atomic_fetch_add(line, 0u, __ATOMIC_RELAXED,
                                      __HIP_MEMORY_SCOPE_AGENT) < tgt)
            __builtin_amdgcn_s_sleep(1);
        (void)__hip_atomic_load(line, __ATOMIC_ACQUIRE, __HIP_MEMORY_SCOPE_AGENT);
    }
    __syncthreads();
}

// drain own stores, block-barrier (all stores at L3), then threads 0..n-1
// each signal one consumer line (fire-and-forget).
__device__ __forceinline__ void signal_fanout(unsigned* __restrict__ cnt,
                                              int line_id, int n)
{
    asm volatile("s_waitcnt vmcnt(0)" ::: "memory");
    __syncthreads();
    if ((int)threadIdx.x < n)
        __hip_atomic_fetch_add(cnt + (size_t)line_id * 64, 1u,
                               __ATOMIC_RELAXED, __HIP_MEMORY_SCOPE_AGENT);
}

// load a weight slice (rows [n0,n0+rows) of W[*, K]) into LDS, row stride wrs
__device__ __forceinline__ void load_wslice(const ushort_t* __restrict__ W,
                                            int n0, int K, int rows,
                                            ushort_t* dst, int wrs)
{
    const int nch = K >> 3;
    const int total = rows * nch;
    for (int c = threadIdx.x; c < total; c += 256) {
        const int row = c / nch, col = (c - row * nch) * 8;
        *(uint4*)&dst[(size_t)row * wrs + col] =
            *(const uint4*)&W[(size_t)(n0 + row) * K + col];
    }
}

// fragment GEMM: acc[MT][4] over rows mrow0+mt*16, 64 cols (4 ntiles).
// PF-deep A-register ring (PF=16: ~15 iterations of latency cover; 1
// block/CU = 1 wave/SIMD, so cover must come from ILP, not TLP).
template <int MT, int NCH1, int NCH2, int PF = 16>
__device__ __forceinline__ void frag_gemm(
    const ushort_t* __restrict__ A1, long a1_rs,
    const ushort_t* __restrict__ A2, long a2_rs,
    const ushort_t* w1, const ushort_t* w2, int wrs,
    int mrow0, f32x4 (&acc)[MT][4])
{
    const int lane = threadIdx.x & 63;
    const int lr = lane & 15, lk = (lane >> 4) * 8;
    constexpr int NCH = NCH1 + NCH2;
    constexpr int PD = (PF < NCH) ? PF : NCH;
    short8 a[PD][MT];

    auto aload = [&](int kc, int slot) {
        const bool p2 = (kc >= NCH1);
        const ushort_t* Ap = p2 ? A2 : A1;
        const long rs = p2 ? a2_rs : a1_rs;
        const int kk = (p2 ? kc - NCH1 : kc) * 32 + lk;
#pragma unroll
        for (int mt = 0; mt < MT; ++mt)
            a[slot][mt] = *(const short8*)(Ap + (size_t)(mrow0 + mt * 16 + lr) * rs + kk);
    };
#pragma unroll
    for (int p = 0; p < PD - 1; ++p) aload(p, p);
#pragma unroll
    for (int kc = 0; kc < NCH; ++kc) {
        if (kc + PD - 1 < NCH) aload(kc + PD - 1, (kc + PD - 1) % PD);
        const bool p2 = (kc >= NCH1);
        const ushort_t* wl = p2 ? w2 : w1;
        const int kk = (p2 ? kc - NCH1 : kc) * 32 + lk;
        short8 wfr[4];
#pragma unroll
        for (int nt = 0; nt < 4; ++nt)
            wfr[nt] = *(const short8*)&wl[(size_t)(nt * 16 + lr) * wrs + kk];
#pragma unroll
        for (int mt = 0; mt < MT; ++mt)
#pragma unroll
            for (int nt = 0; nt < 4; ++nt)
                acc[mt][nt] = __builtin_amdgcn_mfma_f32_16x16x32_bf16(
                    a[kc % PD][mt], wfr[nt], acc[mt][nt], 0, 0, 0);
    }
}

// epilogues: hoisted per-block constants; outputs written as agent-coherent
// (sc1) atomic stores. bf16 pairs packed to 4B via one shfl_xor; f32 pairs
// to 8B. Even lanes store.
template <int MT>
__device__ __forceinline__ void ep_tanh_pre(f32x4 (&acc)[MT][4], int mrow0,
                                            int gc0, const float (&bb)[4],
                                            ushort_t* __restrict__ obf, long o_rs)
{
    const int lane = threadIdx.x & 63;
    const int lr = lane & 15, rq = (lane >> 4) * 4;
    const bool even = !(lane & 1);
#pragma unroll
    for (int mt = 0; mt < MT; ++mt)
#pragma unroll
        for (int nt = 0; nt < 4; ++nt) {
            const int gcol = gc0 + nt * 16 + lr;
#pragma unroll
            for (int r = 0; r < 4; ++r) {
                const int grow = mrow0 + mt * 16 + rq + r;
                const unsigned v =
                    (unsigned)f2bf(ftanh(acc[mt][nt][r] + bb[nt]));
                const unsigned pv = __shfl_xor(v, 1);
                if (even)
                    st_u32((unsigned*)&obf[(size_t)grow * o_rs + gcol],
                           v | (pv << 16));
            }
        }
}

template <int MT>
__device__ __forceinline__ void ep_bn_pre(f32x4 (&acc)[MT][4], int mrow0,
                                          int gc0, const float (&s)[4],
                                          const float (&c)[4],
                                          ushort_t* __restrict__ obf, long o_rs,
                                          float* __restrict__ of32)
{
    const int lane = threadIdx.x & 63;
    const int lr = lane & 15, rq = (lane >> 4) * 4;
    const bool even = !(lane & 1);
#pragma unroll
    for (int mt = 0; mt < MT; ++mt)
#pragma unroll
        for (int nt = 0; nt < 4; ++nt) {
            const int gcol = gc0 + nt * 16 + lr;
#pragma unroll
            for (int r = 0; r < 4; ++r) {
                const int grow = mrow0 + mt * 16 + rq + r;
                const float o = acc[mt][nt][r] * s[nt] + c[nt];
                const unsigned v = (unsigned)f2bf(o);
                const unsigned pv = __shfl_xor(v, 1);
                union { float f; unsigned u; } ou; ou.f = o;
                const unsigned po = __shfl_xor(ou.u, 1);
                if (even) {
                    st_u32((unsigned*)&obf[(size_t)grow * o_rs + gcol],
                           v | (pv << 16));
                    if (of32)
                        st_u64((unsigned long long*)
                                   &of32[(size_t)grow * o_rs + gcol],
                               (unsigned long long)ou.u |
                                   ((unsigned long long)po << 32));
                }
            }
        }
}

// ---------------------------------------------------------------------------
// Persistent decode: 224 stage-specialized blocks, weights resident in LDS.
// roles: [0,32) cell, [32,96) L1, [96,160) L2, [160,224) L3.
// Private inbox line = cnt + blockid*64.
// ---------------------------------------------------------------------------
__global__ __launch_bounds__(256)
void decode_persistent(const ushort_t* __restrict__ seed,
                       const ushort_t* __restrict__ hs,
                       const ushort_t* __restrict__ Wih,
                       const ushort_t* __restrict__ Whh,
                       const ushort_t* __restrict__ W1b,
                       const ushort_t* __restrict__ W2b,
                       const ushort_t* __restrict__ W3b,
                       ushort_t* __restrict__ hdec,
                       ushort_t* __restrict__ zd1, ushort_t* __restrict__ zd2,
                       float* __restrict__ xg, ushort_t* __restrict__ xgb,
                       unsigned* __restrict__ cnt,
                       const float* __restrict__ b_ih, const float* __restrict__ b_hh,
                       const float* __restrict__ b1, const float* __restrict__ rm1,
                       const float* __restrict__ rv1, const float* __restrict__ g1,
                       const float* __restrict__ be1,
                       const float* __restrict__ b2, const float* __restrict__ rm2,
                       const float* __restrict__ rv2, const float* __restrict__ g2,
                       const float* __restrict__ be2,
                       const float* __restrict__ b3, const float* __restrict__ rm3,
                       const float* __restrict__ rv3, const float* __restrict__ g3,
                       const float* __restrict__ be3)
{
    __shared__ ushort_t wlds[66560];   // 133,120 B -> 1 block/CU
    const int id = blockIdx.x;
    const int wave = threadIdx.x >> 6;
    const int lane = threadIdx.x & 63;
    const int lr = lane & 15;
    const int tid = threadIdx.x;
    unsigned* own = cnt + (size_t)id * 64;

    if (id < 32) {
        // ---- cell role: 4 rgroups x 8 cgroups; 128 rows x 64 cols each ----
        // own line: +8/gap cell-done(group rg) and +16/gap l3-done(groups
        // {2rg,2rg+1}) -> after cell-done(k): 24k+8; after l3-done(k): 24k+24
        const int rg = id >> 3, cg = id & 7;
        load_wslice(Wih, cg * 64, FF, 64, wlds, HP);
        load_wslice(Whh, cg * 64, FF, 64, wlds + 64 * HP, HP);
        float bb[4];
#pragma unroll
        for (int nt = 0; nt < 4; ++nt) {
            const int gcol = cg * 64 + nt * 16 + lr;
            bb[nt] = b_ih[gcol] + b_hh[gcol];
        }
        __syncthreads();
        const int m0 = rg * 128 + wave * 32;
        // signal fanout: t<8 -> cell group rg (ids rg*8+t);
        //                8<=t<24 -> L1 rgroups {2rg,2rg+1} (ids 32+16rg+(t-8))
        const int sig_id = (tid < 8) ? (rg * 8 + tid)
                                     : (32 + 16 * rg + (tid - 8));
        for (int g = 0; g < 16; ++g) {
            f32x4 acc[2][4] = {};
            // h-half: needs only previous cell output (overlaps prev gap's
            // L1/L2/L3 stages).
            if (g) wait_line(own, 24u * g - 16u);
            const ushort_t* hprev = g ? (hdec + (size_t)((g - 1) & 1) * BF)
                                      : (hs + (size_t)63 * FF);
            const long h_rs = g ? (long)FF : (long)(TN * FF);
            frag_gemm<2, 16, 0>(hprev, h_rs, nullptr, 0,
                                wlds + 64 * HP, nullptr, HP, m0, acc);
            // x-half: critical path, released by L3 groups {2rg,2rg+1}.
            if (g) wait_line(own, 24u * g);
            const ushort_t* xprev = g ? (xgb + (size_t)(g - 1) * BF) : seed;
            frag_gemm<2, 16, 0>(xprev, FF, nullptr, 0,
                                wlds, nullptr, HP, m0, acc);
            ushort_t* hnew = hdec + (size_t)(g & 1) * BF;
            ep_tanh_pre<2>(acc, m0, cg * 64, bb, hnew, FF);
            signal_fanout(cnt, sig_id, 24);
        }
    } else if (id < 96) {
        // ---- L1 role: 8 rgroups x 8 cgroups; 64 rows x 128 cols each ----
        const int lidx = id - 32;
        const int rg1 = lidx >> 3, cg = lidx & 7;
        load_wslice(W1b, cg * 128, FF, 128, wlds, HP);
        const int gc0 = cg * 128 + (wave & 1) * 64;
        float sA[4], cA[4];
#pragma unroll
        for (int nt = 0; nt < 4; ++nt) {
            const int gcol = gc0 + nt * 16 + lr;
            const bool ok = gcol < HD;
            sA[nt] = ok ? g1[gcol] * rsqrtf(rv1[gcol] + EPSBN) : 0.f;
            cA[nt] = ok ? (b1[gcol] - rm1[gcol]) * sA[nt] + be1[gcol] : 0.f;
        }
        __syncthreads();
        const int m0 = rg1 * 64 + (wave >> 1) * 32;
        // signal: L2 rgroup rg1>>1, all 16 cgroups (ids 96+(rg1>>1)*16+t)
        const int sig_id = 96 + (rg1 >> 1) * 16 + tid;
        for (int g = 0; g < 16; ++g) {
            wait_line(own, 8u * (g + 1));
            const ushort_t* hnew = hdec + (size_t)(g & 1) * BF;
            f32x4 acc[2][4] = {};
            frag_gemm<2, 16, 0>(hnew, FF, nullptr, 0,
                                wlds + (wave & 1) * 64 * HP, nullptr, HP, m0, acc);
            ep_bn_pre<2>(acc, m0, gc0, sA, cA, zd1, HDP, nullptr);
            signal_fanout(cnt, sig_id, 16);
        }
    } else if (id < 160) {
        // ---- L2 role: 4 rgroups x 16 cgroups; 128 rows x 64 cols each ----
        const int lidx = id - 96;
        const int rg2 = lidx >> 4, cg = lidx & 15;
        load_wslice(W2b, cg * 64, HDP, 64, wlds, 1032);
        const int gc0 = cg * 64;
        float sA[4], cA[4];
#pragma unroll
        for (int nt = 0; nt < 4; ++nt) {
            const int gcol = gc0 + nt * 16 + lr;
            const bool ok = gcol < HD;
            sA[nt] = ok ? g2[gcol] * rsqrtf(rv2[gcol] + EPSBN) : 0.f;
            cA[nt] = ok ? (b2[gcol] - rm2[gcol]) * sA[nt] + be2[gcol] : 0.f;
        }
        __syncthreads();
        const int m0 = rg2 * 128 + wave * 32;
        // signal: L3 rgroups {2rg2,2rg2+1}, 8 cgroups each
        // (ids 160+2*rg2*8+t, t<16)
        const int sig_id = 160 + 16 * rg2 + tid;
        for (int g = 0; g < 16; ++g) {
            wait_line(own, 16u * (g + 1));
            f32x4 acc[2][4] = {};
            frag_gemm<2, 32, 0>(zd1, HDP, nullptr, 0,
                                wlds, nullptr, 1032, m0, acc);
            ep_bn_pre<2>(acc, m0, gc0, sA, cA, zd2, HDP, nullptr);
            signal_fanout(cnt, sig_id, 16);
        }
    } else {
        // ---- L3 role: 8 rgroups x 8 cgroups; 64 rows x 64 cols each ----
        const int lidx = id - 160;
        const int rg3 = lidx >> 3, cg = lidx & 7;
        load_wslice(W3b, cg * 64, HDP, 64, wlds, 1032);
        const int gc0 = cg * 64;
        float sA[4], cA[4];
#pragma unroll
        for (int nt = 0; nt < 4; ++nt) {
            const int gcol = gc0 + nt * 16 + lr;   // < 512 always
            sA[nt] = g3[gcol] * rsqrtf(rv3[gcol] + EPSBN);
            cA[nt] = (b3[gcol] - rm3[gcol]) * sA[nt] + be3[gcol];
        }
        __syncthreads();
        const int m0 = rg3 * 64 + wave * 16;
        // signal: cell group rg3>>1, 8 blocks (ids (rg3>>1)*8+t, t<8)
        const int sig_id = (rg3 >> 1) * 8 + tid;
        for (int g = 0; g < 16; ++g) {
            wait_line(own, 16u * (g + 1));
            f32x4 acc[1][4] = {};
            frag_gemm<1, 32, 0>(zd2, HDP, nullptr, 0,
                                wlds, nullptr, 1032, m0, acc);
            ep_bn_pre<1>(acc, m0, gc0, sA, cA,
                         xgb + (size_t)g * BF, FF, xg + (size_t)g * BF);
            signal_fanout(cnt, sig_id, 8);
        }
    }
}

// ---------------------------------------------------------------------------
__global__ void zero_init(float* __restrict__ sums, unsigned* __restrict__ cnt)
{
    const int i = threadIdx.x + blockIdx.x * blockDim.x;
    if (i < 2) sums[i] = 0.f;
    for (int k = i; k < SYNC_WORDS; k += blockDim.x * gridDim.x) cnt[k] = 0u;
}

__global__ void conv_x(const float* __restrict__ x, ushort_t* __restrict__ xb)
{
    const int i = blockIdx.x * blockDim.x + threadIdx.x;
    if (i < MALL * FF / 4) {
        const int e = i * 4;
        const int m = e >> 9;
        const int f = e & (FF - 1);
        const int b = m >> 6, t = m & 63;
        const float4 v = *(const float4*)&x[((size_t)b * TT + t) * FF + f];
        unsigned r0 = (unsigned)f2bf(v.x) | ((unsigned)f2bf(v.y) << 16);
        unsigned r1 = (unsigned)f2bf(v.z) | ((unsigned)f2bf(v.w) << 16);
        *(uint2*)&xb[e] = make_uint2(r0, r1);
    }
}

__global__ void conv_w(const float* __restrict__ src, ushort_t* __restrict__ dst,
                       int Nsrc, int Ksrc, int Npad, int Kpad)
{
    const int i = blockIdx.x * blockDim.x + threadIdx.x;
    if (i < Npad * Kpad) {
        const int n = i / Kpad, k = i - n * Kpad;
        const float v = (n < Nsrc && k < Ksrc) ? src[(size_t)n * Ksrc + k] : 0.f;
        dst[i] = f2bf(v);
    }
}

__global__ void gather_kernel(const float* __restrict__ xgaps,
                              const int* __restrict__ tgap,
                              const float* __restrict__ x,
                              float* __restrict__ out,
                              float* __restrict__ sums)
{
    const int i = blockIdx.x * blockDim.x + threadIdx.x;
    float s = 0.f;
    if (i < BF) {
        const int b = i >> 9, f = i & (FF - 1);
        const int g = tgap[b] - 1;
        const float v = xgaps[((size_t)g * BB + b) * FF + f];
        out[i] = v;
        const float d = v - x[((size_t)b * TT + (TT - 1)) * FF + f];
        s = d * d;
    }
    __shared__ float red[256];
    red[threadIdx.x] = s;
    __syncthreads();
    for (int o = 128; o > 0; o >>= 1) {
        if (threadIdx.x < o) red[threadIdx.x] += red[threadIdx.x + o];
        __syncthreads();
    }
    if (threadIdx.x == 0) atomicAdd(&sums[1], red[0]);
}

__global__ void finalize_kernel(const float* __restrict__ sums,
                                float* __restrict__ out)
{
    if (threadIdx.x == 0 && blockIdx.x == 0) {
        const double n1 = 63.0 * 512.0 * 512.0;
        const double n2 = 512.0 * 512.0;
        out[BF] = (float)((double)sums[0] / (n1 * n1) +
                          (double)sums[1] / (n2 * n2));
    }
}

extern "C" void kernel_launch(void* const* d_in, const int* in_sizes, int n_in,
                              void* d_out, int out_size, void* d_ws, size_t ws_size,
                              hipStream_t stream)
{
    const float* x    = (const float*)d_in[0];
    const int*   tgap = (const int*)d_in[1];
    const float* W_ih = (const float*)d_in[2];
    const float* W_hh = (const float*)d_in[3];
    const float* b_ih = (const float*)d_in[4];
    const float* b_hh = (const float*)d_in[5];
    const float* W1 = (const float*)d_in[6];
    const float* b1 = (const float*)d_in[7];
    const float* g1 = (const float*)d_in[8];
    const float* be1 = (const float*)d_in[9];
    const float* rm1 = (const float*)d_in[10];
    const float* rv1 = (const float*)d_in[11];
    const float* W2 = (const float*)d_in[12];
    const float* b2 = (const float*)d_in[13];
    const float* g2 = (const float*)d_in[14];
    const float* be2 = (const float*)d_in[15];
    const float* rm2 = (const float*)d_in[16];
    const float* rv2 = (const float*)d_in[17];
    const float* W3 = (const float*)d_in[18];
    const float* b3 = (const float*)d_in[19];
    const float* g3 = (const float*)d_in[20];
    const float* be3 = (const float*)d_in[21];
    const float* rm3 = (const float*)d_in[22];
    const float* rv3 = (const float*)d_in[23];
    float* out = (float*)d_out;

    char* p = (char*)d_ws;
    auto take = [&](size_t bytes) -> char* {
        char* r = p; p += (bytes + 63) & ~(size_t)63; return r;
    };
    float*    XWbuf = (float*)take((size_t)MALL * FF * 4);      // 67.1 MB
    ushort_t* hs    = (ushort_t*)take((size_t)MALL * FF * 2);   // 33.5 MB
    ushort_t* xbf   = (ushort_t*)take((size_t)MALL * FF * 2);   // 33.5 MB
    ushort_t* z1    = (ushort_t*)take((size_t)CM * HDP * 2);    // 16.8 MB
    ushort_t* z2    = (ushort_t*)take((size_t)CM * HDP * 2);    // 16.8 MB
    float*    xg    = (float*)take((size_t)16 * BF * 4);        // 16.8 MB
    ushort_t* xgb   = (ushort_t*)take((size_t)16 * BF * 2);     //  8.4 MB
    ushort_t* seed  = (ushort_t*)take((size_t)BF * 2);
    ushort_t* hdec  = (ushort_t*)take((size_t)2 * BF * 2);
    ushort_t* zd1   = (ushort_t*)take((size_t)BB * HDP * 2);
    ushort_t* zd2   = (ushort_t*)take((size_t)BB * HDP * 2);
    ushort_t* Wihb  = (ushort_t*)take((size_t)FF * FF * 2);
    ushort_t* Whhb  = (ushort_t*)take((size_t)FF * FF * 2);
    ushort_t* W1b   = (ushort_t*)take((size_t)HDP * FF * 2);
    ushort_t* W2b   = (ushort_t*)take((size_t)HDP * HDP * 2);
    ushort_t* W3b   = (ushort_t*)take((size_t)FF * HDP * 2);
    float*    sums  = (float*)take(16 * 4);
    unsigned* cnt   = (unsigned*)take((size_t)SYNC_WORDS * 4);

    const dim3 blk(256);

    zero_init<<<dim3(8), blk, 0, stream>>>(sums, cnt);
    conv_x<<<dim3(MALL * FF / 4 / 256), blk, 0, stream>>>(x, xbf);
    conv_w<<<dim3((FF * FF + 255) / 256), blk, 0, stream>>>(W_ih, Wihb, FF, FF, FF, FF);
    conv_w<<<dim3((FF * FF + 255) / 256), blk, 0, stream>>>(W_hh, Whhb, FF, FF, FF, FF);
    conv_w<<<dim3((HDP * FF + 255) / 256), blk, 0, stream>>>(W1, W1b, HD, FF, HDP, FF);
    conv_w<<<dim3((HDP * HDP + 255) / 256), blk, 0, stream>>>(W2, W2b, HD, HD, HDP, HDP);
    conv_w<<<dim3((FF * HDP + 255) / 256), blk, 0, stream>>>(W3, W3b, FF, HD, FF, HDP);

    // 1) XW = x @ W_ih^T + b_ih + b_hh -> fp32
    mfma_gemm<<<dim3(FF / 128, MALL / 128), blk, 0, stream>>>(
        xbf, FF, Wihb, FF, FF, XWbuf, FF, nullptr, 0, 0,
        b_ih, b_hh, nullptr, nullptr, nullptr, nullptr, nullptr, nullptr);

    // 2) recurrence (persistent, batch-split, register W-stream)
    rnn_persistent<<<dim3(BB / 16), blk, 0, stream>>>(Whhb, XWbuf, hs);

    // 3) autoenc over 32768 rows in 4 chunks
    for (int c = 0; c < CH; ++c) {
        const ushort_t* Ac = hs + (size_t)c * CM * FF;
        mfma_gemm<<<dim3(HDP / 128, CM / 128), blk, 0, stream>>>(
            Ac, FF, W1b, FF, HD, z1, HDP, nullptr, 2, 0,
            b1, nullptr, rm1, rv1, g1, be1, nullptr, nullptr);
        mfma_gemm<<<dim3(HDP / 128, CM / 128), blk, 0, stream>>>(
            z1, HDP, W2b, HDP, HD, z2, HDP, nullptr, 2, 0,
            b2, nullptr, rm2, rv2, g2, be2, nullptr, nullptr);
        mfma_gemm<<<dim3(FF / 128, CM / 128), blk, 0, stream>>>(
            z2, HDP, W3b, HDP, FF, nullptr, 0, x, 5, c * CM,
            b3, nullptr, rm3, rv3, g3, be3, seed, sums);
    }

    // 4) decode (persistent, stage-specialized, private-inbox handoffs)
    decode_persistent<<<dim3(DNB), blk, 0, stream>>>(
        seed, hs, Wihb, Whhb, W1b, W2b, W3b,
        hdec, zd1, zd2, xg, xgb, cnt,
        b_ih, b_hh,
        b1, rm1, rv1, g1, be1,
        b2, rm2, rv2, g2, be2,
        b3, rm3, rv3, g3, be3);

    // 5) gather + finalize
    gather_kernel<<<dim3(BF / 256), blk, 0, stream>>>(xg, tgap, x, out, sums);
    finalize_kernel<<<dim3(1), dim3(64), 0, stream>>>(sums, out);
}

// Round 6
// 1502.442 us; speedup vs baseline: 1.4485x; 1.2443x over previous
//
#include <hip/hip_runtime.h>
#include <math.h>

// forecastRNN on MI355X, round 12.
// Round 11's affine collapse had a MATH BUG: A must be S3 W3 S2 W2 S1 W1,
// but W3 was used unscaled (S3 only reached the bias path) -> absmax 0.115.
// Fix: fold s3 into W3 ROWS at conversion (fp32, before bf16 rounding):
//   W3s[n,k] = g3[n]*rsqrt(rv3[n]+eps) * W3[n,k]
// Then Anb = W3s @ Tts and At = Tts @ W3s are the correct A and A^T.
// Everything else identical to round 11:
//   AE(h) = A h + bA; decode h' = tanh(h @ Wf^T + bf), Wf = Wih A + Whh
//   -> row-local 16-step recurrence, zero inter-block sync;
//   x_g batched GEMM afterwards; encoder loss one M=32768 GEMM.

typedef unsigned short ushort_t;
typedef __attribute__((ext_vector_type(8))) short short8;
typedef __attribute__((ext_vector_type(4))) float f32x4;

#define BB 512
#define TT 65
#define TN 64
#define FF 512
#define HD 1000
#define HDP 1024
#define EPSBN 1e-5f
#define BF (BB*FF)          // 262144
#define MALL (BB*TN)        // 32768
#define HP 520              // LDS h row stride (1040 B)

__device__ __forceinline__ ushort_t f2bf(float f) {
    union { float f; unsigned u; } v; v.f = f;
    unsigned r = v.u + 0x7FFFu + ((v.u >> 16) & 1u);
    return (ushort_t)(r >> 16);
}

__device__ __forceinline__ float b2f(ushort_t u) {
    union { unsigned u; float f; } v; v.u = ((unsigned)u) << 16;
    return v.f;
}

__device__ __forceinline__ float ftanh(float x) {
    const float e = __expf(2.f * x);
    return 1.f - 2.f / (e + 1.f);
}

__device__ __forceinline__ void ld16(const ushort_t* g, ushort_t* l) {
    __builtin_amdgcn_global_load_lds(
        (const __attribute__((address_space(1))) unsigned*)g,
        (__attribute__((address_space(3))) unsigned*)l, 16, 0, 0);
}

// ---------------------------------------------------------------------------
// Large-GEMM kernel, 128x128 tile, BK=32. out[m,n] = sum_k A[m,k]*W[n,k].
// epi: 0 f32 v+p1+p2 | 1 bf16 v | 5 loss (o=v+p1; vs aux; seed/out2; sums)
//      6 bf16 v+bf16(out2[m*o_rs+n]) | 7 f32 v+p1 | 8 bf16 masked col-scale
// ---------------------------------------------------------------------------
__global__ __launch_bounds__(256)
void mfma_gemm(const ushort_t* __restrict__ A, long a_rs,
               const ushort_t* __restrict__ W, int K, int Nreal,
               void* __restrict__ outv, long o_rs,
               const float* __restrict__ aux, int epi, int mbase,
               const float* __restrict__ p1, const float* __restrict__ p2,
               const float* __restrict__ rv, const float* __restrict__ gg,
               ushort_t* __restrict__ out2, float* __restrict__ sums)
{
    __shared__ ushort_t As[128 * 32];
    __shared__ ushort_t Bs[128 * 32];
    __shared__ float red[256];

    const int tid  = threadIdx.x;
    const int wave = tid >> 6, lane = tid & 63;
    const int wm = wave >> 1, wn = wave & 1;
    const int tileM = blockIdx.y * 128, tileN = blockIdx.x * 128;

    f32x4 acc[4][4] = {};
    const int srow = lane >> 2;
    const int skb  = (lane & 3) * 8;

    for (int kt = 0; kt < K; kt += 32) {
        __syncthreads();
#pragma unroll
        for (int s = 0; s < 2; ++s) {
            const int instr = wave * 2 + s;
            const int row = instr * 16 + srow;
            ld16(A + (size_t)(tileM + row) * a_rs + kt + skb, &As[instr * 512]);
            ld16(W + (size_t)(tileN + row) * (size_t)K + kt + skb, &Bs[instr * 512]);
        }
        __syncthreads();
        const int lr = lane & 15;
        const int lk = (lane >> 4) * 8;
        short8 af[4], bfr[4];
#pragma unroll
        for (int i = 0; i < 4; ++i)
            af[i] = *(const short8*)&As[(wm * 64 + i * 16 + lr) * 32 + lk];
#pragma unroll
        for (int j = 0; j < 4; ++j)
            bfr[j] = *(const short8*)&Bs[(wn * 64 + j * 16 + lr) * 32 + lk];
#pragma unroll
        for (int i = 0; i < 4; ++i)
#pragma unroll
            for (int j = 0; j < 4; ++j)
                acc[i][j] = __builtin_amdgcn_mfma_f32_16x16x32_bf16(
                    af[i], bfr[j], acc[i][j], 0, 0, 0);
    }

    const int lr = lane & 15;
    const int rquad = (lane >> 4) * 4;
    float lsum = 0.f;
#pragma unroll
    for (int i = 0; i < 4; ++i) {
#pragma unroll
        for (int r = 0; r < 4; ++r) {
            const int grow = tileM + wm * 64 + i * 16 + rquad + r;
#pragma unroll
            for (int j = 0; j < 4; ++j) {
                const int gcol = tileN + wn * 64 + j * 16 + lr;
                const float v = acc[i][j][r];
                if (epi == 0) {
                    ((float*)outv)[(size_t)grow * o_rs + gcol] = v + p1[gcol] + p2[gcol];
                } else if (epi == 1) {
                    ((ushort_t*)outv)[(size_t)grow * o_rs + gcol] = f2bf(v);
                } else if (epi == 6) {
                    const float w0 = b2f(out2[(size_t)grow * o_rs + gcol]);
                    ((ushort_t*)outv)[(size_t)grow * o_rs + gcol] = f2bf(v + w0);
                } else if (epi == 7) {
                    ((float*)outv)[(size_t)grow * o_rs + gcol] = v + p1[gcol];
                } else if (epi == 8) {
                    float o = 0.f;
                    if (gcol < Nreal)
                        o = v * (gg[gcol] * rsqrtf(rv[gcol] + EPSBN));
                    ((ushort_t*)outv)[(size_t)grow * o_rs + gcol] = f2bf(o);
                } else { // epi 5: loss
                    const float o = v + p1[gcol];
                    const int gm = mbase + grow;
                    const int b = gm >> 6, tau = gm & 63;
                    if (tau < 63) {
                        const float d = o - aux[((size_t)b * TT + tau + 1) * FF + gcol];
                        lsum += d * d;
                    } else {
                        out2[(size_t)b * FF + gcol] = f2bf(o);
                    }
                }
            }
        }
    }
    if (epi == 5) {
        red[tid] = lsum;
        __syncthreads();
        for (int o = 128; o > 0; o >>= 1) {
            if (tid < o) red[tid] += red[tid + o];
            __syncthreads();
        }
        if (tid == 0) atomicAdd(&sums[0], red[0]);
    }
}

// ---------------------------------------------------------------------------
// Persistent recurrence (encoder): 32 blocks x 16 batch rows. 3-slot W ring,
// XW register prefetch, fast tanh. Unchanged.
// ---------------------------------------------------------------------------
__global__ __launch_bounds__(256)
void rnn_persistent(const ushort_t* __restrict__ Whh,
                    const float* __restrict__ XW,
                    ushort_t* __restrict__ hs)
{
    __shared__ ushort_t hb[2][16 * HP];
    const int tid = threadIdx.x, wave = tid >> 6, lane = tid & 63;
    const int b0 = blockIdx.x * 16;
    const int lr = lane & 15, lq = lane >> 4;
    const int c0 = wave * 128;

    for (int it = 0; it < 8; ++it) {
        const int e = (it * 256 + tid) * 4;
        const int row = e >> 9, col = e & 511;
        const size_t gi = ((size_t)(b0 + row) * TN) * FF + col;
        const float4 v = *(const float4*)&XW[gi];
        const ushort_t h0 = f2bf(ftanh(v.x)), h1 = f2bf(ftanh(v.y));
        const ushort_t h2 = f2bf(ftanh(v.z)), h3 = f2bf(ftanh(v.w));
        hb[0][row * HP + col + 0] = h0; hb[0][row * HP + col + 1] = h1;
        hb[0][row * HP + col + 2] = h2; hb[0][row * HP + col + 3] = h3;
        unsigned r0 = (unsigned)h0 | ((unsigned)h1 << 16);
        unsigned r1 = (unsigned)h2 | ((unsigned)h3 << 16);
        *(uint2*)&hs[gi] = make_uint2(r0, r1);
    }
    __syncthreads();

    f32x4 acc[8];
    short8 wf[3][8];
    short8 af[3];
    float xw[8][4];

    for (int t = 1; t < TN; ++t) {
        const ushort_t* hcur = hb[(t - 1) & 1];
#pragma unroll
        for (int s = 0; s < 2; ++s) {
            const int kk = s * 32 + lq * 8;
            af[s] = *(const short8*)&hcur[lr * HP + kk];
#pragma unroll
            for (int j = 0; j < 8; ++j)
                wf[s][j] = *(const short8*)(Whh + (size_t)(c0 + j * 16 + lr) * FF + kk);
        }
#pragma unroll
        for (int j = 0; j < 8; ++j)
#pragma unroll
            for (int r = 0; r < 4; ++r)
                xw[j][r] = XW[((size_t)(b0 + lq * 4 + r) * TN + t) * FF
                              + c0 + j * 16 + lr];
#pragma unroll
        for (int j = 0; j < 8; ++j) acc[j] = (f32x4){0.f, 0.f, 0.f, 0.f};

#pragma unroll
        for (int kc = 0; kc < 16; ++kc) {
            if (kc + 2 < 16) {
                const int slot = (kc + 2) % 3;
                const int kk = (kc + 2) * 32 + lq * 8;
                af[slot] = *(const short8*)&hcur[lr * HP + kk];
#pragma unroll
                for (int j = 0; j < 8; ++j)
                    wf[slot][j] = *(const short8*)
                        (Whh + (size_t)(c0 + j * 16 + lr) * FF + kk);
            }
            const int b = kc % 3;
#pragma unroll
            for (int j = 0; j < 8; ++j)
                acc[j] = __builtin_amdgcn_mfma_f32_16x16x32_bf16(
                    af[b], wf[b][j], acc[j], 0, 0, 0);
        }

        ushort_t* hnxt = hb[t & 1];
#pragma unroll
        for (int j = 0; j < 8; ++j) {
            const int col = c0 + j * 16 + lr;
#pragma unroll
            for (int r = 0; r < 4; ++r) {
                const int row = lq * 4 + r;
                const size_t gi = ((size_t)(b0 + row) * TN + t) * FF + col;
                const ushort_t hv = f2bf(ftanh(acc[j][r] + xw[j][r]));
                hnxt[row * HP + col] = hv;
                hs[gi] = hv;
            }
        }
        __syncthreads();
    }
}

// ---------------------------------------------------------------------------
// Fused decode: h' = tanh(h @ Wf^T + bf), 16 steps, row-local, NO sync.
// 32 blocks x 16 batch rows; h ping-pong in LDS; Wf streamed (3-slot ring).
// Stores every step's h into hall[(g*BB + b)*FF + col] (bf16).
// ---------------------------------------------------------------------------
__global__ __launch_bounds__(256)
void decode_fused(const ushort_t* __restrict__ Wf,
                  const float* __restrict__ bfv,
                  const ushort_t* __restrict__ hs,
                  ushort_t* __restrict__ hall)
{
    __shared__ ushort_t hb[2][16 * HP];
    const int tid = threadIdx.x, wave = tid >> 6, lane = tid & 63;
    const int b0 = blockIdx.x * 16;
    const int lr = lane & 15, lq = lane >> 4;
    const int c0 = wave * 128;

    // load h_63 (encoder final state) into hb[0]
    for (int it = 0; it < 4; ++it) {
        const int e = (it * 256 + tid) * 8;
        const int row = e >> 9, col = e & 511;
        const uint4 v = *(const uint4*)&hs[((size_t)(b0 + row) * TN + 63) * FF + col];
        *(uint4*)&hb[0][row * HP + col] = v;
    }
    __syncthreads();

    float bfj[8];
#pragma unroll
    for (int j = 0; j < 8; ++j) bfj[j] = bfv[c0 + j * 16 + lr];

    f32x4 acc[8];
    short8 wf[3][8];
    short8 af[3];

    for (int g = 0; g < 16; ++g) {
        const ushort_t* hcur = hb[g & 1];
#pragma unroll
        for (int s = 0; s < 2; ++s) {
            const int kk = s * 32 + lq * 8;
            af[s] = *(const short8*)&hcur[lr * HP + kk];
#pragma unroll
            for (int j = 0; j < 8; ++j)
                wf[s][j] = *(const short8*)(Wf + (size_t)(c0 + j * 16 + lr) * FF + kk);
        }
#pragma unroll
        for (int j = 0; j < 8; ++j) acc[j] = (f32x4){0.f, 0.f, 0.f, 0.f};

#pragma unroll
        for (int kc = 0; kc < 16; ++kc) {
            if (kc + 2 < 16) {
                const int slot = (kc + 2) % 3;
                const int kk = (kc + 2) * 32 + lq * 8;
                af[slot] = *(const short8*)&hcur[lr * HP + kk];
#pragma unroll
                for (int j = 0; j < 8; ++j)
                    wf[slot][j] = *(const short8*)
                        (Wf + (size_t)(c0 + j * 16 + lr) * FF + kk);
            }
            const int b = kc % 3;
#pragma unroll
            for (int j = 0; j < 8; ++j)
                acc[j] = __builtin_amdgcn_mfma_f32_16x16x32_bf16(
                    af[b], wf[b][j], acc[j], 0, 0, 0);
        }

        ushort_t* hnxt = hb[(g + 1) & 1];
#pragma unroll
        for (int j = 0; j < 8; ++j) {
            const int col = c0 + j * 16 + lr;
#pragma unroll
            for (int r = 0; r < 4; ++r) {
                const int row = lq * 4 + r;
                const ushort_t hv = f2bf(ftanh(acc[j][r] + bfj[j]));
                hnxt[row * HP + col] = hv;
                hall[((size_t)g * BB + b0 + row) * FF + col] = hv;
            }
        }
        __syncthreads();
    }
}

// ---------------------------------------------------------------------------
// Precompute helpers (fp32 bias chain + bf16 conversions).
// ---------------------------------------------------------------------------
__global__ void conv_x(const float* __restrict__ x, ushort_t* __restrict__ xb)
{
    const int i = blockIdx.x * blockDim.x + threadIdx.x;
    if (i < MALL * FF / 4) {
        const int e = i * 4;
        const int m = e >> 9;
        const int f = e & (FF - 1);
        const int b = m >> 6, t = m & 63;
        const float4 v = *(const float4*)&x[((size_t)b * TT + t) * FF + f];
        unsigned r0 = (unsigned)f2bf(v.x) | ((unsigned)f2bf(v.y) << 16);
        unsigned r1 = (unsigned)f2bf(v.z) | ((unsigned)f2bf(v.w) << 16);
        *(uint2*)&xb[e] = make_uint2(r0, r1);
    }
}

__global__ void conv_w(const float* __restrict__ src, ushort_t* __restrict__ dst,
                       int Nsrc, int Ksrc, int Npad, int Kpad)
{
    const int i = blockIdx.x * blockDim.x + threadIdx.x;
    if (i < Npad * Kpad) {
        const int n = i / Kpad, k = i - n * Kpad;
        const float v = (n < Nsrc && k < Ksrc) ? src[(size_t)n * Ksrc + k] : 0.f;
        dst[i] = f2bf(v);
    }
}

// M1T[k, j] = s1[j] * W1[j, k]   (512 x 1024, bf16; j >= HD -> 0)
__global__ void conv_m1t(const float* __restrict__ W1,
                         const float* __restrict__ g1,
                         const float* __restrict__ rv1,
                         ushort_t* __restrict__ M1T)
{
    const int i = blockIdx.x * blockDim.x + threadIdx.x;
    if (i < FF * HDP) {
        const int k = i >> 10, j = i & (HDP - 1);
        float v = 0.f;
        if (j < HD)
            v = g1[j] * rsqrtf(rv1[j] + EPSBN) * W1[(size_t)j * FF + k];
        M1T[i] = f2bf(v);
    }
}

// W3s[n, k] = s3[n] * W3[n, k]  (FF x HDP, bf16; k >= HD -> 0)
// THE ROUND-11 BUG FIX: S3 folded into the matrix, in fp32, pre-rounding.
__global__ void conv_w3s(const float* __restrict__ W3,
                         const float* __restrict__ g3,
                         const float* __restrict__ rv3,
                         ushort_t* __restrict__ dst)
{
    const int i = blockIdx.x * blockDim.x + threadIdx.x;
    if (i < FF * HDP) {
        const int n = i >> 10, k = i & (HDP - 1);
        float v = 0.f;
        if (k < HD)
            v = g3[n] * rsqrtf(rv3[n] + EPSBN) * W3[(size_t)n * HD + k];
        dst[i] = f2bf(v);
    }
}

// c1[j] = (b1[j]-rm1[j])*s1[j] + be1[j]  (j<HD else 0)
__global__ void fuse_c1(const float* __restrict__ b1, const float* __restrict__ rm1,
                        const float* __restrict__ rv1, const float* __restrict__ g1,
                        const float* __restrict__ be1, float* __restrict__ c1)
{
    const int j = blockIdx.x * blockDim.x + threadIdx.x;
    if (j < HDP) {
        float o = 0.f;
        if (j < HD) {
            const float s = g1[j] * rsqrtf(rv1[j] + EPSBN);
            o = (b1[j] - rm1[j]) * s + be1[j];
        }
        c1[j] = o;
    }
}

// out[i] = gg ? s_i*dot + (bb-rm)*s_i + be   : dot + a1[i] + a2[i]
__global__ void fuse_mv(const float* __restrict__ W, int K, int Mreal,
                        const float* __restrict__ vin,
                        const float* __restrict__ gg, const float* __restrict__ rv,
                        const float* __restrict__ bb, const float* __restrict__ rm,
                        const float* __restrict__ be,
                        const float* __restrict__ a1, const float* __restrict__ a2,
                        float* __restrict__ out, int Mout)
{
    const int i = blockIdx.x * blockDim.x + threadIdx.x;
    if (i >= Mout) return;
    float o = 0.f;
    if (i < Mreal) {
        const float* row = W + (size_t)i * K;
        float d = 0.f;
        for (int j = 0; j < K; ++j) d += row[j] * vin[j];
        if (gg) {
            const float s = gg[i] * rsqrtf(rv[i] + EPSBN);
            o = s * d + (bb[i] - rm[i]) * s + be[i];
        } else {
            o = d + a1[i] + a2[i];
        }
    }
    out[i] = o;
}

__global__ void zero_init(float* __restrict__ sums)
{
    if (threadIdx.x < 2 && blockIdx.x == 0) sums[threadIdx.x] = 0.f;
}

__global__ void gather_kernel(const float* __restrict__ xgaps,
                              const int* __restrict__ tgap,
                              const float* __restrict__ x,
                              float* __restrict__ out,
                              float* __restrict__ sums)
{
    const int i = blockIdx.x * blockDim.x + threadIdx.x;
    float s = 0.f;
    if (i < BF) {
        const int b = i >> 9, f = i & (FF - 1);
        const int g = tgap[b] - 1;
        const float v = xgaps[((size_t)g * BB + b) * FF + f];
        out[i] = v;
        const float d = v - x[((size_t)b * TT + (TT - 1)) * FF + f];
        s = d * d;
    }
    __shared__ float red[256];
    red[threadIdx.x] = s;
    __syncthreads();
    for (int o = 128; o > 0; o >>= 1) {
        if (threadIdx.x < o) red[threadIdx.x] += red[threadIdx.x + o];
        __syncthreads();
    }
    if (threadIdx.x == 0) atomicAdd(&sums[1], red[0]);
}

__global__ void finalize_kernel(const float* __restrict__ sums,
                                float* __restrict__ out)
{
    if (threadIdx.x == 0 && blockIdx.x == 0) {
        const double n1 = 63.0 * 512.0 * 512.0;
        const double n2 = 512.0 * 512.0;
        out[BF] = (float)((double)sums[0] / (n1 * n1) +
                          (double)sums[1] / (n2 * n2));
    }
}

extern "C" void kernel_launch(void* const* d_in, const int* in_sizes, int n_in,
                              void* d_out, int out_size, void* d_ws, size_t ws_size,
                              hipStream_t stream)
{
    const float* x    = (const float*)d_in[0];
    const int*   tgap = (const int*)d_in[1];
    const float* W_ih = (const float*)d_in[2];
    const float* W_hh = (const float*)d_in[3];
    const float* b_ih = (const float*)d_in[4];
    const float* b_hh = (const float*)d_in[5];
    const float* W1 = (const float*)d_in[6];
    const float* b1 = (const float*)d_in[7];
    const float* g1 = (const float*)d_in[8];
    const float* be1 = (const float*)d_in[9];
    const float* rm1 = (const float*)d_in[10];
    const float* rv1 = (const float*)d_in[11];
    const float* W2 = (const float*)d_in[12];
    const float* b2 = (const float*)d_in[13];
    const float* g2 = (const float*)d_in[14];
    const float* be2 = (const float*)d_in[15];
    const float* rm2 = (const float*)d_in[16];
    const float* rv2 = (const float*)d_in[17];
    const float* W3 = (const float*)d_in[18];
    const float* b3 = (const float*)d_in[19];
    const float* g3 = (const float*)d_in[20];
    const float* be3 = (const float*)d_in[21];
    const float* rm3 = (const float*)d_in[22];
    const float* rv3 = (const float*)d_in[23];
    float* out = (float*)d_out;

    char* p = (char*)d_ws;
    auto take = [&](size_t bytes) -> char* {
        char* r = p; p += (bytes + 63) & ~(size_t)63; return r;
    };
    float*    XWbuf = (float*)take((size_t)MALL * FF * 4);      // 67.1 MB
    ushort_t* hs    = (ushort_t*)take((size_t)MALL * FF * 2);   // 33.5 MB
    ushort_t* xbf   = (ushort_t*)take((size_t)MALL * FF * 2);   // 33.5 MB
    float*    xg    = (float*)take((size_t)16 * BF * 4);        // 16.8 MB
    ushort_t* hall  = (ushort_t*)take((size_t)16 * BF * 2);     //  8.4 MB
    ushort_t* seed  = (ushort_t*)take((size_t)BF * 2);
    ushort_t* Wihb  = (ushort_t*)take((size_t)FF * FF * 2);
    ushort_t* Whhb  = (ushort_t*)take((size_t)FF * FF * 2);
    ushort_t* W2b   = (ushort_t*)take((size_t)HDP * HDP * 2);
    ushort_t* W3s   = (ushort_t*)take((size_t)FF * HDP * 2);
    ushort_t* M1T   = (ushort_t*)take((size_t)FF * HDP * 2);
    ushort_t* Tts   = (ushort_t*)take((size_t)FF * HDP * 2);
    ushort_t* Anb   = (ushort_t*)take((size_t)FF * FF * 2);
    ushort_t* At    = (ushort_t*)take((size_t)FF * FF * 2);
    ushort_t* Wfb   = (ushort_t*)take((size_t)FF * FF * 2);
    float*    c1v   = (float*)take((size_t)HDP * 4);
    float*    v2v   = (float*)take((size_t)HDP * 4);
    float*    bAv   = (float*)take((size_t)FF * 4);
    float*    bfv   = (float*)take((size_t)FF * 4);
    float*    sums  = (float*)take(16 * 4);

    const dim3 blk(256);

    zero_init<<<dim3(1), dim3(64), 0, stream>>>(sums);
    conv_x<<<dim3(MALL * FF / 4 / 256), blk, 0, stream>>>(x, xbf);
    conv_w<<<dim3((FF * FF + 255) / 256), blk, 0, stream>>>(W_ih, Wihb, FF, FF, FF, FF);
    conv_w<<<dim3((FF * FF + 255) / 256), blk, 0, stream>>>(W_hh, Whhb, FF, FF, FF, FF);
    conv_w<<<dim3((HDP * HDP + 255) / 256), blk, 0, stream>>>(W2, W2b, HD, HD, HDP, HDP);
    conv_w3s<<<dim3((FF * HDP + 255) / 256), blk, 0, stream>>>(W3, g3, rv3, W3s);
    conv_m1t<<<dim3((FF * HDP + 255) / 256), blk, 0, stream>>>(W1, g1, rv1, M1T);

    // fp32 bias chain: c1 -> v2 -> bA -> bf
    fuse_c1<<<dim3((HDP + 255) / 256), blk, 0, stream>>>(b1, rm1, rv1, g1, be1, c1v);
    fuse_mv<<<dim3((HDP + 255) / 256), blk, 0, stream>>>(
        W2, HD, HD, c1v, g2, rv2, b2, rm2, be2, nullptr, nullptr, v2v, HDP);
    fuse_mv<<<dim3((FF + 255) / 256), blk, 0, stream>>>(
        W3, HD, FF, v2v, g3, rv3, b3, rm3, be3, nullptr, nullptr, bAv, FF);
    fuse_mv<<<dim3((FF + 255) / 256), blk, 0, stream>>>(
        W_ih, FF, FF, bAv, nullptr, nullptr, nullptr, nullptr, nullptr,
        b_ih, b_hh, bfv, FF);

    // Tts[k,i] = s2[i] * (W2 @ S1 W1)[i,k]   (512 x 1024)
    mfma_gemm<<<dim3(HDP / 128, FF / 128), blk, 0, stream>>>(
        M1T, HDP, W2b, HDP, HD, Tts, HDP, nullptr, 8, 0,
        nullptr, nullptr, rv2, g2, nullptr, nullptr);
    // Anb[a,b] = A[a,b] = sum_j W3s[a,j] * Tts[b,j]   (A = S3 W3 S2 W2 S1 W1)
    mfma_gemm<<<dim3(FF / 128, FF / 128), blk, 0, stream>>>(
        W3s, HDP, Tts, HDP, FF, Anb, FF, nullptr, 1, 0,
        nullptr, nullptr, nullptr, nullptr, nullptr, nullptr);
    // At[k,i] = A[i,k] = sum_j Tts[k,j] * W3s[i,j]
    mfma_gemm<<<dim3(FF / 128, FF / 128), blk, 0, stream>>>(
        Tts, HDP, W3s, HDP, FF, At, FF, nullptr, 1, 0,
        nullptr, nullptr, nullptr, nullptr, nullptr, nullptr);
    // Wfb[n,k] = sum_m Wihb[n,m] * At[k,m] + Whh[n,k]
    mfma_gemm<<<dim3(FF / 128, FF / 128), blk, 0, stream>>>(
        Wihb, FF, At, FF, FF, Wfb, FF, nullptr, 6, 0,
        nullptr, nullptr, nullptr, nullptr, Whhb, nullptr);

    // encoder: XW = x @ W_ih^T + b_ih + b_hh -> fp32
    mfma_gemm<<<dim3(FF / 128, MALL / 128), blk, 0, stream>>>(
        xbf, FF, Wihb, FF, FF, XWbuf, FF, nullptr, 0, 0,
        b_ih, b_hh, nullptr, nullptr, nullptr, nullptr);
    rnn_persistent<<<dim3(BB / 16), blk, 0, stream>>>(Whhb, XWbuf, hs);

    // fused y = hs @ A^T + bA with loss epilogue (one GEMM, M=32768)
    mfma_gemm<<<dim3(FF / 128, MALL / 128), blk, 0, stream>>>(
        hs, FF, Anb, FF, FF, nullptr, 0, x, 5, 0,
        bAv, nullptr, nullptr, nullptr, seed, sums);

    // fused decode: 16 row-local steps, no sync
    decode_fused<<<dim3(BB / 16), blk, 0, stream>>>(Wfb, bfv, hs, hall);

    // xg[g] = h_g @ A^T + bA  (f32, one batched GEMM M=8192)
    mfma_gemm<<<dim3(FF / 128, (16 * BB) / 128), blk, 0, stream>>>(
        hall, FF, Anb, FF, FF, xg, FF, nullptr, 7, 0,
        bAv, nullptr, nullptr, nullptr, nullptr, nullptr);

    gather_kernel<<<dim3(BF / 256), blk, 0, stream>>>(xg, tgap, x, out, sums);
    finalize_kernel<<<dim3(1), dim3(64), 0, stream>>>(sums, out);
}

// Round 8
// 1376.160 us; speedup vs baseline: 1.5814x; 1.0918x over previous
//
#include <hip/hip_runtime.h>
#include <math.h>

// forecastRNN on MI355X, round 14 (= round 13 resubmit + alignment fix).
// Round-13 bench died at the container level (infra), but audit found a
// real latent bug: LDS W-slice row stride 130 ushorts = 260 B is NOT 16-B
// aligned, yet accessed as uint4/short8 (ds_*_b128 assumes 16-B) ->
// undefined on odd rows. Fix: stride 136 (272 B = 17*16). Banks: row
// stride 68 dwords = 4 mod 32 -> 2-way conflict (free, m136).
// Structure unchanged from round 13:
// - W-RESIDENT encoder RNN: 64 blocks x 8 batch rows; 8 waves x 64 cols;
//   Whh chunks 0..11 in 192 VGPRs/lane, chunks 12..15 in LDS;
//   steady-state K-loop touches zero global W. launch_bounds(512,2).
// - Affine-collapsed autoencoder/decode (round 12) unchanged.

typedef unsigned short ushort_t;
typedef __attribute__((ext_vector_type(8))) short short8;
typedef __attribute__((ext_vector_type(4))) float f32x4;

#define BB 512
#define TT 65
#define TN 64
#define FF 512
#define HD 1000
#define HDP 1024
#define EPSBN 1e-5f
#define BF (BB*FF)          // 262144
#define MALL (BB*TN)        // 32768
#define HP 520              // LDS h row stride (1040 B)
#define RROWS 8             // batch rows per rnn block
#define WLS 136             // LDS W row stride (272 B, 16-B aligned)

__device__ __forceinline__ ushort_t f2bf(float f) {
    union { float f; unsigned u; } v; v.f = f;
    unsigned r = v.u + 0x7FFFu + ((v.u >> 16) & 1u);
    return (ushort_t)(r >> 16);
}

__device__ __forceinline__ float b2f(ushort_t u) {
    union { unsigned u; float f; } v; v.u = ((unsigned)u) << 16;
    return v.f;
}

__device__ __forceinline__ float ftanh(float x) {
    const float e = __expf(2.f * x);
    return 1.f - 2.f / (e + 1.f);
}

__device__ __forceinline__ void ld16(const ushort_t* g, ushort_t* l) {
    __builtin_amdgcn_global_load_lds(
        (const __attribute__((address_space(1))) unsigned*)g,
        (__attribute__((address_space(3))) unsigned*)l, 16, 0, 0);
}

// ---------------------------------------------------------------------------
// Large-GEMM kernel, 128x128 tile, BK=32. out[m,n] = sum_k A[m,k]*W[n,k].
// epi: 0 f32 v+p1+p2 | 1 bf16 v | 5 loss (o=v+p1; vs aux; seed/out2; sums)
//      6 bf16 v+bf16(out2[m*o_rs+n]) | 7 f32 v+p1 | 8 bf16 masked col-scale
// ---------------------------------------------------------------------------
__global__ __launch_bounds__(256)
void mfma_gemm(const ushort_t* __restrict__ A, long a_rs,
               const ushort_t* __restrict__ W, int K, int Nreal,
               void* __restrict__ outv, long o_rs,
               const float* __restrict__ aux, int epi, int mbase,
               const float* __restrict__ p1, const float* __restrict__ p2,
               const float* __restrict__ rv, const float* __restrict__ gg,
               ushort_t* __restrict__ out2, float* __restrict__ sums)
{
    __shared__ ushort_t As[128 * 32];
    __shared__ ushort_t Bs[128 * 32];
    __shared__ float red[256];

    const int tid  = threadIdx.x;
    const int wave = tid >> 6, lane = tid & 63;
    const int wm = wave >> 1, wn = wave & 1;
    const int tileM = blockIdx.y * 128, tileN = blockIdx.x * 128;

    f32x4 acc[4][4] = {};
    const int srow = lane >> 2;
    const int skb  = (lane & 3) * 8;

    for (int kt = 0; kt < K; kt += 32) {
        __syncthreads();
#pragma unroll
        for (int s = 0; s < 2; ++s) {
            const int instr = wave * 2 + s;
            const int row = instr * 16 + srow;
            ld16(A + (size_t)(tileM + row) * a_rs + kt + skb, &As[instr * 512]);
            ld16(W + (size_t)(tileN + row) * (size_t)K + kt + skb, &Bs[instr * 512]);
        }
        __syncthreads();
        const int lr = lane & 15;
        const int lk = (lane >> 4) * 8;
        short8 af[4], bfr[4];
#pragma unroll
        for (int i = 0; i < 4; ++i)
            af[i] = *(const short8*)&As[(wm * 64 + i * 16 + lr) * 32 + lk];
#pragma unroll
        for (int j = 0; j < 4; ++j)
            bfr[j] = *(const short8*)&Bs[(wn * 64 + j * 16 + lr) * 32 + lk];
#pragma unroll
        for (int i = 0; i < 4; ++i)
#pragma unroll
            for (int j = 0; j < 4; ++j)
                acc[i][j] = __builtin_amdgcn_mfma_f32_16x16x32_bf16(
                    af[i], bfr[j], acc[i][j], 0, 0, 0);
    }

    const int lr = lane & 15;
    const int rquad = (lane >> 4) * 4;
    float lsum = 0.f;
#pragma unroll
    for (int i = 0; i < 4; ++i) {
#pragma unroll
        for (int r = 0; r < 4; ++r) {
            const int grow = tileM + wm * 64 + i * 16 + rquad + r;
#pragma unroll
            for (int j = 0; j < 4; ++j) {
                const int gcol = tileN + wn * 64 + j * 16 + lr;
                const float v = acc[i][j][r];
                if (epi == 0) {
                    ((float*)outv)[(size_t)grow * o_rs + gcol] = v + p1[gcol] + p2[gcol];
                } else if (epi == 1) {
                    ((ushort_t*)outv)[(size_t)grow * o_rs + gcol] = f2bf(v);
                } else if (epi == 6) {
                    const float w0 = b2f(out2[(size_t)grow * o_rs + gcol]);
                    ((ushort_t*)outv)[(size_t)grow * o_rs + gcol] = f2bf(v + w0);
                } else if (epi == 7) {
                    ((float*)outv)[(size_t)grow * o_rs + gcol] = v + p1[gcol];
                } else if (epi == 8) {
                    float o = 0.f;
                    if (gcol < Nreal)
                        o = v * (gg[gcol] * rsqrtf(rv[gcol] + EPSBN));
                    ((ushort_t*)outv)[(size_t)grow * o_rs + gcol] = f2bf(o);
                } else { // epi 5: loss
                    const float o = v + p1[gcol];
                    const int gm = mbase + grow;
                    const int b = gm >> 6, tau = gm & 63;
                    if (tau < 63) {
                        const float d = o - aux[((size_t)b * TT + tau + 1) * FF + gcol];
                        lsum += d * d;
                    } else {
                        out2[(size_t)b * FF + gcol] = f2bf(o);
                    }
                }
            }
        }
    }
    if (epi == 5) {
        red[tid] = lsum;
        __syncthreads();
        for (int o = 128; o > 0; o >>= 1) {
            if (tid < o) red[tid] += red[tid + o];
            __syncthreads();
        }
        if (tid == 0) atomicAdd(&sums[0], red[0]);
    }
}

// ---------------------------------------------------------------------------
// Persistent recurrence (encoder), W-RESIDENT version.
// 64 blocks x 8 batch rows; 8 waves (512 thr) x 64 output cols.
// Whh slice per wave: chunks 0..11 in 192 VGPRs, chunks 12..15 in LDS.
// ---------------------------------------------------------------------------
__global__ __launch_bounds__(512, 2)
void rnn_persistent(const ushort_t* __restrict__ Whh,
                    const float* __restrict__ XW,
                    ushort_t* __restrict__ hs)
{
    __shared__ ushort_t hb[2][RROWS * HP];   // 16,640 B
    __shared__ ushort_t wl[8 * 64 * WLS];    // 139,264 B
    const int tid = threadIdx.x, wave = tid >> 6, lane = tid & 63;
    const int b0 = blockIdx.x * RROWS;
    const int lr = lane & 15, lq = lane >> 4;   // lq in [0,4): K-subgroup
    const int rq = lq * 4;                      // acc row quad
    const int c0 = wave * 64;
    ushort_t* wlw = wl + wave * (64 * WLS);

    // ---- one-time Whh residency ----
    short8 wreg[12][4];                      // 192 VGPR, static indices only
#pragma unroll
    for (int kc = 0; kc < 12; ++kc)
#pragma unroll
        for (int nt = 0; nt < 4; ++nt)
            wreg[kc][nt] = *(const short8*)(Whh +
                (size_t)(c0 + nt * 16 + lr) * FF + kc * 32 + lq * 8);
#pragma unroll
    for (int i = 0; i < 16; ++i) {           // chunks 12..15 -> LDS
        const int u = i * 64 + lane;         // u in [0,1024)
        const int row = u >> 4, c16 = u & 15;
        *(uint4*)&wlw[row * WLS + c16 * 8] =
            *(const uint4*)(Whh + (size_t)(c0 + row) * FF + 384 + c16 * 8);
    }

    // ---- t = 0: h = tanh(XW_0) ----
#pragma unroll
    for (int it = 0; it < 2; ++it) {
        const int e = (it * 512 + tid) * 4;  // 8 rows x 512 cols
        const int row = e >> 9, col = e & 511;
        const size_t gi = ((size_t)(b0 + row) * TN) * FF + col;
        const float4 v = *(const float4*)&XW[gi];
        const ushort_t h0 = f2bf(ftanh(v.x)), h1 = f2bf(ftanh(v.y));
        const ushort_t h2 = f2bf(ftanh(v.z)), h3 = f2bf(ftanh(v.w));
        hb[0][row * HP + col + 0] = h0; hb[0][row * HP + col + 1] = h1;
        hb[0][row * HP + col + 2] = h2; hb[0][row * HP + col + 3] = h3;
        unsigned r0 = (unsigned)h0 | ((unsigned)h1 << 16);
        unsigned r1 = (unsigned)h2 | ((unsigned)h3 << 16);
        *(uint2*)&hs[gi] = make_uint2(r0, r1);
    }
    __syncthreads();

    f32x4 acc[4];
    short8 af[3];

    for (int t = 1; t < TN; ++t) {
        const ushort_t* hcur = hb[(t - 1) & 1];
#pragma unroll
        for (int s = 0; s < 2; ++s)
            af[s] = *(const short8*)&hcur[(lr & 7) * HP + s * 32 + lq * 8];
#pragma unroll
        for (int j = 0; j < 4; ++j) acc[j] = (f32x4){0.f, 0.f, 0.f, 0.f};

#pragma unroll
        for (int kc = 0; kc < 16; ++kc) {
            if (kc + 2 < 16)
                af[(kc + 2) % 3] = *(const short8*)
                    &hcur[(lr & 7) * HP + (kc + 2) * 32 + lq * 8];
            const int b = kc % 3;
            if (kc < 12) {
#pragma unroll
                for (int nt = 0; nt < 4; ++nt)
                    acc[nt] = __builtin_amdgcn_mfma_f32_16x16x32_bf16(
                        af[b], wreg[kc][nt], acc[nt], 0, 0, 0);
            } else {
#pragma unroll
                for (int nt = 0; nt < 4; ++nt) {
                    const short8 wfr = *(const short8*)
                        &wlw[(nt * 16 + lr) * WLS + (kc - 12) * 32 + lq * 8];
                    acc[nt] = __builtin_amdgcn_mfma_f32_16x16x32_bf16(
                        af[b], wfr, acc[nt], 0, 0, 0);
                }
            }
        }

        ushort_t* hnxt = hb[t & 1];
        if (rq < 8) {                        // lanes 32..63: dup rows, skip
#pragma unroll
            for (int nt = 0; nt < 4; ++nt) {
                const int col = c0 + nt * 16 + lr;
#pragma unroll
                for (int r = 0; r < 4; ++r) {
                    const int row = rq + r;
                    const size_t gi = ((size_t)(b0 + row) * TN + t) * FF + col;
                    const ushort_t hv = f2bf(ftanh(acc[nt][r] + XW[gi]));
                    hnxt[row * HP + col] = hv;
                    hs[gi] = hv;
                }
            }
        }
        __syncthreads();
    }
}

// ---------------------------------------------------------------------------
// Fused decode: h' = tanh(h @ Wf^T + bf), 16 steps, row-local, NO sync.
// 32 blocks x 16 batch rows; h ping-pong in LDS; Wf streamed (3-slot ring).
// ---------------------------------------------------------------------------
__global__ __launch_bounds__(256)
void decode_fused(const ushort_t* __restrict__ Wf,
                  const float* __restrict__ bfv,
                  const ushort_t* __restrict__ hs,
                  ushort_t* __restrict__ hall)
{
    __shared__ ushort_t hb[2][16 * HP];
    const int tid = threadIdx.x, wave = tid >> 6, lane = tid & 63;
    const int b0 = blockIdx.x * 16;
    const int lr = lane & 15, lq = lane >> 4;
    const int c0 = wave * 128;

    // load h_63 (encoder final state) into hb[0]
    for (int it = 0; it < 4; ++it) {
        const int e = (it * 256 + tid) * 8;
        const int row = e >> 9, col = e & 511;
        const uint4 v = *(const uint4*)&hs[((size_t)(b0 + row) * TN + 63) * FF + col];
        *(uint4*)&hb[0][row * HP + col] = v;
    }
    __syncthreads();

    float bfj[8];
#pragma unroll
    for (int j = 0; j < 8; ++j) bfj[j] = bfv[c0 + j * 16 + lr];

    f32x4 acc[8];
    short8 wf[3][8];
    short8 af[3];

    for (int g = 0; g < 16; ++g) {
        const ushort_t* hcur = hb[g & 1];
#pragma unroll
        for (int s = 0; s < 2; ++s) {
            const int kk = s * 32 + lq * 8;
            af[s] = *(const short8*)&hcur[lr * HP + kk];
#pragma unroll
            for (int j = 0; j < 8; ++j)
                wf[s][j] = *(const short8*)(Wf + (size_t)(c0 + j * 16 + lr) * FF + kk);
        }
#pragma unroll
        for (int j = 0; j < 8; ++j) acc[j] = (f32x4){0.f, 0.f, 0.f, 0.f};

#pragma unroll
        for (int kc = 0; kc < 16; ++kc) {
            if (kc + 2 < 16) {
                const int slot = (kc + 2) % 3;
                const int kk = (kc + 2) * 32 + lq * 8;
                af[slot] = *(const short8*)&hcur[lr * HP + kk];
#pragma unroll
                for (int j = 0; j < 8; ++j)
                    wf[slot][j] = *(const short8*)
                        (Wf + (size_t)(c0 + j * 16 + lr) * FF + kk);
            }
            const int b = kc % 3;
#pragma unroll
            for (int j = 0; j < 8; ++j)
                acc[j] = __builtin_amdgcn_mfma_f32_16x16x32_bf16(
                    af[b], wf[b][j], acc[j], 0, 0, 0);
        }

        ushort_t* hnxt = hb[(g + 1) & 1];
#pragma unroll
        for (int j = 0; j < 8; ++j) {
            const int col = c0 + j * 16 + lr;
#pragma unroll
            for (int r = 0; r < 4; ++r) {
                const int row = lq * 4 + r;
                const ushort_t hv = f2bf(ftanh(acc[j][r] + bfj[j]));
                hnxt[row * HP + col] = hv;
                hall[((size_t)g * BB + b0 + row) * FF + col] = hv;
            }
        }
        __syncthreads();
    }
}

// ---------------------------------------------------------------------------
// Precompute helpers (fp32 bias chain + bf16 conversions).
// ---------------------------------------------------------------------------
__global__ void conv_x(const float* __restrict__ x, ushort_t* __restrict__ xb)
{
    const int i = blockIdx.x * blockDim.x + threadIdx.x;
    if (i < MALL * FF / 4) {
        const int e = i * 4;
        const int m = e >> 9;
        const int f = e & (FF - 1);
        const int b = m >> 6, t = m & 63;
        const float4 v = *(const float4*)&x[((size_t)b * TT + t) * FF + f];
        unsigned r0 = (unsigned)f2bf(v.x) | ((unsigned)f2bf(v.y) << 16);
        unsigned r1 = (unsigned)f2bf(v.z) | ((unsigned)f2bf(v.w) << 16);
        *(uint2*)&xb[e] = make_uint2(r0, r1);
    }
}

__global__ void conv_w(const float* __restrict__ src, ushort_t* __restrict__ dst,
                       int Nsrc, int Ksrc, int Npad, int Kpad)
{
    const int i = blockIdx.x * blockDim.x + threadIdx.x;
    if (i < Npad * Kpad) {
        const int n = i / Kpad, k = i - n * Kpad;
        const float v = (n < Nsrc && k < Ksrc) ? src[(size_t)n * Ksrc + k] : 0.f;
        dst[i] = f2bf(v);
    }
}

// M1T[k, j] = s1[j] * W1[j, k]   (512 x 1024, bf16; j >= HD -> 0)
__global__ void conv_m1t(const float* __restrict__ W1,
                         const float* __restrict__ g1,
                         const float* __restrict__ rv1,
                         ushort_t* __restrict__ M1T)
{
    const int i = blockIdx.x * blockDim.x + threadIdx.x;
    if (i < FF * HDP) {
        const int k = i >> 10, j = i & (HDP - 1);
        float v = 0.f;
        if (j < HD)
            v = g1[j] * rsqrtf(rv1[j] + EPSBN) * W1[(size_t)j * FF + k];
        M1T[i] = f2bf(v);
    }
}

// W3s[n, k] = s3[n] * W3[n, k]  (FF x HDP, bf16; k >= HD -> 0)
__global__ void conv_w3s(const float* __restrict__ W3,
                         const float* __restrict__ g3,
                         const float* __restrict__ rv3,
                         ushort_t* __restrict__ dst)
{
    const int i = blockIdx.x * blockDim.x + threadIdx.x;
    if (i < FF * HDP) {
        const int n = i >> 10, k = i & (HDP - 1);
        float v = 0.f;
        if (k < HD)
            v = g3[n] * rsqrtf(rv3[n] + EPSBN) * W3[(size_t)n * HD + k];
        dst[i] = f2bf(v);
    }
}

// c1[j] = (b1[j]-rm1[j])*s1[j] + be1[j]  (j<HD else 0)
__global__ void fuse_c1(const float* __restrict__ b1, const float* __restrict__ rm1,
                        const float* __restrict__ rv1, const float* __restrict__ g1,
                        const float* __restrict__ be1, float* __restrict__ c1)
{
    const int j = blockIdx.x * blockDim.x + threadIdx.x;
    if (j < HDP) {
        float o = 0.f;
        if (j < HD) {
            const float s = g1[j] * rsqrtf(rv1[j] + EPSBN);
            o = (b1[j] - rm1[j]) * s + be1[j];
        }
        c1[j] = o;
    }
}

// out[i] = gg ? s_i*dot + (bb-rm)*s_i + be   : dot + a1[i] + a2[i]
__global__ void fuse_mv(const float* __restrict__ W, int K, int Mreal,
                        const float* __restrict__ vin,
                        const float* __restrict__ gg, const float* __restrict__ rv,
                        const float* __restrict__ bb, const float* __restrict__ rm,
                        const float* __restrict__ be,
                        const float* __restrict__ a1, const float* __restrict__ a2,
                        float* __restrict__ out, int Mout)
{
    const int i = blockIdx.x * blockDim.x + threadIdx.x;
    if (i >= Mout) return;
    float o = 0.f;
    if (i < Mreal) {
        const float* row = W + (size_t)i * K;
        float d = 0.f;
        for (int j = 0; j < K; ++j) d += row[j] * vin[j];
        if (gg) {
            const float s = gg[i] * rsqrtf(rv[i] + EPSBN);
            o = s * d + (bb[i] - rm[i]) * s + be[i];
        } else {
            o = d + a1[i] + a2[i];
        }
    }
    out[i] = o;
}

__global__ void zero_init(float* __restrict__ sums)
{
    if (threadIdx.x < 2 && blockIdx.x == 0) sums[threadIdx.x] = 0.f;
}

__global__ void gather_kernel(const float* __restrict__ xgaps,
                              const int* __restrict__ tgap,
                              const float* __restrict__ x,
                              float* __restrict__ out,
                              float* __restrict__ sums)
{
    const int i = blockIdx.x * blockDim.x + threadIdx.x;
    float s = 0.f;
    if (i < BF) {
        const int b = i >> 9, f = i & (FF - 1);
        const int g = tgap[b] - 1;
        const float v = xgaps[((size_t)g * BB + b) * FF + f];
        out[i] = v;
        const float d = v - x[((size_t)b * TT + (TT - 1)) * FF + f];
        s = d * d;
    }
    __shared__ float red[256];
    red[threadIdx.x] = s;
    __syncthreads();
    for (int o = 128; o > 0; o >>= 1) {
        if (threadIdx.x < o) red[threadIdx.x] += red[threadIdx.x + o];
        __syncthreads();
    }
    if (threadIdx.x == 0) atomicAdd(&sums[1], red[0]);
}

__global__ void finalize_kernel(const float* __restrict__ sums,
                                float* __restrict__ out)
{
    if (threadIdx.x == 0 && blockIdx.x == 0) {
        const double n1 = 63.0 * 512.0 * 512.0;
        const double n2 = 512.0 * 512.0;
        out[BF] = (float)((double)sums[0] / (n1 * n1) +
                          (double)sums[1] / (n2 * n2));
    }
}

extern "C" void kernel_launch(void* const* d_in, const int* in_sizes, int n_in,
                              void* d_out, int out_size, void* d_ws, size_t ws_size,
                              hipStream_t stream)
{
    const float* x    = (const float*)d_in[0];
    const int*   tgap = (const int*)d_in[1];
    const float* W_ih = (const float*)d_in[2];
    const float* W_hh = (const float*)d_in[3];
    const float* b_ih = (const float*)d_in[4];
    const float* b_hh = (const float*)d_in[5];
    const float* W1 = (const float*)d_in[6];
    const float* b1 = (const float*)d_in[7];
    const float* g1 = (const float*)d_in[8];
    const float* be1 = (const float*)d_in[9];
    const float* rm1 = (const float*)d_in[10];
    const float* rv1 = (const float*)d_in[11];
    const float* W2 = (const float*)d_in[12];
    const float* b2 = (const float*)d_in[13];
    const float* g2 = (const float*)d_in[14];
    const float* be2 = (const float*)d_in[15];
    const float* rm2 = (const float*)d_in[16];
    const float* rv2 = (const float*)d_in[17];
    const float* W3 = (const float*)d_in[18];
    const float* b3 = (const float*)d_in[19];
    const float* g3 = (const float*)d_in[20];
    const float* be3 = (const float*)d_in[21];
    const float* rm3 = (const float*)d_in[22];
    const float* rv3 = (const float*)d_in[23];
    float* out = (float*)d_out;

    char* p = (char*)d_ws;
    auto take = [&](size_t bytes) -> char* {
        char* r = p; p += (bytes + 63) & ~(size_t)63; return r;
    };
    float*    XWbuf = (float*)take((size_t)MALL * FF * 4);      // 67.1 MB
    ushort_t* hs    = (ushort_t*)take((size_t)MALL * FF * 2);   // 33.5 MB
    ushort_t* xbf   = (ushort_t*)take((size_t)MALL * FF * 2);   // 33.5 MB
    float*    xg    = (float*)take((size_t)16 * BF * 4);        // 16.8 MB
    ushort_t* hall  = (ushort_t*)take((size_t)16 * BF * 2);     //  8.4 MB
    ushort_t* seed  = (ushort_t*)take((size_t)BF * 2);
    ushort_t* Wihb  = (ushort_t*)take((size_t)FF * FF * 2);
    ushort_t* Whhb  = (ushort_t*)take((size_t)FF * FF * 2);
    ushort_t* W2b   = (ushort_t*)take((size_t)HDP * HDP * 2);
    ushort_t* W3s   = (ushort_t*)take((size_t)FF * HDP * 2);
    ushort_t* M1T   = (ushort_t*)take((size_t)FF * HDP * 2);
    ushort_t* Tts   = (ushort_t*)take((size_t)FF * HDP * 2);
    ushort_t* Anb   = (ushort_t*)take((size_t)FF * FF * 2);
    ushort_t* At    = (ushort_t*)take((size_t)FF * FF * 2);
    ushort_t* Wfb   = (ushort_t*)take((size_t)FF * FF * 2);
    float*    c1v   = (float*)take((size_t)HDP * 4);
    float*    v2v   = (float*)take((size_t)HDP * 4);
    float*    bAv   = (float*)take((size_t)FF * 4);
    float*    bfv   = (float*)take((size_t)FF * 4);
    float*    sums  = (float*)take(16 * 4);

    const dim3 blk(256);

    zero_init<<<dim3(1), dim3(64), 0, stream>>>(sums);
    conv_x<<<dim3(MALL * FF / 4 / 256), blk, 0, stream>>>(x, xbf);
    conv_w<<<dim3((FF * FF + 255) / 256), blk, 0, stream>>>(W_ih, Wihb, FF, FF, FF, FF);
    conv_w<<<dim3((FF * FF + 255) / 256), blk, 0, stream>>>(W_hh, Whhb, FF, FF, FF, FF);
    conv_w<<<dim3((HDP * HDP + 255) / 256), blk, 0, stream>>>(W2, W2b, HD, HD, HDP, HDP);
    conv_w3s<<<dim3((FF * HDP + 255) / 256), blk, 0, stream>>>(W3, g3, rv3, W3s);
    conv_m1t<<<dim3((FF * HDP + 255) / 256), blk, 0, stream>>>(W1, g1, rv1, M1T);

    // fp32 bias chain: c1 -> v2 -> bA -> bf
    fuse_c1<<<dim3((HDP + 255) / 256), blk, 0, stream>>>(b1, rm1, rv1, g1, be1, c1v);
    fuse_mv<<<dim3((HDP + 255) / 256), blk, 0, stream>>>(
        W2, HD, HD, c1v, g2, rv2, b2, rm2, be2, nullptr, nullptr, v2v, HDP);
    fuse_mv<<<dim3((FF + 255) / 256), blk, 0, stream>>>(
        W3, HD, FF, v2v, g3, rv3, b3, rm3, be3, nullptr, nullptr, bAv, FF);
    fuse_mv<<<dim3((FF + 255) / 256), blk, 0, stream>>>(
        W_ih, FF, FF, bAv, nullptr, nullptr, nullptr, nullptr, nullptr,
        b_ih, b_hh, bfv, FF);

    // Tts[k,i] = s2[i] * (W2 @ S1 W1)[i,k]   (512 x 1024)
    mfma_gemm<<<dim3(HDP / 128, FF / 128), blk, 0, stream>>>(
        M1T, HDP, W2b, HDP, HD, Tts, HDP, nullptr, 8, 0,
        nullptr, nullptr, rv2, g2, nullptr, nullptr);
    // Anb[a,b] = A[a,b] = sum_j W3s[a,j] * Tts[b,j]   (A = S3 W3 S2 W2 S1 W1)
    mfma_gemm<<<dim3(FF / 128, FF / 128), blk, 0, stream>>>(
        W3s, HDP, Tts, HDP, FF, Anb, FF, nullptr, 1, 0,
        nullptr, nullptr, nullptr, nullptr, nullptr, nullptr);
    // At[k,i] = A[i,k] = sum_j Tts[k,j] * W3s[i,j]
    mfma_gemm<<<dim3(FF / 128, FF / 128), blk, 0, stream>>>(
        Tts, HDP, W3s, HDP, FF, At, FF, nullptr, 1, 0,
        nullptr, nullptr, nullptr, nullptr, nullptr, nullptr);
    // Wfb[n,k] = sum_m Wihb[n,m] * At[k,m] + Whh[n,k]
    mfma_gemm<<<dim3(FF / 128, FF / 128), blk, 0, stream>>>(
        Wihb, FF, At, FF, FF, Wfb, FF, nullptr, 6, 0,
        nullptr, nullptr, nullptr, nullptr, Whhb, nullptr);

    // encoder: XW = x @ W_ih^T + b_ih + b_hh -> fp32
    mfma_gemm<<<dim3(FF / 128, MALL / 128), blk, 0, stream>>>(
        xbf, FF, Wihb, FF, FF, XWbuf, FF, nullptr, 0, 0,
        b_ih, b_hh, nullptr, nullptr, nullptr, nullptr);
    rnn_persistent<<<dim3(BB / RROWS), dim3(512), 0, stream>>>(Whhb, XWbuf, hs);

    // fused y = hs @ A^T + bA with loss epilogue (one GEMM, M=32768)
    mfma_gemm<<<dim3(FF / 128, MALL / 128), blk, 0, stream>>>(
        hs, FF, Anb, FF, FF, nullptr, 0, x, 5, 0,
        bAv, nullptr, nullptr, nullptr, seed, sums);

    // fused decode: 16 row-local steps, no sync
    decode_fused<<<dim3(BB / 16), blk, 0, stream>>>(Wfb, bfv, hs, hall);

    // xg[g] = h_g @ A^T + bA  (f32, one batched GEMM M=8192)
    mfma_gemm<<<dim3(FF / 128, (16 * BB) / 128), blk, 0, stream>>>(
        hall, FF, Anb, FF, FF, xg, FF, nullptr, 7, 0,
        bAv, nullptr, nullptr, nullptr, nullptr, nullptr);

    gather_kernel<<<dim3(BF / 256), blk, 0, stream>>>(xg, tgap, x, out, sums);
    finalize_kernel<<<dim3(1), dim3(64), 0, stream>>>(sums, out);
}

// Round 10
// 1111.439 us; speedup vs baseline: 1.9580x; 1.2382x over previous
//
#include <hip/hip_runtime.h>
#include <math.h>

// forecastRNN on MI355X, round 16.
// Round 15 failed (absmax 1.46e-2): the LDS W swizzle with WLS=136 (272 B
// stride) is NON-BIJECTIVE -- XOR key (row&7)<<4 acts on bits 4..6 of the
// total offset, and 272 is not a multiple of 128, so rows share 128-B
// blocks and collide (e.g. row1 x=240 and row2 x=16 both -> byte 528).
// Fix: WLS=128 (256 B stride = 2x128B blocks) -> XOR confined to the row,
// bijective, write/read keys consistent; post-swizzle bank pattern is
// throughput-optimal (8 lanes per 4-bank group). LDS now 147.7 KB.
// Round 14's perf finding: VGPR_Count=128 -> the 192-reg W array was
// remat'd from L2 INSIDE the K-loop (~14.7K cyc/step). launch_bounds'
// 2nd arg is only a MIN; pin the allocator with amdgpu_waves_per_eu(2,2)
// (max=2 is truthful: 139KB LDS -> 1 block/CU = 2 waves/SIMD) to unlock
// the 256-VGPR budget.
// Everything else unchanged from round 14 (passed, absmax 1.95e-3).

typedef unsigned short ushort_t;
typedef __attribute__((ext_vector_type(8))) short short8;
typedef __attribute__((ext_vector_type(4))) float f32x4;

#define BB 512
#define TT 65
#define TN 64
#define FF 512
#define HD 1000
#define HDP 1024
#define EPSBN 1e-5f
#define BF (BB*FF)          // 262144
#define MALL (BB*TN)        // 32768
#define HP 520              // LDS h row stride (1040 B)
#define RROWS 8             // batch rows per rnn block
#define WLS 128             // LDS W row stride (256 B = 2x128B -> bijective XOR)

__device__ __forceinline__ ushort_t f2bf(float f) {
    union { float f; unsigned u; } v; v.f = f;
    unsigned r = v.u + 0x7FFFu + ((v.u >> 16) & 1u);
    return (ushort_t)(r >> 16);
}

__device__ __forceinline__ float b2f(ushort_t u) {
    union { unsigned u; float f; } v; v.u = ((unsigned)u) << 16;
    return v.f;
}

__device__ __forceinline__ float ftanh(float x) {
    const float e = __expf(2.f * x);
    return 1.f - 2.f / (e + 1.f);
}

__device__ __forceinline__ void ld16(const ushort_t* g, ushort_t* l) {
    __builtin_amdgcn_global_load_lds(
        (const __attribute__((address_space(1))) unsigned*)g,
        (__attribute__((address_space(3))) unsigned*)l, 16, 0, 0);
}

// ---------------------------------------------------------------------------
// Large-GEMM kernel, 128x128 tile, BK=32. out[m,n] = sum_k A[m,k]*W[n,k].
// epi: 0 f32 v+p1+p2 | 1 bf16 v | 5 loss (o=v+p1; vs aux; seed/out2; sums)
//      6 bf16 v+bf16(out2[m*o_rs+n]) | 7 f32 v+p1 | 8 bf16 masked col-scale
// ---------------------------------------------------------------------------
__global__ __launch_bounds__(256)
void mfma_gemm(const ushort_t* __restrict__ A, long a_rs,
               const ushort_t* __restrict__ W, int K, int Nreal,
               void* __restrict__ outv, long o_rs,
               const float* __restrict__ aux, int epi, int mbase,
               const float* __restrict__ p1, const float* __restrict__ p2,
               const float* __restrict__ rv, const float* __restrict__ gg,
               ushort_t* __restrict__ out2, float* __restrict__ sums)
{
    __shared__ ushort_t As[128 * 32];
    __shared__ ushort_t Bs[128 * 32];
    __shared__ float red[256];

    const int tid  = threadIdx.x;
    const int wave = tid >> 6, lane = tid & 63;
    const int wm = wave >> 1, wn = wave & 1;
    const int tileM = blockIdx.y * 128, tileN = blockIdx.x * 128;

    f32x4 acc[4][4] = {};
    const int srow = lane >> 2;
    const int skb  = (lane & 3) * 8;

    for (int kt = 0; kt < K; kt += 32) {
        __syncthreads();
#pragma unroll
        for (int s = 0; s < 2; ++s) {
            const int instr = wave * 2 + s;
            const int row = instr * 16 + srow;
            ld16(A + (size_t)(tileM + row) * a_rs + kt + skb, &As[instr * 512]);
            ld16(W + (size_t)(tileN + row) * (size_t)K + kt + skb, &Bs[instr * 512]);
        }
        __syncthreads();
        const int lr = lane & 15;
        const int lk = (lane >> 4) * 8;
        short8 af[4], bfr[4];
#pragma unroll
        for (int i = 0; i < 4; ++i)
            af[i] = *(const short8*)&As[(wm * 64 + i * 16 + lr) * 32 + lk];
#pragma unroll
        for (int j = 0; j < 4; ++j)
            bfr[j] = *(const short8*)&Bs[(wn * 64 + j * 16 + lr) * 32 + lk];
#pragma unroll
        for (int i = 0; i < 4; ++i)
#pragma unroll
            for (int j = 0; j < 4; ++j)
                acc[i][j] = __builtin_amdgcn_mfma_f32_16x16x32_bf16(
                    af[i], bfr[j], acc[i][j], 0, 0, 0);
    }

    const int lr = lane & 15;
    const int rquad = (lane >> 4) * 4;
    float lsum = 0.f;
#pragma unroll
    for (int i = 0; i < 4; ++i) {
#pragma unroll
        for (int r = 0; r < 4; ++r) {
            const int grow = tileM + wm * 64 + i * 16 + rquad + r;
#pragma unroll
            for (int j = 0; j < 4; ++j) {
                const int gcol = tileN + wn * 64 + j * 16 + lr;
                const float v = acc[i][j][r];
                if (epi == 0) {
                    ((float*)outv)[(size_t)grow * o_rs + gcol] = v + p1[gcol] + p2[gcol];
                } else if (epi == 1) {
                    ((ushort_t*)outv)[(size_t)grow * o_rs + gcol] = f2bf(v);
                } else if (epi == 6) {
                    const float w0 = b2f(out2[(size_t)grow * o_rs + gcol]);
                    ((ushort_t*)outv)[(size_t)grow * o_rs + gcol] = f2bf(v + w0);
                } else if (epi == 7) {
                    ((float*)outv)[(size_t)grow * o_rs + gcol] = v + p1[gcol];
                } else if (epi == 8) {
                    float o = 0.f;
                    if (gcol < Nreal)
                        o = v * (gg[gcol] * rsqrtf(rv[gcol] + EPSBN));
                    ((ushort_t*)outv)[(size_t)grow * o_rs + gcol] = f2bf(o);
                } else { // epi 5: loss
                    const float o = v + p1[gcol];
                    const int gm = mbase + grow;
                    const int b = gm >> 6, tau = gm & 63;
                    if (tau < 63) {
                        const float d = o - aux[((size_t)b * TT + tau + 1) * FF + gcol];
                        lsum += d * d;
                    } else {
                        out2[(size_t)b * FF + gcol] = f2bf(o);
                    }
                }
            }
        }
    }
    if (epi == 5) {
        red[tid] = lsum;
        __syncthreads();
        for (int o = 128; o > 0; o >>= 1) {
            if (tid < o) red[tid] += red[tid + o];
            __syncthreads();
        }
        if (tid == 0) atomicAdd(&sums[0], red[0]);
    }
}

// ---------------------------------------------------------------------------
// t = 0 init for the encoder RNN: h0 = tanh(XW[:,0,:]) -> hs (bf16).
// ---------------------------------------------------------------------------
__global__ void rnn_t0(const float* __restrict__ XW, ushort_t* __restrict__ hs)
{
    const int i = blockIdx.x * blockDim.x + threadIdx.x;
    if (i < BF / 2) {
        const int b = i / (FF / 2), c = (i - b * (FF / 2)) * 2;
        const size_t g = ((size_t)b * TN) * FF + c;
        const float2 v = *(const float2*)&XW[g];
        const unsigned rr = (unsigned)f2bf(ftanh(v.x)) |
                            ((unsigned)f2bf(ftanh(v.y)) << 16);
        *(unsigned*)&hs[g] = rr;
    }
}

// ---------------------------------------------------------------------------
// Persistent recurrence (encoder), W-RESIDENT v3.
// 64 blocks x 8 batch rows; 8 waves (512 thr) x 64 output cols.
// Whh chunks 0..11 in 192 regs/lane; chunks 12..15 in bijectively
// XOR-swizzled LDS (WLS=128). waves_per_eu(2,2) pins the 256-VGPR budget.
// ---------------------------------------------------------------------------
__global__ __launch_bounds__(512)
__attribute__((amdgpu_waves_per_eu(2, 2)))
void rnn_persistent(const ushort_t* __restrict__ Whh,
                    const float* __restrict__ XW,
                    ushort_t* __restrict__ hs)
{
    __shared__ ushort_t hb[2][RROWS * HP];   // 16,640 B
    __shared__ ushort_t wl[8 * 64 * WLS];    // 131,072 B
    const int tid = threadIdx.x, wave = tid >> 6, lane = tid & 63;
    const int b0 = blockIdx.x * RROWS;
    const int lr = lane & 15, lq = lane >> 4;
    const int c0 = wave * 64;
    ushort_t* wlw = wl + wave * (64 * WLS);

    // ---- Whh chunks 0..11 -> registers ----
    short8 wreg[12][4];
#pragma unroll
    for (int kc = 0; kc < 12; ++kc)
#pragma unroll
        for (int nt = 0; nt < 4; ++nt)
            wreg[kc][nt] = *(const short8*)(Whh +
                (size_t)(c0 + nt * 16 + lr) * FF + kc * 32 + lq * 8);

    // ---- chunks 12..15 -> LDS, XOR-swizzled (bijective at stride 256 B) ----
#pragma unroll
    for (int i = 0; i < 16; ++i) {
        const int u = i * 64 + lane;         // u in [0,1024): row*16 + c16
        const int row = u >> 4, c16 = u & 15;
        const int boff = (row * (WLS * 2) + c16 * 16) ^ ((row & 7) << 4);
        *(uint4*)((char*)wlw + boff) =
            *(const uint4*)(Whh + (size_t)(c0 + row) * FF + 384 + c16 * 8);
    }

    // ---- load h_0 (from rnn_t0) into hb[0]: 512 thr x 16 B = 8 KB ----
    {
        const int r2 = tid >> 6, cu = (tid & 63) * 8;
        *(uint4*)&hb[0][r2 * HP + cu] =
            *(const uint4*)&hs[((size_t)(b0 + r2) * TN) * FF + cu];
    }
    __syncthreads();

    // ---- per-lane epilogue bases (advanced by +FF per step) ----
    const int base_r = (lq & 1) * 4 + (lq >> 1) * 2;   // lq 0,1,2,3 -> 0,4,2,6
    const float*  xwp0 = XW + ((size_t)(b0 + base_r) * TN) * FF + c0 + lr;
    const float*  xwp1 = XW + ((size_t)(b0 + base_r + 1) * TN) * FF + c0 + lr;
    ushort_t*     hsp0 = hs + ((size_t)(b0 + base_r) * TN) * FF + c0 + lr;
    ushort_t*     hsp1 = hs + ((size_t)(b0 + base_r + 1) * TN) * FF + c0 + lr;
    const int hbo = base_r * HP + c0 + lr;             // LDS write base (ushort)

    f32x4 acc[4];
    short8 af[3];

    for (int t = 1; t < TN; ++t) {
        const ushort_t* hcur = hb[(t - 1) & 1];
        xwp0 += FF; xwp1 += FF; hsp0 += FF; hsp1 += FF;
#pragma unroll
        for (int s = 0; s < 2; ++s)
            af[s] = *(const short8*)&hcur[(lr & 7) * HP + s * 32 + lq * 8];
#pragma unroll
        for (int j = 0; j < 4; ++j) acc[j] = (f32x4){0.f, 0.f, 0.f, 0.f};

#pragma unroll
        for (int kc = 0; kc < 16; ++kc) {
            if (kc + 2 < 16)
                af[(kc + 2) % 3] = *(const short8*)
                    &hcur[(lr & 7) * HP + (kc + 2) * 32 + lq * 8];
            const int b = kc % 3;
            if (kc < 12) {
#pragma unroll
                for (int nt = 0; nt < 4; ++nt)
                    acc[nt] = __builtin_amdgcn_mfma_f32_16x16x32_bf16(
                        af[b], wreg[kc][nt], acc[nt], 0, 0, 0);
            } else {
#pragma unroll
                for (int nt = 0; nt < 4; ++nt) {
                    const int boff = (((nt * 16 + lr) * WLS +
                                       (kc - 12) * 32 + lq * 8) * 2)
                                     ^ ((lr & 7) << 4);
                    const short8 wfr = *(const short8*)((char*)wlw + boff);
                    acc[nt] = __builtin_amdgcn_mfma_f32_16x16x32_bf16(
                        af[b], wfr, acc[nt], 0, 0, 0);
                }
            }
        }

        // epilogue: all 64 lanes write 8 outputs (2 rows x 4 col-tiles).
        // lq>=2 lanes hold duplicate rows in acc[.][2..3] -> rows 2,3 / 6,7.
        ushort_t* hn = hb[t & 1];
#pragma unroll
        for (int nt = 0; nt < 4; ++nt) {
#pragma unroll
            for (int j = 0; j < 2; ++j) {
                const float a = (lq & 2) ? acc[nt][2 + j] : acc[nt][j];
                const float xv = j ? xwp1[nt * 16] : xwp0[nt * 16];
                const ushort_t hv = f2bf(ftanh(a + xv));
                hn[hbo + j * HP + nt * 16] = hv;
                if (j) hsp1[nt * 16] = hv; else hsp0[nt * 16] = hv;
            }
        }
        __syncthreads();
    }
}

// ---------------------------------------------------------------------------
// Fused decode: h' = tanh(h @ Wf^T + bf), 16 steps, row-local, NO sync.
// 32 blocks x 16 batch rows; h ping-pong in LDS; Wf streamed (3-slot ring).
// ---------------------------------------------------------------------------
__global__ __launch_bounds__(256)
void decode_fused(const ushort_t* __restrict__ Wf,
                  const float* __restrict__ bfv,
                  const ushort_t* __restrict__ hs,
                  ushort_t* __restrict__ hall)
{
    __shared__ ushort_t hb[2][16 * HP];
    const int tid = threadIdx.x, wave = tid >> 6, lane = tid & 63;
    const int b0 = blockIdx.x * 16;
    const int lr = lane & 15, lq = lane >> 4;
    const int c0 = wave * 128;

    // load h_63 (encoder final state) into hb[0]
    for (int it = 0; it < 4; ++it) {
        const int e = (it * 256 + tid) * 8;
        const int row = e >> 9, col = e & 511;
        const uint4 v = *(const uint4*)&hs[((size_t)(b0 + row) * TN + 63) * FF + col];
        *(uint4*)&hb[0][row * HP + col] = v;
    }
    __syncthreads();

    float bfj[8];
#pragma unroll
    for (int j = 0; j < 8; ++j) bfj[j] = bfv[c0 + j * 16 + lr];

    f32x4 acc[8];
    short8 wf[3][8];
    short8 af[3];

    for (int g = 0; g < 16; ++g) {
        const ushort_t* hcur = hb[g & 1];
#pragma unroll
        for (int s = 0; s < 2; ++s) {
            const int kk = s * 32 + lq * 8;
            af[s] = *(const short8*)&hcur[lr * HP + kk];
#pragma unroll
            for (int j = 0; j < 8; ++j)
                wf[s][j] = *(const short8*)(Wf + (size_t)(c0 + j * 16 + lr) * FF + kk);
        }
#pragma unroll
        for (int j = 0; j < 8; ++j) acc[j] = (f32x4){0.f, 0.f, 0.f, 0.f};

#pragma unroll
        for (int kc = 0; kc < 16; ++kc) {
            if (kc + 2 < 16) {
                const int slot = (kc + 2) % 3;
                const int kk = (kc + 2) * 32 + lq * 8;
                af[slot] = *(const short8*)&hcur[lr * HP + kk];
#pragma unroll
                for (int j = 0; j < 8; ++j)
                    wf[slot][j] = *(const short8*)
                        (Wf + (size_t)(c0 + j * 16 + lr) * FF + kk);
            }
            const int b = kc % 3;
#pragma unroll
            for (int j = 0; j < 8; ++j)
                acc[j] = __builtin_amdgcn_mfma_f32_16x16x32_bf16(
                    af[b], wf[b][j], acc[j], 0, 0, 0);
        }

        ushort_t* hnxt = hb[(g + 1) & 1];
#pragma unroll
        for (int j = 0; j < 8; ++j) {
            const int col = c0 + j * 16 + lr;
#pragma unroll
            for (int r = 0; r < 4; ++r) {
                const int row = lq * 4 + r;
                const ushort_t hv = f2bf(ftanh(acc[j][r] + bfj[j]));
                hnxt[row * HP + col] = hv;
                hall[((size_t)g * BB + b0 + row) * FF + col] = hv;
            }
        }
        __syncthreads();
    }
}

// ---------------------------------------------------------------------------
// Precompute helpers (fp32 bias chain + bf16 conversions).
// ---------------------------------------------------------------------------
__global__ void conv_x(const float* __restrict__ x, ushort_t* __restrict__ xb)
{
    const int i = blockIdx.x * blockDim.x + threadIdx.x;
    if (i < MALL * FF / 4) {
        const int e = i * 4;
        const int m = e >> 9;
        const int f = e & (FF - 1);
        const int b = m >> 6, t = m & 63;
        const float4 v = *(const float4*)&x[((size_t)b * TT + t) * FF + f];
        unsigned r0 = (unsigned)f2bf(v.x) | ((unsigned)f2bf(v.y) << 16);
        unsigned r1 = (unsigned)f2bf(v.z) | ((unsigned)f2bf(v.w) << 16);
        *(uint2*)&xb[e] = make_uint2(r0, r1);
    }
}

__global__ void conv_w(const float* __restrict__ src, ushort_t* __restrict__ dst,
                       int Nsrc, int Ksrc, int Npad, int Kpad)
{
    const int i = blockIdx.x * blockDim.x + threadIdx.x;
    if (i < Npad * Kpad) {
        const int n = i / Kpad, k = i - n * Kpad;
        const float v = (n < Nsrc && k < Ksrc) ? src[(size_t)n * Ksrc + k] : 0.f;
        dst[i] = f2bf(v);
    }
}

// M1T[k, j] = s1[j] * W1[j, k]   (512 x 1024, bf16; j >= HD -> 0)
__global__ void conv_m1t(const float* __restrict__ W1,
                         const float* __restrict__ g1,
                         const float* __restrict__ rv1,
                         ushort_t* __restrict__ M1T)
{
    const int i = blockIdx.x * blockDim.x + threadIdx.x;
    if (i < FF * HDP) {
        const int k = i >> 10, j = i & (HDP - 1);
        float v = 0.f;
        if (j < HD)
            v = g1[j] * rsqrtf(rv1[j] + EPSBN) * W1[(size_t)j * FF + k];
        M1T[i] = f2bf(v);
    }
}

// W3s[n, k] = s3[n] * W3[n, k]  (FF x HDP, bf16; k >= HD -> 0)
__global__ void conv_w3s(const float* __restrict__ W3,
                         const float* __restrict__ g3,
                         const float* __restrict__ rv3,
                         ushort_t* __restrict__ dst)
{
    const int i = blockIdx.x * blockDim.x + threadIdx.x;
    if (i < FF * HDP) {
        const int n = i >> 10, k = i & (HDP - 1);
        float v = 0.f;
        if (k < HD)
            v = g3[n] * rsqrtf(rv3[n] + EPSBN) * W3[(size_t)n * HD + k];
        dst[i] = f2bf(v);
    }
}

// c1[j] = (b1[j]-rm1[j])*s1[j] + be1[j]  (j<HD else 0)
__global__ void fuse_c1(const float* __restrict__ b1, const float* __restrict__ rm1,
                        const float* __restrict__ rv1, const float* __restrict__ g1,
                        const float* __restrict__ be1, float* __restrict__ c1)
{
    const int j = blockIdx.x * blockDim.x + threadIdx.x;
    if (j < HDP) {
        float o = 0.f;
        if (j < HD) {
            const float s = g1[j] * rsqrtf(rv1[j] + EPSBN);
            o = (b1[j] - rm1[j]) * s + be1[j];
        }
        c1[j] = o;
    }
}

// out[i] = gg ? s_i*dot + (bb-rm)*s_i + be   : dot + a1[i] + a2[i]
__global__ void fuse_mv(const float* __restrict__ W, int K, int Mreal,
                        const float* __restrict__ vin,
                        const float* __restrict__ gg, const float* __restrict__ rv,
                        const float* __restrict__ bb, const float* __restrict__ rm,
                        const float* __restrict__ be,
                        const float* __restrict__ a1, const float* __restrict__ a2,
                        float* __restrict__ out, int Mout)
{
    const int i = blockIdx.x * blockDim.x + threadIdx.x;
    if (i >= Mout) return;
    float o = 0.f;
    if (i < Mreal) {
        const float* row = W + (size_t)i * K;
        float d = 0.f;
        for (int j = 0; j < K; ++j) d += row[j] * vin[j];
        if (gg) {
            const float s = gg[i] * rsqrtf(rv[i] + EPSBN);
            o = s * d + (bb[i] - rm[i]) * s + be[i];
        } else {
            o = d + a1[i] + a2[i];
        }
    }
    out[i] = o;
}

__global__ void zero_init(float* __restrict__ sums)
{
    if (threadIdx.x < 2 && blockIdx.x == 0) sums[threadIdx.x] = 0.f;
}

__global__ void gather_kernel(const float* __restrict__ xgaps,
                              const int* __restrict__ tgap,
                              const float* __restrict__ x,
                              float* __restrict__ out,
                              float* __restrict__ sums)
{
    const int i = blockIdx.x * blockDim.x + threadIdx.x;
    float s = 0.f;
    if (i < BF) {
        const int b = i >> 9, f = i & (FF - 1);
        const int g = tgap[b] - 1;
        const float v = xgaps[((size_t)g * BB + b) * FF + f];
        out[i] = v;
        const float d = v - x[((size_t)b * TT + (TT - 1)) * FF + f];
        s = d * d;
    }
    __shared__ float red[256];
    red[threadIdx.x] = s;
    __syncthreads();
    for (int o = 128; o > 0; o >>= 1) {
        if (threadIdx.x < o) red[threadIdx.x] += red[threadIdx.x + o];
        __syncthreads();
    }
    if (threadIdx.x == 0) atomicAdd(&sums[1], red[0]);
}

__global__ void finalize_kernel(const float* __restrict__ sums,
                                float* __restrict__ out)
{
    if (threadIdx.x == 0 && blockIdx.x == 0) {
        const double n1 = 63.0 * 512.0 * 512.0;
        const double n2 = 512.0 * 512.0;
        out[BF] = (float)((double)sums[0] / (n1 * n1) +
                          (double)sums[1] / (n2 * n2));
    }
}

extern "C" void kernel_launch(void* const* d_in, const int* in_sizes, int n_in,
                              void* d_out, int out_size, void* d_ws, size_t ws_size,
                              hipStream_t stream)
{
    const float* x    = (const float*)d_in[0];
    const int*   tgap = (const int*)d_in[1];
    const float* W_ih = (const float*)d_in[2];
    const float* W_hh = (const float*)d_in[3];
    const float* b_ih = (const float*)d_in[4];
    const float* b_hh = (const float*)d_in[5];
    const float* W1 = (const float*)d_in[6];
    const float* b1 = (const float*)d_in[7];
    const float* g1 = (const float*)d_in[8];
    const float* be1 = (const float*)d_in[9];
    const float* rm1 = (const float*)d_in[10];
    const float* rv1 = (const float*)d_in[11];
    const float* W2 = (const float*)d_in[12];
    const float* b2 = (const float*)d_in[13];
    const float* g2 = (const float*)d_in[14];
    const float* be2 = (const float*)d_in[15];
    const float* rm2 = (const float*)d_in[16];
    const float* rv2 = (const float*)d_in[17];
    const float* W3 = (const float*)d_in[18];
    const float* b3 = (const float*)d_in[19];
    const float* g3 = (const float*)d_in[20];
    const float* be3 = (const float*)d_in[21];
    const float* rm3 = (const float*)d_in[22];
    const float* rv3 = (const float*)d_in[23];
    float* out = (float*)d_out;

    char* p = (char*)d_ws;
    auto take = [&](size_t bytes) -> char* {
        char* r = p; p += (bytes + 63) & ~(size_t)63; return r;
    };
    float*    XWbuf = (float*)take((size_t)MALL * FF * 4);      // 67.1 MB
    ushort_t* hs    = (ushort_t*)take((size_t)MALL * FF * 2);   // 33.5 MB
    ushort_t* xbf   = (ushort_t*)take((size_t)MALL * FF * 2);   // 33.5 MB
    float*    xg    = (float*)take((size_t)16 * BF * 4);        // 16.8 MB
    ushort_t* hall  = (ushort_t*)take((size_t)16 * BF * 2);     //  8.4 MB
    ushort_t* seed  = (ushort_t*)take((size_t)BF * 2);
    ushort_t* Wihb  = (ushort_t*)take((size_t)FF * FF * 2);
    ushort_t* Whhb  = (ushort_t*)take((size_t)FF * FF * 2);
    ushort_t* W2b   = (ushort_t*)take((size_t)HDP * HDP * 2);
    ushort_t* W3s   = (ushort_t*)take((size_t)FF * HDP * 2);
    ushort_t* M1T   = (ushort_t*)take((size_t)FF * HDP * 2);
    ushort_t* Tts   = (ushort_t*)take((size_t)FF * HDP * 2);
    ushort_t* Anb   = (ushort_t*)take((size_t)FF * FF * 2);
    ushort_t* At    = (ushort_t*)take((size_t)FF * FF * 2);
    ushort_t* Wfb   = (ushort_t*)take((size_t)FF * FF * 2);
    float*    c1v   = (float*)take((size_t)HDP * 4);
    float*    v2v   = (float*)take((size_t)HDP * 4);
    float*    bAv   = (float*)take((size_t)FF * 4);
    float*    bfv   = (float*)take((size_t)FF * 4);
    float*    sums  = (float*)take(16 * 4);

    const dim3 blk(256);

    zero_init<<<dim3(1), dim3(64), 0, stream>>>(sums);
    conv_x<<<dim3(MALL * FF / 4 / 256), blk, 0, stream>>>(x, xbf);
    conv_w<<<dim3((FF * FF + 255) / 256), blk, 0, stream>>>(W_ih, Wihb, FF, FF, FF, FF);
    conv_w<<<dim3((FF * FF + 255) / 256), blk, 0, stream>>>(W_hh, Whhb, FF, FF, FF, FF);
    conv_w<<<dim3((HDP * HDP + 255) / 256), blk, 0, stream>>>(W2, W2b, HD, HD, HDP, HDP);
    conv_w3s<<<dim3((FF * HDP + 255) / 256), blk, 0, stream>>>(W3, g3, rv3, W3s);
    conv_m1t<<<dim3((FF * HDP + 255) / 256), blk, 0, stream>>>(W1, g1, rv1, M1T);

    // fp32 bias chain: c1 -> v2 -> bA -> bf
    fuse_c1<<<dim3((HDP + 255) / 256), blk, 0, stream>>>(b1, rm1, rv1, g1, be1, c1v);
    fuse_mv<<<dim3((HDP + 255) / 256), blk, 0, stream>>>(
        W2, HD, HD, c1v, g2, rv2, b2, rm2, be2, nullptr, nullptr, v2v, HDP);
    fuse_mv<<<dim3((FF + 255) / 256), blk, 0, stream>>>(
        W3, HD, FF, v2v, g3, rv3, b3, rm3, be3, nullptr, nullptr, bAv, FF);
    fuse_mv<<<dim3((FF + 255) / 256), blk, 0, stream>>>(
        W_ih, FF, FF, bAv, nullptr, nullptr, nullptr, nullptr, nullptr,
        b_ih, b_hh, bfv, FF);

    // Tts[k,i] = s2[i] * (W2 @ S1 W1)[i,k]   (512 x 1024)
    mfma_gemm<<<dim3(HDP / 128, FF / 128), blk, 0, stream>>>(
        M1T, HDP, W2b, HDP, HD, Tts, HDP, nullptr, 8, 0,
        nullptr, nullptr, rv2, g2, nullptr, nullptr);
    // Anb[a,b] = A[a,b] = sum_j W3s[a,j] * Tts[b,j]   (A = S3 W3 S2 W2 S1 W1)
    mfma_gemm<<<dim3(FF / 128, FF / 128), blk, 0, stream>>>(
        W3s, HDP, Tts, HDP, FF, Anb, FF, nullptr, 1, 0,
        nullptr, nullptr, nullptr, nullptr, nullptr, nullptr);
    // At[k,i] = A[i,k] = sum_j Tts[k,j] * W3s[i,j]
    mfma_gemm<<<dim3(FF / 128, FF / 128), blk, 0, stream>>>(
        Tts, HDP, W3s, HDP, FF, At, FF, nullptr, 1, 0,
        nullptr, nullptr, nullptr, nullptr, nullptr, nullptr);
    // Wfb[n,k] = sum_m Wihb[n,m] * At[k,m] + Whh[n,k]
    mfma_gemm<<<dim3(FF / 128, FF / 128), blk, 0, stream>>>(
        Wihb, FF, At, FF, FF, Wfb, FF, nullptr, 6, 0,
        nullptr, nullptr, nullptr, nullptr, Whhb, nullptr);

    // encoder: XW = x @ W_ih^T + b_ih + b_hh -> fp32
    mfma_gemm<<<dim3(FF / 128, MALL / 128), blk, 0, stream>>>(
        xbf, FF, Wihb, FF, FF, XWbuf, FF, nullptr, 0, 0,
        b_ih, b_hh, nullptr, nullptr, nullptr, nullptr);
    rnn_t0<<<dim3(BF / 2 / 256), blk, 0, stream>>>(XWbuf, hs);
    rnn_persistent<<<dim3(BB / RROWS), dim3(512), 0, stream>>>(Whhb, XWbuf, hs);

    // fused y = hs @ A^T + bA with loss epilogue (one GEMM, M=32768)
    mfma_gemm<<<dim3(FF / 128, MALL / 128), blk, 0, stream>>>(
        hs, FF, Anb, FF, FF, nullptr, 0, x, 5, 0,
        bAv, nullptr, nullptr, nullptr, seed, sums);

    // fused decode: 16 row-local steps, no sync
    decode_fused<<<dim3(BB / 16), blk, 0, stream>>>(Wfb, bfv, hs, hall);

    // xg[g] = h_g @ A^T + bA  (f32, one batched GEMM M=8192)
    mfma_gemm<<<dim3(FF / 128, (16 * BB) / 128), blk, 0, stream>>>(
        hall, FF, Anb, FF, FF, xg, FF, nullptr, 7, 0,
        bAv, nullptr, nullptr, nullptr, nullptr, nullptr);

    gather_kernel<<<dim3(BF / 256), blk, 0, stream>>>(xg, tgap, x, out, sums);
    finalize_kernel<<<dim3(1), dim3(64), 0, stream>>>(sums, out);
}